// Round 11
// baseline (182.447 us; speedup 1.0000x reference)
//
#include <hip/hip_runtime.h>
#include <hip/hip_bf16.h>

// HumanVAttention: QKV proj (+fused RoPE epilogue) -> V transpose -> GQA block-sparse attn -> out proj
// B=1 S=4096 HID=2048 NH=16 NKV=4 HD=128 BLK=64 LOCAL=4 GNB=2 STRIDE=4 ROT=64

typedef short short8 __attribute__((ext_vector_type(8)));
typedef float f32x4  __attribute__((ext_vector_type(4)));

#define NEGV   (-1.0e9f)
#define SCALE  (0.08838834764831845f)

__device__ __forceinline__ void gload16(const void* g, void* l) {
  __builtin_amdgcn_global_load_lds(
      (const __attribute__((address_space(1))) unsigned int*)g,
      (__attribute__((address_space(3))) unsigned int*)l, 16, 0, 0);
}

__device__ __forceinline__ float bf2f(short s) {
  union { unsigned u; float f; } c;
  c.u = ((unsigned)(unsigned short)s) << 16;
  return c.f;
}

__device__ __forceinline__ short f2bf_s(float f) {
  __hip_bfloat16 b = __float2bfloat16(f);
  short s;
  __builtin_memcpy(&s, &b, 2);
  return s;
}

// ---------------- fused prep: hidden f32->bf16 convert + 4 weight transposes ----------------
__global__ void prep_all(const float* __restrict__ H, const float* __restrict__ Wq,
                         const float* __restrict__ Wk, const float* __restrict__ Wv,
                         const float* __restrict__ Wo, __hip_bfloat16* __restrict__ X,
                         __hip_bfloat16* __restrict__ Wt, __hip_bfloat16* __restrict__ Wot) {
  __shared__ __hip_bfloat16 tile[64][73];
  int b = blockIdx.x;
  if (b < 8192) {
    size_t t = (size_t)b * 256 + threadIdx.x;
    float4 v = *(const float4*)(H + t * 4);
    __hip_bfloat16* o = X + t * 4;
    o[0] = __float2bfloat16(v.x); o[1] = __float2bfloat16(v.y);
    o[2] = __float2bfloat16(v.z); o[3] = __float2bfloat16(v.w);
    return;
  }
  const float* src; __hip_bfloat16* dst; int C; int idx;
  if (b < 9216)      { src = Wq; dst = Wt;                          C = 2048; idx = b - 8192; }
  else if (b < 9472) { src = Wk; dst = Wt + (size_t)2048 * 2048;    C = 512;  idx = b - 9216; }
  else if (b < 9728) { src = Wv; dst = Wt + (size_t)2560 * 2048;    C = 512;  idx = b - 9472; }
  else               { src = Wo; dst = Wot;                         C = 2048; idx = b - 9728; }
  int r0 = (idx & 31) * 64, c0 = (idx >> 5) * 64;
  int c = threadIdx.x & 63, rq = threadIdx.x >> 6;
#pragma unroll
  for (int i = 0; i < 16; ++i) {
    int r = i * 4 + rq;
    tile[r][c] = __float2bfloat16(src[(size_t)(r0 + r) * C + c0 + c]);
  }
  __syncthreads();
#pragma unroll
  for (int i = 0; i < 16; ++i) {
    int cc = i * 4 + rq;
    dst[(size_t)(c0 + cc) * 2048 + r0 + c] = tile[c][cc];
  }
}

// ---------------- V transpose: Vb[s][c] (bf16, [4096][512]) -> Vt[c][s] ----------------
__global__ void transpose_v(const __hip_bfloat16* __restrict__ Vb,
                            __hip_bfloat16* __restrict__ Vt) {
  __shared__ __hip_bfloat16 tile[64][73];
  int idx = blockIdx.x;                     // 512 blocks: 64 x 8
  int s0 = (idx & 63) * 64, c0 = (idx >> 6) * 64;
  int c = threadIdx.x & 63, rq = threadIdx.x >> 6;
#pragma unroll
  for (int i = 0; i < 16; ++i) {
    int r = i * 4 + rq;
    tile[r][c] = Vb[(size_t)(s0 + r) * 512 + c0 + c];
  }
  __syncthreads();
#pragma unroll
  for (int i = 0; i < 16; ++i) {
    int cc = i * 4 + rq;
    Vt[(size_t)(c0 + cc) * 4096 + s0 + c] = tile[c][cc];
  }
}

// ---------------- GEMM1: 256x256 tile, pipelined 4-phase + fused RoPE epilogue ----------------
// X[4096][2048] . Wt[3072][2048]^T -> Qb/Kb (roped in-register) / Vb.
// RoPE in epilogue: occupancy is LDS-pinned (128 KiB -> 1 block/CU), so extra VGPR is free
// (R4's regression mechanism doesn't apply). Partner element d^32 = acc[m8][ni^2], same lane,
// compile-time index. Head-local d<64 <=> (wn&1)==0 (wave-uniform). Sign: ni<2 ? - : +.
__global__ __launch_bounds__(512, 2) void gemm_qkv4p(
    const __hip_bfloat16* __restrict__ A, const __hip_bfloat16* __restrict__ Bt,
    const float* __restrict__ cosb, const float* __restrict__ sinb,
    __hip_bfloat16* __restrict__ Qb, __hip_bfloat16* __restrict__ Kb,
    __hip_bfloat16* __restrict__ Vb) {
  const int K = 2048;
  const int tid = threadIdx.x;
  const int wave = tid >> 6, lane = tid & 63;
  const int l15 = lane & 15, lg = lane >> 4;
  const int bm = blockIdx.x, bn = blockIdx.y;
  const int wm = wave >> 2, wn = wave & 3;

  __shared__ __hip_bfloat16 lds[65536];

  f32x4 acc[8][4] = {};
  const int srow = lane >> 3;
  const int sslot = lane & 7;
  const int scol = (sslot ^ srow) * 8;
  const size_t abase = (size_t)bm * 256 * K;
  const size_t bbase = (size_t)bn * 256 * K;
  const int r3 = l15 & 7;

#define STAGE_HALF(SRC, SBASE, HALF, KO, LBASE)                                  \
  {                                                                              \
    _Pragma("unroll")                                                            \
    for (int l = 0; l < 2; ++l) {                                                \
      int chunk = l * 8 + wave;                                                  \
      int row = chunk * 8 + srow;                                                \
      gload16(SRC + (SBASE) + (size_t)((HALF) * 128 + row) * K + (KO) + scol,    \
              &lds[(LBASE) + chunk * 512]);                                      \
    }                                                                            \
  }

  short8 bfr[4][2];
  short8 af[2][2][2];

#define READ_AF(P, Q, BA)                                                        \
  {                                                                              \
    _Pragma("unroll")                                                            \
    for (int m2 = 0; m2 < 2; ++m2)                                               \
      _Pragma("unroll")                                                          \
      for (int ks = 0; ks < 2; ++ks) {                                           \
        int row = ((Q) * 2 + m2) * 16 + l15;                                     \
        int slot = (ks * 4 + lg) ^ r3;                                           \
        af[P][m2][ks] = *(const short8*)&lds[(BA) + row * 64 + slot * 8];        \
      }                                                                          \
  }

#define READ_BF(BB)                                                              \
  {                                                                              \
    _Pragma("unroll")                                                            \
    for (int ni = 0; ni < 4; ++ni)                                               \
      _Pragma("unroll")                                                          \
      for (int ks = 0; ks < 2; ++ks) {                                           \
        int row = (wn & 1) * 64 + ni * 16 + l15;                                 \
        int slot = (ks * 4 + lg) ^ r3;                                           \
        bfr[ni][ks] = *(const short8*)&lds[(BB) + row * 64 + slot * 8];          \
      }                                                                          \
  }

#define MFMA_Q(Q, P)                                                             \
  {                                                                              \
    __builtin_amdgcn_s_setprio(1);                                               \
    _Pragma("unroll")                                                            \
    for (int ks = 0; ks < 2; ++ks)                                               \
      _Pragma("unroll")                                                          \
      for (int m2 = 0; m2 < 2; ++m2)                                             \
        _Pragma("unroll")                                                        \
        for (int ni = 0; ni < 4; ++ni)                                           \
          acc[(Q) * 2 + m2][ni] = __builtin_amdgcn_mfma_f32_16x16x32_bf16(       \
              af[P][m2][ks], bfr[ni][ks], acc[(Q) * 2 + m2][ni], 0, 0, 0);       \
    __builtin_amdgcn_s_setprio(0);                                               \
  }

#define LGKM0()                                                                  \
  asm volatile("s_waitcnt lgkmcnt(0)" ::: "memory");                             \
  __builtin_amdgcn_sched_barrier(0);

  STAGE_HALF(Bt, bbase, 0, 0, 16384);
  STAGE_HALF(Bt, bbase, 1, 0, 24576);
  STAGE_HALF(A, abase, 0, 0, 0);
  STAGE_HALF(A, abase, 1, 0, 8192);
  STAGE_HALF(Bt, bbase, 0, 64, 49152);
  STAGE_HALF(Bt, bbase, 1, 64, 57344);
  asm volatile("s_waitcnt vmcnt(4)" ::: "memory");
  __builtin_amdgcn_sched_barrier(0);
  __builtin_amdgcn_s_barrier();
  {
    const int bA0 = wm * 8192;
    const int bB0 = 16384 + (wn >> 1) * 8192;
    READ_BF(bB0);
    READ_AF(0, 0, bA0);
  }
  LGKM0();

  for (int t = 0; t < 32; ++t) {
    const int buf = (t & 1) * 32768;
    const int nbuf = buf ^ 32768;
    const int bA = buf + wm * 8192;
    if (t + 1 < 32) STAGE_HALF(A, abase, 0, (t + 1) * 64, nbuf);
    __builtin_amdgcn_s_barrier();
    MFMA_Q(0, 0);
    READ_AF(1, 1, bA);
    LGKM0();
    if (t + 1 < 32) STAGE_HALF(A, abase, 1, (t + 1) * 64, nbuf + 8192);
    __builtin_amdgcn_s_barrier();
    MFMA_Q(1, 1);
    READ_AF(0, 2, bA);
    LGKM0();
    if (t + 2 < 32) STAGE_HALF(Bt, bbase, 0, (t + 2) * 64, buf + 16384);
    __builtin_amdgcn_s_barrier();
    MFMA_Q(2, 0);
    READ_AF(1, 3, bA);
    LGKM0();
    if (t + 2 < 32) STAGE_HALF(Bt, bbase, 1, (t + 2) * 64, buf + 24576);
    if (t < 30) asm volatile("s_waitcnt vmcnt(4)" ::: "memory");
    else        asm volatile("s_waitcnt vmcnt(0)" ::: "memory");
    __builtin_amdgcn_sched_barrier(0);
    __builtin_amdgcn_s_barrier();
    MFMA_Q(3, 1);
    if (t + 1 < 32) {
      const int nbA = nbuf + wm * 8192;
      const int nbB = nbuf + 16384 + (wn >> 1) * 8192;
      READ_BF(nbB);
      READ_AF(0, 0, nbA);
    }
    LGKM0();
  }
#undef STAGE_HALF
#undef READ_AF
#undef READ_BF
#undef MFMA_Q
#undef LGKM0

  // ---- epilogue: Q (bn<8, rope), K (8,9, rope), V (10,11, plain) ----
  __hip_bfloat16* dst; int ldc, coff;
  if (bn < 8)       { dst = Qb; ldc = 2048; coff = bn * 256; }
  else if (bn < 10) { dst = Kb; ldc = 512;  coff = bn * 256 - 2048; }
  else              { dst = Vb; ldc = 512;  coff = bn * 256 - 2560; }
  const bool ropew = (bn < 10) && ((wn & 1) == 0);   // wave-uniform: cols with head-d < 64
#pragma unroll
  for (int m8 = 0; m8 < 8; ++m8)
#pragma unroll
    for (int ni = 0; ni < 4; ++ni) {
      int row = bm * 256 + wm * 128 + m8 * 16 + lg * 4;   // source row s
      int col = coff + wn * 64 + ni * 16 + l15;
      if (ropew) {
        const int hd = ni * 16 + l15;                     // head-local d, 0..63
        const float sgn = (ni < 2) ? -1.f : 1.f;
#pragma unroll
        for (int r = 0; r < 4; ++r) {
          float cv = cosb[(size_t)(row + r) * 64 + hd];
          float sv = sinb[(size_t)(row + r) * 64 + hd];
          float pv = acc[m8][ni ^ 2][r];                  // partner d ^ 32 (acc never mutated)
          dst[(size_t)(row + r) * ldc + col] =
              __float2bfloat16(acc[m8][ni][r] * cv + sgn * pv * sv);
        }
      } else {
#pragma unroll
        for (int r = 0; r < 4; ++r)
          dst[(size_t)(row + r) * ldc + col] = __float2bfloat16(acc[m8][ni][r]);
      }
    }
}

// ---------------- GEMM2: C[M][N] f32 = A[M][K] bf16 . Bt[N][K]^T bf16 (verified 128^2) ----------------
__global__ __launch_bounds__(256) void gemm_bt(
    const __hip_bfloat16* __restrict__ A, const __hip_bfloat16* __restrict__ Bt,
    float* __restrict__ C, int M, int N, int K) {
  const int tid = threadIdx.x;
  const int wave = tid >> 6, lane = tid & 63;
  const int l15 = lane & 15, lg = lane >> 4;
  const int bm = blockIdx.x, bn = blockIdx.y;
  const int wm = wave >> 1, wn = wave & 1;

  __shared__ __hip_bfloat16 As[128 * 64];
  __shared__ __hip_bfloat16 Bs[128 * 64];

  f32x4 acc[4][4] = {};
  const int lrow = lane >> 3;
  const int lslot = lane & 7;
  const int scol = (lslot ^ lrow) * 8;
  const size_t abase = (size_t)bm * 128 * K;
  const size_t bbase = (size_t)bn * 128 * K;
  const int r3 = l15 & 7;

  for (int k0 = 0; k0 < K; k0 += 64) {
#pragma unroll
    for (int i = 0; i < 4; ++i) {
      int seg = i * 4 + wave;
      int row = seg * 8 + lrow;
      gload16(A + abase + (size_t)row * K + k0 + scol, &As[seg * 512]);
      gload16(Bt + bbase + (size_t)row * K + k0 + scol, &Bs[seg * 512]);
    }
    __syncthreads();
#pragma unroll
    for (int ks = 0; ks < 2; ++ks) {
      const int slot = (ks * 4 + lg) ^ r3;
      short8 af[4], bf[4];
#pragma unroll
      for (int mi = 0; mi < 4; ++mi)
        af[mi] = *(const short8*)&As[(wm * 64 + mi * 16 + l15) * 64 + slot * 8];
#pragma unroll
      for (int ni = 0; ni < 4; ++ni)
        bf[ni] = *(const short8*)&Bs[(wn * 64 + ni * 16 + l15) * 64 + slot * 8];
#pragma unroll
      for (int mi = 0; mi < 4; ++mi)
#pragma unroll
        for (int ni = 0; ni < 4; ++ni)
          acc[mi][ni] = __builtin_amdgcn_mfma_f32_16x16x32_bf16(af[mi], bf[ni], acc[mi][ni], 0, 0, 0);
    }
    __syncthreads();
  }
#pragma unroll
  for (int mi = 0; mi < 4; ++mi)
#pragma unroll
    for (int ni = 0; ni < 4; ++ni) {
      int row = bm * 128 + wm * 64 + mi * 16 + lg * 4;
      int col = bn * 128 + wn * 64 + ni * 16 + l15;
#pragma unroll
      for (int r = 0; r < 4; ++r)
        C[(size_t)(row + r) * N + col] = acc[mi][ni][r];
    }
}

// ---------------- block-sparse attention: one block per (bi, kvh), 8 waves (R10-verified) ----
__global__ __launch_bounds__(512, 2) void attn_kernel(
    const __hip_bfloat16* __restrict__ Qb,  // [4096][2048]
    const __hip_bfloat16* __restrict__ Kb,  // [4096][512]
    const __hip_bfloat16* __restrict__ Vt,  // [512][4096]  (channel-major)
    const float* __restrict__ amask,        // [4096]
    __hip_bfloat16* __restrict__ AO)        // [4096][2048]
{
  const int bid = blockIdx.x;
  const int kvh = bid & 3;
  const int bi  = bid >> 2;
  const int tid = threadIdx.x;
  const int wave = tid >> 6, lane = tid & 63;
  const int l15 = lane & 15, lg = lane >> 4;
  const int h  = kvh * 4 + (wave >> 1);
  const int rh = wave & 1;
  const int q0 = bi * 64 + rh * 32;

  int sel[6]; int nsel = 0;
  {
    int gtop = bi >> 2;
    for (int j = 0; j <= bi; ++j) {
      bool pick = (j == 0) || (j >= bi - 3) || (((j & 3) == 0) && ((j >> 2) >= gtop - 1));
      if (pick && nsel < 6) sel[nsel++] = j;
    }
  }

  __shared__ __hip_bfloat16 kv[2][16384];  // per buf: K [64][128] at 0, V [128][64] at 8192
  __shared__ __hip_bfloat16 Pl[8][2304];   // per wave: P [32][72]

  short8 qf[2][4];
#pragma unroll
  for (int mi = 0; mi < 2; ++mi)
#pragma unroll
    for (int ks = 0; ks < 4; ++ks)
      qf[mi][ks] = *(const short8*)(Qb + (size_t)(q0 + mi * 16 + l15) * 2048 +
                                    h * 128 + ks * 32 + lg * 8);

  float m[2][4], l[2][4];
  f32x4 oacc[2][8] = {};
#pragma unroll
  for (int mi = 0; mi < 2; ++mi)
#pragma unroll
    for (int r = 0; r < 4; ++r) { m[mi][r] = -3.0e38f; l[mi][r] = 0.f; }

#define STAGE_KV(KB, BUF)                                                          \
  {                                                                                \
    _Pragma("unroll")                                                              \
    for (int i = 0; i < 2; ++i) {                                                  \
      int chunk = (i * 8 + wave) * 64 + lane;                                      \
      int row = chunk >> 4, slot = chunk & 15;                                     \
      gload16(Kb + (size_t)((KB) * 64 + row) * 512 + kvh * 128 +                   \
                  ((slot ^ (row & 15)) * 8),                                       \
              &kv[BUF][(i * 8 + wave) * 512]);                                     \
    }                                                                              \
    _Pragma("unroll")                                                              \
    for (int i = 0; i < 2; ++i) {                                                  \
      int chunk = (i * 8 + wave) * 64 + lane;                                      \
      int row = chunk >> 3, slot = chunk & 7;                                      \
      gload16(Vt + (size_t)(kvh * 128 + row) * 4096 + (KB) * 64 +                  \
                  ((slot ^ (row & 7)) * 8),                                        \
              &kv[BUF][8192 + (i * 8 + wave) * 512]);                              \
    }                                                                              \
  }

  STAGE_KV(sel[0], 0);

#pragma unroll
  for (int j = 0; j < 6; ++j) {
    if (j < nsel) {
      const int kb = sel[j];
      if (j + 1 < nsel) {
        STAGE_KV(sel[j + 1], (j + 1) & 1);
        asm volatile("s_waitcnt vmcnt(4)" ::: "memory");
      } else {
        asm volatile("s_waitcnt vmcnt(0)" ::: "memory");
      }
      __builtin_amdgcn_sched_barrier(0);
      __builtin_amdgcn_s_barrier();
      const __hip_bfloat16* kbuf = kv[j & 1];

      f32x4 sc[2][4] = {};
#pragma unroll
      for (int nf = 0; nf < 4; ++nf)
#pragma unroll
        for (int ks = 0; ks < 4; ++ks) {
          short8 b = *(const short8*)&kbuf[(nf * 16 + l15) * 128 +
                                           (((ks * 4 + lg) ^ l15) * 8)];
          sc[0][nf] = __builtin_amdgcn_mfma_f32_16x16x32_bf16(qf[0][ks], b, sc[0][nf], 0, 0, 0);
          sc[1][nf] = __builtin_amdgcn_mfma_f32_16x16x32_bf16(qf[1][ks], b, sc[1][nf], 0, 0, 0);
        }

      float am[4];
#pragma unroll
      for (int nf = 0; nf < 4; ++nf)
        am[nf] = (1.0f - amask[kb * 64 + nf * 16 + l15]) * NEGV;
#pragma unroll
      for (int mi = 0; mi < 2; ++mi)
#pragma unroll
        for (int nf = 0; nf < 4; ++nf) {
          int keyl = nf * 16 + l15;
#pragma unroll
          for (int r = 0; r < 4; ++r) {
            float s = sc[mi][nf][r] * SCALE + am[nf];
            if (kb == bi) {
              int qrow = rh * 32 + mi * 16 + lg * 4 + r;
              if (keyl > qrow) s = NEGV;
            }
            sc[mi][nf][r] = s;
          }
        }

      float pm[2][4];
#pragma unroll
      for (int mi = 0; mi < 2; ++mi)
#pragma unroll
        for (int r = 0; r < 4; ++r) {
          float v = fmaxf(fmaxf(sc[mi][0][r], sc[mi][1][r]),
                          fmaxf(sc[mi][2][r], sc[mi][3][r]));
          v = fmaxf(v, __shfl_xor(v, 1)); v = fmaxf(v, __shfl_xor(v, 2));
          v = fmaxf(v, __shfl_xor(v, 4)); v = fmaxf(v, __shfl_xor(v, 8));
          pm[mi][r] = v;
        }

      bool need = false;
#pragma unroll
      for (int mi = 0; mi < 2; ++mi)
#pragma unroll
        for (int r = 0; r < 4; ++r) need |= (pm[mi][r] - m[mi][r] > 8.0f);
      if (__any(need)) {
#pragma unroll
        for (int mi = 0; mi < 2; ++mi)
#pragma unroll
          for (int r = 0; r < 4; ++r) {
            float mn = fmaxf(m[mi][r], pm[mi][r]);
            float scl = __expf(m[mi][r] - mn);
            l[mi][r] *= scl;
#pragma unroll
            for (int df = 0; df < 8; ++df) oacc[mi][df][r] *= scl;
            m[mi][r] = mn;
          }
      }

#pragma unroll
      for (int mi = 0; mi < 2; ++mi)
#pragma unroll
        for (int r = 0; r < 4; ++r) {
          float rs = 0.f;
#pragma unroll
          for (int nf = 0; nf < 4; ++nf) {
            float p = __expf(sc[mi][nf][r] - m[mi][r]);
            rs += p;
            Pl[wave][(mi * 16 + lg * 4 + r) * 72 + nf * 16 + l15] = __float2bfloat16(p);
          }
          rs += __shfl_xor(rs, 1); rs += __shfl_xor(rs, 2);
          rs += __shfl_xor(rs, 4); rs += __shfl_xor(rs, 8);
          l[mi][r] += rs;
        }

      short8 af2[2][2];
#pragma unroll
      for (int mi = 0; mi < 2; ++mi)
#pragma unroll
        for (int ks = 0; ks < 2; ++ks)
          af2[mi][ks] = *(const short8*)&Pl[wave][(mi * 16 + l15) * 72 + ks * 32 + lg * 8];
#pragma unroll
      for (int df = 0; df < 8; ++df)
#pragma unroll
        for (int ks = 0; ks < 2; ++ks) {
          short8 vb = *(const short8*)&kbuf[8192 + (df * 16 + l15) * 64 +
                                            (((ks * 4 + lg) ^ (l15 & 7)) * 8)];
          oacc[0][df] = __builtin_amdgcn_mfma_f32_16x16x32_bf16(af2[0][ks], vb, oacc[0][df], 0, 0, 0);
          oacc[1][df] = __builtin_amdgcn_mfma_f32_16x16x32_bf16(af2[1][ks], vb, oacc[1][df], 0, 0, 0);
        }
      __builtin_amdgcn_s_barrier();
    }
  }
#undef STAGE_KV

#pragma unroll
  for (int mi = 0; mi < 2; ++mi) {
    float inv[4];
#pragma unroll
    for (int r = 0; r < 4; ++r) inv[r] = 1.0f / l[mi][r];
#pragma unroll
    for (int df = 0; df < 8; ++df)
#pragma unroll
      for (int r = 0; r < 4; ++r) {
        int qrow = q0 + mi * 16 + lg * 4 + r;
        AO[(size_t)qrow * 2048 + h * 128 + df * 16 + l15] =
            __float2bfloat16(oacc[mi][df][r] * inv[r]);
      }
  }
}

// ---------------- launch ----------------
extern "C" void kernel_launch(void* const* d_in, const int* in_sizes, int n_in,
                              void* d_out, int out_size, void* d_ws, size_t ws_size,
                              hipStream_t stream) {
  const float* hidden = (const float*)d_in[0];
  const float* cosb   = (const float*)d_in[1];
  const float* sinb   = (const float*)d_in[2];
  const float* Wq     = (const float*)d_in[3];
  const float* Wk     = (const float*)d_in[4];
  const float* Wv     = (const float*)d_in[5];
  const float* Wo     = (const float*)d_in[6];
  const float* amask  = (const float*)d_in[7];

  char* ws = (char*)d_ws;
  __hip_bfloat16* Xb   = (__hip_bfloat16*)(ws);               // 16,777,216 B  [4096][2048]
  __hip_bfloat16* Wt   = (__hip_bfloat16*)(ws + 16777216);    // 12,582,912 B  [3072][2048]
  __hip_bfloat16* Wot  = (__hip_bfloat16*)(ws + 29360128);    //  8,388,608 B  [2048][2048]
  __hip_bfloat16* Qb   = (__hip_bfloat16*)(ws + 37748736);    // 16,777,216 B  [4096][2048]
  __hip_bfloat16* Kb   = (__hip_bfloat16*)(ws + 54525952);    //  4,194,304 B  [4096][512]
  __hip_bfloat16* Vb   = (__hip_bfloat16*)(ws + 58720256);    //  4,194,304 B  [4096][512]
  __hip_bfloat16* Vt   = (__hip_bfloat16*)(ws + 62914560);    //  4,194,304 B  [512][4096]
  __hip_bfloat16* AO   = Xb;  // Xb dead after gemm_qkv4p; reuse for attention output

  prep_all<<<10752, 256, 0, stream>>>(hidden, Wq, Wk, Wv, Wo, Xb, Wt, Wot);

  gemm_qkv4p<<<dim3(16, 12), 512, 0, stream>>>(Xb, Wt, cosb, sinb, Qb, Kb, Vb);

  transpose_v<<<512, 256, 0, stream>>>(Vb, Vt);

  attn_kernel<<<256, 512, 0, stream>>>(Qb, Kb, Vt, amask, AO);

  gemm_bt<<<dim3(32, 16), 256, 0, stream>>>(AO, Wot, (float*)d_out, 4096, 2048, 2048);
}

// Round 12
// 175.118 us; speedup vs baseline: 1.0419x; 1.0419x over previous
//
#include <hip/hip_runtime.h>
#include <hip/hip_bf16.h>

// HumanVAttention: QKV proj -> in-place RoPE + V transpose -> GQA block-sparse attn -> out proj
// B=1 S=4096 HID=2048 NH=16 NKV=4 HD=128 BLK=64 LOCAL=4 GNB=2 STRIDE=4 ROT=64

typedef short short8 __attribute__((ext_vector_type(8)));
typedef float f32x4  __attribute__((ext_vector_type(4)));

#define NEGV   (-1.0e9f)
#define SCALE  (0.08838834764831845f)

__device__ __forceinline__ void gload16(const void* g, void* l) {
  __builtin_amdgcn_global_load_lds(
      (const __attribute__((address_space(1))) unsigned int*)g,
      (__attribute__((address_space(3))) unsigned int*)l, 16, 0, 0);
}

__device__ __forceinline__ float bf2f(short s) {
  union { unsigned u; float f; } c;
  c.u = ((unsigned)(unsigned short)s) << 16;
  return c.f;
}

__device__ __forceinline__ short f2bf_s(float f) {
  __hip_bfloat16 b = __float2bfloat16(f);
  short s;
  __builtin_memcpy(&s, &b, 2);
  return s;
}

// ---------------- fused prep: hidden f32->bf16 convert + 4 weight transposes ----------------
__global__ void prep_all(const float* __restrict__ H, const float* __restrict__ Wq,
                         const float* __restrict__ Wk, const float* __restrict__ Wv,
                         const float* __restrict__ Wo, __hip_bfloat16* __restrict__ X,
                         __hip_bfloat16* __restrict__ Wt, __hip_bfloat16* __restrict__ Wot) {
  __shared__ __hip_bfloat16 tile[64][73];
  int b = blockIdx.x;
  if (b < 8192) {
    size_t t = (size_t)b * 256 + threadIdx.x;
    float4 v = *(const float4*)(H + t * 4);
    __hip_bfloat16* o = X + t * 4;
    o[0] = __float2bfloat16(v.x); o[1] = __float2bfloat16(v.y);
    o[2] = __float2bfloat16(v.z); o[3] = __float2bfloat16(v.w);
    return;
  }
  const float* src; __hip_bfloat16* dst; int C; int idx;
  if (b < 9216)      { src = Wq; dst = Wt;                          C = 2048; idx = b - 8192; }
  else if (b < 9472) { src = Wk; dst = Wt + (size_t)2048 * 2048;    C = 512;  idx = b - 9216; }
  else if (b < 9728) { src = Wv; dst = Wt + (size_t)2560 * 2048;    C = 512;  idx = b - 9472; }
  else               { src = Wo; dst = Wot;                         C = 2048; idx = b - 9728; }
  int r0 = (idx & 31) * 64, c0 = (idx >> 5) * 64;
  int c = threadIdx.x & 63, rq = threadIdx.x >> 6;
#pragma unroll
  for (int i = 0; i < 16; ++i) {
    int r = i * 4 + rq;
    tile[r][c] = __float2bfloat16(src[(size_t)(r0 + r) * C + c0 + c]);
  }
  __syncthreads();
#pragma unroll
  for (int i = 0; i < 16; ++i) {
    int cc = i * 4 + rq;
    dst[(size_t)(c0 + cc) * 2048 + r0 + c] = tile[c][cc];
  }
}

// ---------------- fused postproc: in-place RoPE (Q,K) + V transpose (R10-verified) ----------------
__global__ void postproc(const float* __restrict__ cosb, const float* __restrict__ sinb,
                         __hip_bfloat16* __restrict__ Qb, __hip_bfloat16* __restrict__ Kb,
                         const __hip_bfloat16* __restrict__ Vb, __hip_bfloat16* __restrict__ Vt) {
  __shared__ __hip_bfloat16 tile[64][73];
  int blk = blockIdx.x;
  if (blk < 1280) {
    int t = blk * 256 + threadIdx.x;
    __hip_bfloat16* p;
    int s;
    if (t < 262144) {               // Q
      s = t >> 6;
      int rem = t & 63;
      p = Qb + (size_t)s * 2048 + (rem >> 2) * 128 + (rem & 3) * 8;
    } else {                        // K
      int tk = t - 262144;
      s = tk >> 4;
      int rem = tk & 15;
      p = Kb + (size_t)s * 512 + (rem >> 2) * 128 + (rem & 3) * 8;
    }
    const int g8 = (t & 3) * 8;
    const float* cp = cosb + (size_t)s * 64 + g8;
    const float* sp = sinb + (size_t)s * 64 + g8;
    short8 a = *(const short8*)p;
    short8 b = *(const short8*)(p + 32);
    float ca[8], sa[8], cb[8], sb[8];
    *(float4*)&ca[0] = *(const float4*)cp;        *(float4*)&ca[4] = *(const float4*)(cp + 4);
    *(float4*)&cb[0] = *(const float4*)(cp + 32); *(float4*)&cb[4] = *(const float4*)(cp + 36);
    *(float4*)&sa[0] = *(const float4*)sp;        *(float4*)&sa[4] = *(const float4*)(sp + 4);
    *(float4*)&sb[0] = *(const float4*)(sp + 32); *(float4*)&sb[4] = *(const float4*)(sp + 36);
    short8 oa, ob;
#pragma unroll
    for (int i = 0; i < 8; ++i) {
      float av = bf2f(a[i]), bv = bf2f(b[i]);
      oa[i] = f2bf_s(av * ca[i] - bv * sa[i]);
      ob[i] = f2bf_s(bv * cb[i] + av * sb[i]);
    }
    *(short8*)p = oa;
    *(short8*)(p + 32) = ob;
    return;
  }
  int idx = blk - 1280;                     // 512 blocks: 64 x 8
  int s0 = (idx & 63) * 64, c0 = (idx >> 6) * 64;
  int c = threadIdx.x & 63, rq = threadIdx.x >> 6;
#pragma unroll
  for (int i = 0; i < 16; ++i) {
    int r = i * 4 + rq;
    tile[r][c] = Vb[(size_t)(s0 + r) * 512 + c0 + c];
  }
  __syncthreads();
#pragma unroll
  for (int i = 0; i < 16; ++i) {
    int cc = i * 4 + rq;
    Vt[(size_t)(c0 + cc) * 4096 + s0 + c] = tile[c][cc];
  }
}

// ---------------- GEMM1: BM=256 x BN=128 tile, 2-phase (R7-verified structure), grid 384 ----
// X[4096][2048] . Wt[3072][2048]^T -> Qb/Kb/Vb. 8 waves (4 wm x 2 wn), per-wave 64x64
// (R3-verified wave-level code). LDS 96 KiB = 2 buf x (A 256x64 = 32KB + B 128x64 = 16KB).
// Grid 384 = 1.5 blocks/CU (fills all 256 CUs; 256^2 left 64 idle). Bijective XCD swizzle:
// XCD x gets 3 consecutive B-panels (1.5 MB, L2-resident, reused by 16 bm-blocks).
__global__ __launch_bounds__(512) void gemm_qkv(
    const __hip_bfloat16* __restrict__ A, const __hip_bfloat16* __restrict__ Bt,
    __hip_bfloat16* __restrict__ Qb, __hip_bfloat16* __restrict__ Kb,
    __hip_bfloat16* __restrict__ Vb) {
  const int K = 2048;
  const int tid = threadIdx.x;
  const int wave = tid >> 6, lane = tid & 63;
  const int l15 = lane & 15, lg = lane >> 4;
  // XCD-bijective remap: nwg=384 (384%8==0); j = (id&7)*48 + id>>3; bm fastest.
  const int j = (blockIdx.x & 7) * 48 + (blockIdx.x >> 3);
  const int bm = j & 15, bn = j >> 4;       // bm 0..15, bn 0..23
  const int wm = wave >> 1, wn = wave & 1;  // 4 x 2 wave grid; per-wave C: 64x64

  __shared__ __hip_bfloat16 lds[49152];     // 96 KiB: [buf][A 16384 | B 8192] elems

  f32x4 acc[4][4] = {};
  const int lrow = lane >> 3;               // 0..7
  const int lslot = lane & 7;
  const int scol = (lslot ^ lrow) * 8;      // pre-swizzled global col (row&7 == lrow)
  const size_t abase = (size_t)bm * 256 * K;
  const size_t bbase = (size_t)bn * 128 * K;
  const int r3 = l15 & 7;

  // stage one K-tile (A 256x64 + B 128x64): 6 gload16/thread
#define STAGE_TILE(BUF, KO)                                                        \
  {                                                                                \
    _Pragma("unroll")                                                              \
    for (int i = 0; i < 4; ++i) {                                                  \
      int seg = i * 8 + wave;               /* 0..31, 8 rows each */               \
      int row = seg * 8 + lrow;             /* 0..255 */                           \
      gload16(A + abase + (size_t)row * K + (KO) + scol, &lds[(BUF) + seg * 512]); \
    }                                                                              \
    _Pragma("unroll")                                                              \
    for (int i = 0; i < 2; ++i) {                                                  \
      int seg = i * 8 + wave;               /* 0..15, 8 rows each */               \
      int row = seg * 8 + lrow;             /* 0..127 */                           \
      gload16(Bt + bbase + (size_t)row * K + (KO) + scol,                          \
              &lds[(BUF) + 16384 + seg * 512]);                                    \
    }                                                                              \
  }

  STAGE_TILE(0, 0);

  for (int t = 0; t < 32; ++t) {
    asm volatile("s_waitcnt vmcnt(0)" ::: "memory");
    __builtin_amdgcn_s_barrier();
    __builtin_amdgcn_sched_barrier(0);
    const int buf = (t & 1) ? 24576 : 0;
    const int nbuf = buf ^ 24576;
    if (t + 1 < 32) STAGE_TILE(nbuf, (t + 1) * 64);
    const __hip_bfloat16* As_ = lds + buf;
    const __hip_bfloat16* Bs_ = lds + buf + 16384;
#pragma unroll
    for (int ks = 0; ks < 2; ++ks) {
      const int slot = (ks * 4 + lg) ^ r3;
      short8 af[4], bf[4];
#pragma unroll
      for (int mi = 0; mi < 4; ++mi)
        af[mi] = *(const short8*)&As_[(wm * 64 + mi * 16 + l15) * 64 + slot * 8];
#pragma unroll
      for (int ni = 0; ni < 4; ++ni)
        bf[ni] = *(const short8*)&Bs_[(wn * 64 + ni * 16 + l15) * 64 + slot * 8];
      __builtin_amdgcn_s_setprio(1);
#pragma unroll
      for (int mi = 0; mi < 4; ++mi)
#pragma unroll
        for (int ni = 0; ni < 4; ++ni)
          acc[mi][ni] = __builtin_amdgcn_mfma_f32_16x16x32_bf16(af[mi], bf[ni], acc[mi][ni], 0, 0, 0);
      __builtin_amdgcn_s_setprio(0);
    }
  }
#undef STAGE_TILE

  // ---- epilogue: bn tile (128 cols) == one head: Q (bn<16), K (16..19), V (20..23) ----
  __hip_bfloat16* dst; int ldc, coff;
  if (bn < 16)      { dst = Qb; ldc = 2048; coff = bn * 128; }
  else if (bn < 20) { dst = Kb; ldc = 512;  coff = (bn - 16) * 128; }
  else              { dst = Vb; ldc = 512;  coff = (bn - 20) * 128; }
#pragma unroll
  for (int mi = 0; mi < 4; ++mi)
#pragma unroll
    for (int ni = 0; ni < 4; ++ni) {
      int row = bm * 256 + wm * 64 + mi * 16 + lg * 4;
      int col = coff + wn * 64 + ni * 16 + l15;
#pragma unroll
      for (int r = 0; r < 4; ++r)
        dst[(size_t)(row + r) * ldc + col] = __float2bfloat16(acc[mi][ni][r]);
    }
}

// ---------------- GEMM2: C[M][N] f32 = A[M][K] bf16 . Bt[N][K]^T bf16 (verified 128^2) ----------------
__global__ __launch_bounds__(256) void gemm_bt(
    const __hip_bfloat16* __restrict__ A, const __hip_bfloat16* __restrict__ Bt,
    float* __restrict__ C, int M, int N, int K) {
  const int tid = threadIdx.x;
  const int wave = tid >> 6, lane = tid & 63;
  const int l15 = lane & 15, lg = lane >> 4;
  const int bm = blockIdx.x, bn = blockIdx.y;
  const int wm = wave >> 1, wn = wave & 1;

  __shared__ __hip_bfloat16 As[128 * 64];
  __shared__ __hip_bfloat16 Bs[128 * 64];

  f32x4 acc[4][4] = {};
  const int lrow = lane >> 3;
  const int lslot = lane & 7;
  const int scol = (lslot ^ lrow) * 8;
  const size_t abase = (size_t)bm * 128 * K;
  const size_t bbase = (size_t)bn * 128 * K;
  const int r3 = l15 & 7;

  for (int k0 = 0; k0 < K; k0 += 64) {
#pragma unroll
    for (int i = 0; i < 4; ++i) {
      int seg = i * 4 + wave;
      int row = seg * 8 + lrow;
      gload16(A + abase + (size_t)row * K + k0 + scol, &As[seg * 512]);
      gload16(Bt + bbase + (size_t)row * K + k0 + scol, &Bs[seg * 512]);
    }
    __syncthreads();
#pragma unroll
    for (int ks = 0; ks < 2; ++ks) {
      const int slot = (ks * 4 + lg) ^ r3;
      short8 af[4], bf[4];
#pragma unroll
      for (int mi = 0; mi < 4; ++mi)
        af[mi] = *(const short8*)&As[(wm * 64 + mi * 16 + l15) * 64 + slot * 8];
#pragma unroll
      for (int ni = 0; ni < 4; ++ni)
        bf[ni] = *(const short8*)&Bs[(wn * 64 + ni * 16 + l15) * 64 + slot * 8];
#pragma unroll
      for (int mi = 0; mi < 4; ++mi)
#pragma unroll
        for (int ni = 0; ni < 4; ++ni)
          acc[mi][ni] = __builtin_amdgcn_mfma_f32_16x16x32_bf16(af[mi], bf[ni], acc[mi][ni], 0, 0, 0);
    }
    __syncthreads();
  }
#pragma unroll
  for (int mi = 0; mi < 4; ++mi)
#pragma unroll
    for (int ni = 0; ni < 4; ++ni) {
      int row = bm * 128 + wm * 64 + mi * 16 + lg * 4;
      int col = bn * 128 + wn * 64 + ni * 16 + l15;
#pragma unroll
      for (int r = 0; r < 4; ++r)
        C[(size_t)(row + r) * N + col] = acc[mi][ni][r];
    }
}

// ---------------- block-sparse attention: one block per (bi, kvh), 8 waves (R10-verified) ----
__global__ __launch_bounds__(512, 2) void attn_kernel(
    const __hip_bfloat16* __restrict__ Qb,  // [4096][2048]
    const __hip_bfloat16* __restrict__ Kb,  // [4096][512]
    const __hip_bfloat16* __restrict__ Vt,  // [512][4096]  (channel-major)
    const float* __restrict__ amask,        // [4096]
    __hip_bfloat16* __restrict__ AO)        // [4096][2048]
{
  const int bid = blockIdx.x;
  const int kvh = bid & 3;
  const int bi  = bid >> 2;
  const int tid = threadIdx.x;
  const int wave = tid >> 6, lane = tid & 63;
  const int l15 = lane & 15, lg = lane >> 4;
  const int h  = kvh * 4 + (wave >> 1);
  const int rh = wave & 1;
  const int q0 = bi * 64 + rh * 32;

  int sel[6]; int nsel = 0;
  {
    int gtop = bi >> 2;
    for (int j = 0; j <= bi; ++j) {
      bool pick = (j == 0) || (j >= bi - 3) || (((j & 3) == 0) && ((j >> 2) >= gtop - 1));
      if (pick && nsel < 6) sel[nsel++] = j;
    }
  }

  __shared__ __hip_bfloat16 kv[2][16384];  // per buf: K [64][128] at 0, V [128][64] at 8192
  __shared__ __hip_bfloat16 Pl[8][2304];   // per wave: P [32][72]

  short8 qf[2][4];
#pragma unroll
  for (int mi = 0; mi < 2; ++mi)
#pragma unroll
    for (int ks = 0; ks < 4; ++ks)
      qf[mi][ks] = *(const short8*)(Qb + (size_t)(q0 + mi * 16 + l15) * 2048 +
                                    h * 128 + ks * 32 + lg * 8);

  float m[2][4], l[2][4];
  f32x4 oacc[2][8] = {};
#pragma unroll
  for (int mi = 0; mi < 2; ++mi)
#pragma unroll
    for (int r = 0; r < 4; ++r) { m[mi][r] = -3.0e38f; l[mi][r] = 0.f; }

#define STAGE_KV(KB, BUF)                                                          \
  {                                                                                \
    _Pragma("unroll")                                                              \
    for (int i = 0; i < 2; ++i) {                                                  \
      int chunk = (i * 8 + wave) * 64 + lane;                                      \
      int row = chunk >> 4, slot = chunk & 15;                                     \
      gload16(Kb + (size_t)((KB) * 64 + row) * 512 + kvh * 128 +                   \
                  ((slot ^ (row & 15)) * 8),                                       \
              &kv[BUF][(i * 8 + wave) * 512]);                                     \
    }                                                                              \
    _Pragma("unroll")                                                              \
    for (int i = 0; i < 2; ++i) {                                                  \
      int chunk = (i * 8 + wave) * 64 + lane;                                      \
      int row = chunk >> 3, slot = chunk & 7;                                      \
      gload16(Vt + (size_t)(kvh * 128 + row) * 4096 + (KB) * 64 +                  \
                  ((slot ^ (row & 7)) * 8),                                        \
              &kv[BUF][8192 + (i * 8 + wave) * 512]);                              \
    }                                                                              \
  }

  STAGE_KV(sel[0], 0);

#pragma unroll
  for (int j = 0; j < 6; ++j) {
    if (j < nsel) {
      const int kb = sel[j];
      if (j + 1 < nsel) {
        STAGE_KV(sel[j + 1], (j + 1) & 1);
        asm volatile("s_waitcnt vmcnt(4)" ::: "memory");
      } else {
        asm volatile("s_waitcnt vmcnt(0)" ::: "memory");
      }
      __builtin_amdgcn_sched_barrier(0);
      __builtin_amdgcn_s_barrier();
      const __hip_bfloat16* kbuf = kv[j & 1];

      f32x4 sc[2][4] = {};
#pragma unroll
      for (int nf = 0; nf < 4; ++nf)
#pragma unroll
        for (int ks = 0; ks < 4; ++ks) {
          short8 b = *(const short8*)&kbuf[(nf * 16 + l15) * 128 +
                                           (((ks * 4 + lg) ^ l15) * 8)];
          sc[0][nf] = __builtin_amdgcn_mfma_f32_16x16x32_bf16(qf[0][ks], b, sc[0][nf], 0, 0, 0);
          sc[1][nf] = __builtin_amdgcn_mfma_f32_16x16x32_bf16(qf[1][ks], b, sc[1][nf], 0, 0, 0);
        }

      float am[4];
#pragma unroll
      for (int nf = 0; nf < 4; ++nf)
        am[nf] = (1.0f - amask[kb * 64 + nf * 16 + l15]) * NEGV;
#pragma unroll
      for (int mi = 0; mi < 2; ++mi)
#pragma unroll
        for (int nf = 0; nf < 4; ++nf) {
          int keyl = nf * 16 + l15;
#pragma unroll
          for (int r = 0; r < 4; ++r) {
            float s = sc[mi][nf][r] * SCALE + am[nf];
            if (kb == bi) {
              int qrow = rh * 32 + mi * 16 + lg * 4 + r;
              if (keyl > qrow) s = NEGV;
            }
            sc[mi][nf][r] = s;
          }
        }

      float pm[2][4];
#pragma unroll
      for (int mi = 0; mi < 2; ++mi)
#pragma unroll
        for (int r = 0; r < 4; ++r) {
          float v = fmaxf(fmaxf(sc[mi][0][r], sc[mi][1][r]),
                          fmaxf(sc[mi][2][r], sc[mi][3][r]));
          v = fmaxf(v, __shfl_xor(v, 1)); v = fmaxf(v, __shfl_xor(v, 2));
          v = fmaxf(v, __shfl_xor(v, 4)); v = fmaxf(v, __shfl_xor(v, 8));
          pm[mi][r] = v;
        }

      bool need = false;
#pragma unroll
      for (int mi = 0; mi < 2; ++mi)
#pragma unroll
        for (int r = 0; r < 4; ++r) need |= (pm[mi][r] - m[mi][r] > 8.0f);
      if (__any(need)) {
#pragma unroll
        for (int mi = 0; mi < 2; ++mi)
#pragma unroll
          for (int r = 0; r < 4; ++r) {
            float mn = fmaxf(m[mi][r], pm[mi][r]);
            float scl = __expf(m[mi][r] - mn);
            l[mi][r] *= scl;
#pragma unroll
            for (int df = 0; df < 8; ++df) oacc[mi][df][r] *= scl;
            m[mi][r] = mn;
          }
      }

#pragma unroll
      for (int mi = 0; mi < 2; ++mi)
#pragma unroll
        for (int r = 0; r < 4; ++r) {
          float rs = 0.f;
#pragma unroll
          for (int nf = 0; nf < 4; ++nf) {
            float p = __expf(sc[mi][nf][r] - m[mi][r]);
            rs += p;
            Pl[wave][(mi * 16 + lg * 4 + r) * 72 + nf * 16 + l15] = __float2bfloat16(p);
          }
          rs += __shfl_xor(rs, 1); rs += __shfl_xor(rs, 2);
          rs += __shfl_xor(rs, 4); rs += __shfl_xor(rs, 8);
          l[mi][r] += rs;
        }

      short8 af2[2][2];
#pragma unroll
      for (int mi = 0; mi < 2; ++mi)
#pragma unroll
        for (int ks = 0; ks < 2; ++ks)
          af2[mi][ks] = *(const short8*)&Pl[wave][(mi * 16 + l15) * 72 + ks * 32 + lg * 8];
#pragma unroll
      for (int df = 0; df < 8; ++df)
#pragma unroll
        for (int ks = 0; ks < 2; ++ks) {
          short8 vb = *(const short8*)&kbuf[8192 + (df * 16 + l15) * 64 +
                                            (((ks * 4 + lg) ^ (l15 & 7)) * 8)];
          oacc[0][df] = __builtin_amdgcn_mfma_f32_16x16x32_bf16(af2[0][ks], vb, oacc[0][df], 0, 0, 0);
          oacc[1][df] = __builtin_amdgcn_mfma_f32_16x16x32_bf16(af2[1][ks], vb, oacc[1][df], 0, 0, 0);
        }
      __builtin_amdgcn_s_barrier();
    }
  }
#undef STAGE_KV

#pragma unroll
  for (int mi = 0; mi < 2; ++mi) {
    float inv[4];
#pragma unroll
    for (int r = 0; r < 4; ++r) inv[r] = 1.0f / l[mi][r];
#pragma unroll
    for (int df = 0; df < 8; ++df)
#pragma unroll
      for (int r = 0; r < 4; ++r) {
        int qrow = q0 + mi * 16 + lg * 4 + r;
        AO[(size_t)qrow * 2048 + h * 128 + df * 16 + l15] =
            __float2bfloat16(oacc[mi][df][r] * inv[r]);
      }
  }
}

// ---------------- launch ----------------
extern "C" void kernel_launch(void* const* d_in, const int* in_sizes, int n_in,
                              void* d_out, int out_size, void* d_ws, size_t ws_size,
                              hipStream_t stream) {
  const float* hidden = (const float*)d_in[0];
  const float* cosb   = (const float*)d_in[1];
  const float* sinb   = (const float*)d_in[2];
  const float* Wq     = (const float*)d_in[3];
  const float* Wk     = (const float*)d_in[4];
  const float* Wv     = (const float*)d_in[5];
  const float* Wo     = (const float*)d_in[6];
  const float* amask  = (const float*)d_in[7];

  char* ws = (char*)d_ws;
  __hip_bfloat16* Xb   = (__hip_bfloat16*)(ws);               // 16,777,216 B  [4096][2048]
  __hip_bfloat16* Wt   = (__hip_bfloat16*)(ws + 16777216);    // 12,582,912 B  [3072][2048]
  __hip_bfloat16* Wot  = (__hip_bfloat16*)(ws + 29360128);    //  8,388,608 B  [2048][2048]
  __hip_bfloat16* Qb   = (__hip_bfloat16*)(ws + 37748736);    // 16,777,216 B  [4096][2048]
  __hip_bfloat16* Kb   = (__hip_bfloat16*)(ws + 54525952);    //  4,194,304 B  [4096][512]
  __hip_bfloat16* Vb   = (__hip_bfloat16*)(ws + 58720256);    //  4,194,304 B  [4096][512]
  __hip_bfloat16* Vt   = (__hip_bfloat16*)(ws + 62914560);    //  4,194,304 B  [512][4096]
  __hip_bfloat16* AO   = Xb;  // Xb dead after gemm_qkv; reuse for attention output

  prep_all<<<10752, 256, 0, stream>>>(hidden, Wq, Wk, Wv, Wo, Xb, Wt, Wot);

  gemm_qkv<<<384, 512, 0, stream>>>(Xb, Wt, Qb, Kb, Vb);

  postproc<<<1792, 256, 0, stream>>>(cosb, sinb, Qb, Kb, Vb, Vt);

  attn_kernel<<<256, 512, 0, stream>>>(Qb, Kb, Vt, amask, AO);

  gemm_bt<<<dim3(32, 16), 256, 0, stream>>>(AO, Wot, (float*)d_out, 4096, 2048, 2048);
}

// Round 13
// 165.233 us; speedup vs baseline: 1.1042x; 1.0598x over previous
//
#include <hip/hip_runtime.h>
#include <hip/hip_bf16.h>

// HumanVAttention: QKV proj -> K-rope + V transpose -> GQA block-sparse attn (Q-rope fused) -> out proj
// B=1 S=4096 HID=2048 NH=16 NKV=4 HD=128 BLK=64 LOCAL=4 GNB=2 STRIDE=4 ROT=64

typedef short short8 __attribute__((ext_vector_type(8)));
typedef float f32x4  __attribute__((ext_vector_type(4)));

#define NEGV   (-1.0e9f)
#define SCALE  (0.08838834764831845f)

__device__ __forceinline__ void gload16(const void* g, void* l) {
  __builtin_amdgcn_global_load_lds(
      (const __attribute__((address_space(1))) unsigned int*)g,
      (__attribute__((address_space(3))) unsigned int*)l, 16, 0, 0);
}

__device__ __forceinline__ float bf2f(short s) {
  union { unsigned u; float f; } c;
  c.u = ((unsigned)(unsigned short)s) << 16;
  return c.f;
}

__device__ __forceinline__ short f2bf_s(float f) {
  __hip_bfloat16 b = __float2bfloat16(f);
  short s;
  __builtin_memcpy(&s, &b, 2);
  return s;
}

// ---------------- fused prep: hidden f32->bf16 convert + 4 weight transposes (R10-verified) ----------------
__global__ void prep_all(const float* __restrict__ H, const float* __restrict__ Wq,
                         const float* __restrict__ Wk, const float* __restrict__ Wv,
                         const float* __restrict__ Wo, __hip_bfloat16* __restrict__ X,
                         __hip_bfloat16* __restrict__ Wt, __hip_bfloat16* __restrict__ Wot) {
  __shared__ __hip_bfloat16 tile[64][73];
  int b = blockIdx.x;
  if (b < 8192) {
    size_t t = (size_t)b * 256 + threadIdx.x;
    float4 v = *(const float4*)(H + t * 4);
    __hip_bfloat16* o = X + t * 4;
    o[0] = __float2bfloat16(v.x); o[1] = __float2bfloat16(v.y);
    o[2] = __float2bfloat16(v.z); o[3] = __float2bfloat16(v.w);
    return;
  }
  const float* src; __hip_bfloat16* dst; int C; int idx;
  if (b < 9216)      { src = Wq; dst = Wt;                          C = 2048; idx = b - 8192; }
  else if (b < 9472) { src = Wk; dst = Wt + (size_t)2048 * 2048;    C = 512;  idx = b - 9216; }
  else if (b < 9728) { src = Wv; dst = Wt + (size_t)2560 * 2048;    C = 512;  idx = b - 9472; }
  else               { src = Wo; dst = Wot;                         C = 2048; idx = b - 9728; }
  int r0 = (idx & 31) * 64, c0 = (idx >> 5) * 64;
  int c = threadIdx.x & 63, rq = threadIdx.x >> 6;
#pragma unroll
  for (int i = 0; i < 16; ++i) {
    int r = i * 4 + rq;
    tile[r][c] = __float2bfloat16(src[(size_t)(r0 + r) * C + c0 + c]);
  }
  __syncthreads();
#pragma unroll
  for (int i = 0; i < 16; ++i) {
    int cc = i * 4 + rq;
    dst[(size_t)(c0 + cc) * 2048 + r0 + c] = tile[c][cc];
  }
}

// ---------------- postproc: in-place K-rope + V transpose (Q-rope moved into attn) ----------------
// blocks [0,256): K rope; [256,768): transpose Vb[4096][512] -> Vt[512][4096]
__global__ void postproc(const float* __restrict__ cosb, const float* __restrict__ sinb,
                         __hip_bfloat16* __restrict__ Kb,
                         const __hip_bfloat16* __restrict__ Vb, __hip_bfloat16* __restrict__ Vt) {
  __shared__ __hip_bfloat16 tile[64][73];
  int blk = blockIdx.x;
  if (blk < 256) {
    int tk = blk * 256 + threadIdx.x;       // [0, 65536): 4096 s x 4 h x 4 g
    int s = tk >> 4;
    int rem = tk & 15;
    __hip_bfloat16* p = Kb + (size_t)s * 512 + (rem >> 2) * 128 + (rem & 3) * 8;
    const int g8 = (tk & 3) * 8;            // d offset in [0,32)
    const float* cp = cosb + (size_t)s * 64 + g8;
    const float* sp = sinb + (size_t)s * 64 + g8;
    short8 a = *(const short8*)p;           // x[d],    d in [0,32)
    short8 b = *(const short8*)(p + 32);    // x[d+32]
    float ca[8], sa[8], cb[8], sb[8];
    *(float4*)&ca[0] = *(const float4*)cp;        *(float4*)&ca[4] = *(const float4*)(cp + 4);
    *(float4*)&cb[0] = *(const float4*)(cp + 32); *(float4*)&cb[4] = *(const float4*)(cp + 36);
    *(float4*)&sa[0] = *(const float4*)sp;        *(float4*)&sa[4] = *(const float4*)(sp + 4);
    *(float4*)&sb[0] = *(const float4*)(sp + 32); *(float4*)&sb[4] = *(const float4*)(sp + 36);
    short8 oa, ob;
#pragma unroll
    for (int i = 0; i < 8; ++i) {
      float av = bf2f(a[i]), bv = bf2f(b[i]);
      oa[i] = f2bf_s(av * ca[i] - bv * sa[i]);   // rot_half: d<32 -> -x[d+32]
      ob[i] = f2bf_s(bv * cb[i] + av * sb[i]);   // d>=32   -> +x[d-32]
    }
    *(short8*)p = oa;
    *(short8*)(p + 32) = ob;
    return;
  }
  int idx = blk - 256;                      // 512 blocks: 64 x 8
  int s0 = (idx & 63) * 64, c0 = (idx >> 6) * 64;
  int c = threadIdx.x & 63, rq = threadIdx.x >> 6;
#pragma unroll
  for (int i = 0; i < 16; ++i) {
    int r = i * 4 + rq;
    tile[r][c] = Vb[(size_t)(s0 + r) * 512 + c0 + c];
  }
  __syncthreads();
#pragma unroll
  for (int i = 0; i < 16; ++i) {
    int cc = i * 4 + rq;
    Vt[(size_t)(c0 + cc) * 4096 + s0 + c] = tile[c][cc];
  }
}

// ---------------- GEMM1: 256x256 tile, pipelined 4-phase (R10-verified, 62.3 us) ----------------
__global__ __launch_bounds__(512, 2) void gemm_qkv4p(
    const __hip_bfloat16* __restrict__ A, const __hip_bfloat16* __restrict__ Bt,
    __hip_bfloat16* __restrict__ Qb, __hip_bfloat16* __restrict__ Kb,
    __hip_bfloat16* __restrict__ Vb) {
  const int K = 2048;
  const int tid = threadIdx.x;
  const int wave = tid >> 6, lane = tid & 63;
  const int l15 = lane & 15, lg = lane >> 4;
  const int bm = blockIdx.x, bn = blockIdx.y;
  const int wm = wave >> 2, wn = wave & 3;

  __shared__ __hip_bfloat16 lds[65536];

  f32x4 acc[8][4] = {};
  const int srow = lane >> 3;
  const int sslot = lane & 7;
  const int scol = (sslot ^ srow) * 8;
  const size_t abase = (size_t)bm * 256 * K;
  const size_t bbase = (size_t)bn * 256 * K;
  const int r3 = l15 & 7;

#define STAGE_HALF(SRC, SBASE, HALF, KO, LBASE)                                  \
  {                                                                              \
    _Pragma("unroll")                                                            \
    for (int l = 0; l < 2; ++l) {                                                \
      int chunk = l * 8 + wave;                                                  \
      int row = chunk * 8 + srow;                                                \
      gload16(SRC + (SBASE) + (size_t)((HALF) * 128 + row) * K + (KO) + scol,    \
              &lds[(LBASE) + chunk * 512]);                                      \
    }                                                                            \
  }

  short8 bfr[4][2];
  short8 af[2][2][2];

#define READ_AF(P, Q, BA)                                                        \
  {                                                                              \
    _Pragma("unroll")                                                            \
    for (int m2 = 0; m2 < 2; ++m2)                                               \
      _Pragma("unroll")                                                          \
      for (int ks = 0; ks < 2; ++ks) {                                           \
        int row = ((Q) * 2 + m2) * 16 + l15;                                     \
        int slot = (ks * 4 + lg) ^ r3;                                           \
        af[P][m2][ks] = *(const short8*)&lds[(BA) + row * 64 + slot * 8];        \
      }                                                                          \
  }

#define READ_BF(BB)                                                              \
  {                                                                              \
    _Pragma("unroll")                                                            \
    for (int ni = 0; ni < 4; ++ni)                                               \
      _Pragma("unroll")                                                          \
      for (int ks = 0; ks < 2; ++ks) {                                           \
        int row = (wn & 1) * 64 + ni * 16 + l15;                                 \
        int slot = (ks * 4 + lg) ^ r3;                                           \
        bfr[ni][ks] = *(const short8*)&lds[(BB) + row * 64 + slot * 8];          \
      }                                                                          \
  }

#define MFMA_Q(Q, P)                                                             \
  {                                                                              \
    __builtin_amdgcn_s_setprio(1);                                               \
    _Pragma("unroll")                                                            \
    for (int ks = 0; ks < 2; ++ks)                                               \
      _Pragma("unroll")                                                          \
      for (int m2 = 0; m2 < 2; ++m2)                                             \
        _Pragma("unroll")                                                        \
        for (int ni = 0; ni < 4; ++ni)                                           \
          acc[(Q) * 2 + m2][ni] = __builtin_amdgcn_mfma_f32_16x16x32_bf16(       \
              af[P][m2][ks], bfr[ni][ks], acc[(Q) * 2 + m2][ni], 0, 0, 0);       \
    __builtin_amdgcn_s_setprio(0);                                               \
  }

#define LGKM0()                                                                  \
  asm volatile("s_waitcnt lgkmcnt(0)" ::: "memory");                             \
  __builtin_amdgcn_sched_barrier(0);

  STAGE_HALF(Bt, bbase, 0, 0, 16384);
  STAGE_HALF(Bt, bbase, 1, 0, 24576);
  STAGE_HALF(A, abase, 0, 0, 0);
  STAGE_HALF(A, abase, 1, 0, 8192);
  STAGE_HALF(Bt, bbase, 0, 64, 49152);
  STAGE_HALF(Bt, bbase, 1, 64, 57344);
  asm volatile("s_waitcnt vmcnt(4)" ::: "memory");
  __builtin_amdgcn_sched_barrier(0);
  __builtin_amdgcn_s_barrier();
  {
    const int bA0 = wm * 8192;
    const int bB0 = 16384 + (wn >> 1) * 8192;
    READ_BF(bB0);
    READ_AF(0, 0, bA0);
  }
  LGKM0();

  for (int t = 0; t < 32; ++t) {
    const int buf = (t & 1) * 32768;
    const int nbuf = buf ^ 32768;
    const int bA = buf + wm * 8192;
    if (t + 1 < 32) STAGE_HALF(A, abase, 0, (t + 1) * 64, nbuf);
    __builtin_amdgcn_s_barrier();
    MFMA_Q(0, 0);
    READ_AF(1, 1, bA);
    LGKM0();
    if (t + 1 < 32) STAGE_HALF(A, abase, 1, (t + 1) * 64, nbuf + 8192);
    __builtin_amdgcn_s_barrier();
    MFMA_Q(1, 1);
    READ_AF(0, 2, bA);
    LGKM0();
    if (t + 2 < 32) STAGE_HALF(Bt, bbase, 0, (t + 2) * 64, buf + 16384);
    __builtin_amdgcn_s_barrier();
    MFMA_Q(2, 0);
    READ_AF(1, 3, bA);
    LGKM0();
    if (t + 2 < 32) STAGE_HALF(Bt, bbase, 1, (t + 2) * 64, buf + 24576);
    if (t < 30) asm volatile("s_waitcnt vmcnt(4)" ::: "memory");
    else        asm volatile("s_waitcnt vmcnt(0)" ::: "memory");
    __builtin_amdgcn_sched_barrier(0);
    __builtin_amdgcn_s_barrier();
    MFMA_Q(3, 1);
    if (t + 1 < 32) {
      const int nbA = nbuf + wm * 8192;
      const int nbB = nbuf + 16384 + (wn >> 1) * 8192;
      READ_BF(nbB);
      READ_AF(0, 0, nbA);
    }
    LGKM0();
  }
#undef STAGE_HALF
#undef READ_AF
#undef READ_BF
#undef MFMA_Q
#undef LGKM0

  __hip_bfloat16* dst; int ldc, coff;
  if (bn < 8)       { dst = Qb; ldc = 2048; coff = bn * 256; }
  else if (bn < 10) { dst = Kb; ldc = 512;  coff = bn * 256 - 2048; }
  else              { dst = Vb; ldc = 512;  coff = bn * 256 - 2560; }
#pragma unroll
  for (int m8 = 0; m8 < 8; ++m8)
#pragma unroll
    for (int ni = 0; ni < 4; ++ni) {
      int row = bm * 256 + wm * 128 + m8 * 16 + lg * 4;
      int col = coff + wn * 64 + ni * 16 + l15;
#pragma unroll
      for (int r = 0; r < 4; ++r)
        dst[(size_t)(row + r) * ldc + col] = __float2bfloat16(acc[m8][ni][r]);
    }
}

// ---------------- GEMM2: C[M][N] f32 = A[M][K] bf16 . Bt[N][K]^T bf16 (verified 128^2) ----------------
__global__ __launch_bounds__(256) void gemm_bt(
    const __hip_bfloat16* __restrict__ A, const __hip_bfloat16* __restrict__ Bt,
    float* __restrict__ C, int M, int N, int K) {
  const int tid = threadIdx.x;
  const int wave = tid >> 6, lane = tid & 63;
  const int l15 = lane & 15, lg = lane >> 4;
  const int bm = blockIdx.x, bn = blockIdx.y;
  const int wm = wave >> 1, wn = wave & 1;

  __shared__ __hip_bfloat16 As[128 * 64];
  __shared__ __hip_bfloat16 Bs[128 * 64];

  f32x4 acc[4][4] = {};
  const int lrow = lane >> 3;
  const int lslot = lane & 7;
  const int scol = (lslot ^ lrow) * 8;
  const size_t abase = (size_t)bm * 128 * K;
  const size_t bbase = (size_t)bn * 128 * K;
  const int r3 = l15 & 7;

  for (int k0 = 0; k0 < K; k0 += 64) {
#pragma unroll
    for (int i = 0; i < 4; ++i) {
      int seg = i * 4 + wave;
      int row = seg * 8 + lrow;
      gload16(A + abase + (size_t)row * K + k0 + scol, &As[seg * 512]);
      gload16(Bt + bbase + (size_t)row * K + k0 + scol, &Bs[seg * 512]);
    }
    __syncthreads();
#pragma unroll
    for (int ks = 0; ks < 2; ++ks) {
      const int slot = (ks * 4 + lg) ^ r3;
      short8 af[4], bf[4];
#pragma unroll
      for (int mi = 0; mi < 4; ++mi)
        af[mi] = *(const short8*)&As[(wm * 64 + mi * 16 + l15) * 64 + slot * 8];
#pragma unroll
      for (int ni = 0; ni < 4; ++ni)
        bf[ni] = *(const short8*)&Bs[(wn * 64 + ni * 16 + l15) * 64 + slot * 8];
#pragma unroll
      for (int mi = 0; mi < 4; ++mi)
#pragma unroll
        for (int ni = 0; ni < 4; ++ni)
          acc[mi][ni] = __builtin_amdgcn_mfma_f32_16x16x32_bf16(af[mi], bf[ni], acc[mi][ni], 0, 0, 0);
    }
    __syncthreads();
  }
#pragma unroll
  for (int mi = 0; mi < 4; ++mi)
#pragma unroll
    for (int ni = 0; ni < 4; ++ni) {
      int row = bm * 128 + wm * 64 + mi * 16 + lg * 4;
      int col = bn * 128 + wn * 64 + ni * 16 + l15;
#pragma unroll
      for (int r = 0; r < 4; ++r)
        C[(size_t)(row + r) * N + col] = acc[mi][ni][r];
    }
}

// ---------------- block-sparse attention: one block per (bi, kvh), 8 waves (R10-verified)
// + fused Q-rope: qf[0]/qf[1] hold the (d, d+32) pair in the same thread/slot; rope math
// identical to the R6-verified rope_inplace (cos/sin rows L2-resident, prologue-only regs).
__global__ __launch_bounds__(512, 2) void attn_kernel(
    const __hip_bfloat16* __restrict__ Qb,  // [4096][2048]  (un-roped)
    const __hip_bfloat16* __restrict__ Kb,  // [4096][512]   (roped by postproc)
    const __hip_bfloat16* __restrict__ Vt,  // [512][4096]   (channel-major)
    const float* __restrict__ cosb, const float* __restrict__ sinb,
    const float* __restrict__ amask,        // [4096]
    __hip_bfloat16* __restrict__ AO)        // [4096][2048]
{
  const int bid = blockIdx.x;
  const int kvh = bid & 3;
  const int bi  = bid >> 2;
  const int tid = threadIdx.x;
  const int wave = tid >> 6, lane = tid & 63;
  const int l15 = lane & 15, lg = lane >> 4;
  const int h  = kvh * 4 + (wave >> 1);
  const int rh = wave & 1;
  const int q0 = bi * 64 + rh * 32;

  int sel[6]; int nsel = 0;
  {
    int gtop = bi >> 2;
    for (int j = 0; j <= bi; ++j) {
      bool pick = (j == 0) || (j >= bi - 3) || (((j & 3) == 0) && ((j >> 2) >= gtop - 1));
      if (pick && nsel < 6) sel[nsel++] = j;
    }
  }

  __shared__ __hip_bfloat16 kv[2][16384];  // per buf: K [64][128] at 0, V [128][64] at 8192
  __shared__ __hip_bfloat16 Pl[8][2304];   // per wave: P [32][72]

  short8 qf[2][4];
#pragma unroll
  for (int mi = 0; mi < 2; ++mi) {
    const int s_ = q0 + mi * 16 + l15;
    const __hip_bfloat16* qrow = Qb + (size_t)s_ * 2048 + h * 128;
#pragma unroll
    for (int ks = 0; ks < 4; ++ks)
      qf[mi][ks] = *(const short8*)(qrow + ks * 32 + lg * 8);
    // fused partial RoPE on head-d < 64: a = qf[0] (d = lg*8+i), b = qf[1] (d+32)
    const float* cp = cosb + (size_t)s_ * 64 + lg * 8;
    const float* sp = sinb + (size_t)s_ * 64 + lg * 8;
    float ca[8], sa[8], cb[8], sb[8];
    *(float4*)&ca[0] = *(const float4*)cp;        *(float4*)&ca[4] = *(const float4*)(cp + 4);
    *(float4*)&cb[0] = *(const float4*)(cp + 32); *(float4*)&cb[4] = *(const float4*)(cp + 36);
    *(float4*)&sa[0] = *(const float4*)sp;        *(float4*)&sa[4] = *(const float4*)(sp + 4);
    *(float4*)&sb[0] = *(const float4*)(sp + 32); *(float4*)&sb[4] = *(const float4*)(sp + 36);
    short8 a = qf[mi][0], b = qf[mi][1], oa, ob;
#pragma unroll
    for (int i = 0; i < 8; ++i) {
      float av = bf2f(a[i]), bv = bf2f(b[i]);
      oa[i] = f2bf_s(av * ca[i] - bv * sa[i]);   // d<32:  -x[d+32]*sin
      ob[i] = f2bf_s(bv * cb[i] + av * sb[i]);   // d>=32: +x[d-32]*sin
    }
    qf[mi][0] = oa;
    qf[mi][1] = ob;
  }

  float m[2][4], l[2][4];
  f32x4 oacc[2][8] = {};
#pragma unroll
  for (int mi = 0; mi < 2; ++mi)
#pragma unroll
    for (int r = 0; r < 4; ++r) { m[mi][r] = -3.0e38f; l[mi][r] = 0.f; }

#define STAGE_KV(KB, BUF)                                                          \
  {                                                                                \
    _Pragma("unroll")                                                              \
    for (int i = 0; i < 2; ++i) {                                                  \
      int chunk = (i * 8 + wave) * 64 + lane;                                      \
      int row = chunk >> 4, slot = chunk & 15;                                     \
      gload16(Kb + (size_t)((KB) * 64 + row) * 512 + kvh * 128 +                   \
                  ((slot ^ (row & 15)) * 8),                                       \
              &kv[BUF][(i * 8 + wave) * 512]);                                     \
    }                                                                              \
    _Pragma("unroll")                                                              \
    for (int i = 0; i < 2; ++i) {                                                  \
      int chunk = (i * 8 + wave) * 64 + lane;                                      \
      int row = chunk >> 3, slot = chunk & 7;                                      \
      gload16(Vt + (size_t)(kvh * 128 + row) * 4096 + (KB) * 64 +                  \
                  ((slot ^ (row & 7)) * 8),                                        \
              &kv[BUF][8192 + (i * 8 + wave) * 512]);                              \
    }                                                                              \
  }

  STAGE_KV(sel[0], 0);

#pragma unroll
  for (int j = 0; j < 6; ++j) {
    if (j < nsel) {
      const int kb = sel[j];
      if (j + 1 < nsel) {
        STAGE_KV(sel[j + 1], (j + 1) & 1);
        asm volatile("s_waitcnt vmcnt(4)" ::: "memory");
      } else {
        asm volatile("s_waitcnt vmcnt(0)" ::: "memory");
      }
      __builtin_amdgcn_sched_barrier(0);
      __builtin_amdgcn_s_barrier();
      const __hip_bfloat16* kbuf = kv[j & 1];

      f32x4 sc[2][4] = {};
#pragma unroll
      for (int nf = 0; nf < 4; ++nf)
#pragma unroll
        for (int ks = 0; ks < 4; ++ks) {
          short8 b = *(const short8*)&kbuf[(nf * 16 + l15) * 128 +
                                           (((ks * 4 + lg) ^ l15) * 8)];
          sc[0][nf] = __builtin_amdgcn_mfma_f32_16x16x32_bf16(qf[0][ks], b, sc[0][nf], 0, 0, 0);
          sc[1][nf] = __builtin_amdgcn_mfma_f32_16x16x32_bf16(qf[1][ks], b, sc[1][nf], 0, 0, 0);
        }

      float am[4];
#pragma unroll
      for (int nf = 0; nf < 4; ++nf)
        am[nf] = (1.0f - amask[kb * 64 + nf * 16 + l15]) * NEGV;
#pragma unroll
      for (int mi = 0; mi < 2; ++mi)
#pragma unroll
        for (int nf = 0; nf < 4; ++nf) {
          int keyl = nf * 16 + l15;
#pragma unroll
          for (int r = 0; r < 4; ++r) {
            float s = sc[mi][nf][r] * SCALE + am[nf];
            if (kb == bi) {
              int qrow = rh * 32 + mi * 16 + lg * 4 + r;
              if (keyl > qrow) s = NEGV;
            }
            sc[mi][nf][r] = s;
          }
        }

      float pm[2][4];
#pragma unroll
      for (int mi = 0; mi < 2; ++mi)
#pragma unroll
        for (int r = 0; r < 4; ++r) {
          float v = fmaxf(fmaxf(sc[mi][0][r], sc[mi][1][r]),
                          fmaxf(sc[mi][2][r], sc[mi][3][r]));
          v = fmaxf(v, __shfl_xor(v, 1)); v = fmaxf(v, __shfl_xor(v, 2));
          v = fmaxf(v, __shfl_xor(v, 4)); v = fmaxf(v, __shfl_xor(v, 8));
          pm[mi][r] = v;
        }

      bool need = false;
#pragma unroll
      for (int mi = 0; mi < 2; ++mi)
#pragma unroll
        for (int r = 0; r < 4; ++r) need |= (pm[mi][r] - m[mi][r] > 8.0f);
      if (__any(need)) {
#pragma unroll
        for (int mi = 0; mi < 2; ++mi)
#pragma unroll
          for (int r = 0; r < 4; ++r) {
            float mn = fmaxf(m[mi][r], pm[mi][r]);
            float scl = __expf(m[mi][r] - mn);
            l[mi][r] *= scl;
#pragma unroll
            for (int df = 0; df < 8; ++df) oacc[mi][df][r] *= scl;
            m[mi][r] = mn;
          }
      }

#pragma unroll
      for (int mi = 0; mi < 2; ++mi)
#pragma unroll
        for (int r = 0; r < 4; ++r) {
          float rs = 0.f;
#pragma unroll
          for (int nf = 0; nf < 4; ++nf) {
            float p = __expf(sc[mi][nf][r] - m[mi][r]);
            rs += p;
            Pl[wave][(mi * 16 + lg * 4 + r) * 72 + nf * 16 + l15] = __float2bfloat16(p);
          }
          rs += __shfl_xor(rs, 1); rs += __shfl_xor(rs, 2);
          rs += __shfl_xor(rs, 4); rs += __shfl_xor(rs, 8);
          l[mi][r] += rs;
        }

      short8 af2[2][2];
#pragma unroll
      for (int mi = 0; mi < 2; ++mi)
#pragma unroll
        for (int ks = 0; ks < 2; ++ks)
          af2[mi][ks] = *(const short8*)&Pl[wave][(mi * 16 + l15) * 72 + ks * 32 + lg * 8];
#pragma unroll
      for (int df = 0; df < 8; ++df)
#pragma unroll
        for (int ks = 0; ks < 2; ++ks) {
          short8 vb = *(const short8*)&kbuf[8192 + (df * 16 + l15) * 64 +
                                            (((ks * 4 + lg) ^ (l15 & 7)) * 8)];
          oacc[0][df] = __builtin_amdgcn_mfma_f32_16x16x32_bf16(af2[0][ks], vb, oacc[0][df], 0, 0, 0);
          oacc[1][df] = __builtin_amdgcn_mfma_f32_16x16x32_bf16(af2[1][ks], vb, oacc[1][df], 0, 0, 0);
        }
      __builtin_amdgcn_s_barrier();
    }
  }
#undef STAGE_KV

#pragma unroll
  for (int mi = 0; mi < 2; ++mi) {
    float inv[4];
#pragma unroll
    for (int r = 0; r < 4; ++r) inv[r] = 1.0f / l[mi][r];
#pragma unroll
    for (int df = 0; df < 8; ++df)
#pragma unroll
      for (int r = 0; r < 4; ++r) {
        int qrow = q0 + mi * 16 + lg * 4 + r;
        AO[(size_t)qrow * 2048 + h * 128 + df * 16 + l15] =
            __float2bfloat16(oacc[mi][df][r] * inv[r]);
      }
  }
}

// ---------------- launch ----------------
extern "C" void kernel_launch(void* const* d_in, const int* in_sizes, int n_in,
                              void* d_out, int out_size, void* d_ws, size_t ws_size,
                              hipStream_t stream) {
  const float* hidden = (const float*)d_in[0];
  const float* cosb   = (const float*)d_in[1];
  const float* sinb   = (const float*)d_in[2];
  const float* Wq     = (const float*)d_in[3];
  const float* Wk     = (const float*)d_in[4];
  const float* Wv     = (const float*)d_in[5];
  const float* Wo     = (const float*)d_in[6];
  const float* amask  = (const float*)d_in[7];

  char* ws = (char*)d_ws;
  __hip_bfloat16* Xb   = (__hip_bfloat16*)(ws);               // 16,777,216 B  [4096][2048]
  __hip_bfloat16* Wt   = (__hip_bfloat16*)(ws + 16777216);    // 12,582,912 B  [3072][2048]
  __hip_bfloat16* Wot  = (__hip_bfloat16*)(ws + 29360128);    //  8,388,608 B  [2048][2048]
  __hip_bfloat16* Qb   = (__hip_bfloat16*)(ws + 37748736);    // 16,777,216 B  [4096][2048]
  __hip_bfloat16* Kb   = (__hip_bfloat16*)(ws + 54525952);    //  4,194,304 B  [4096][512]
  __hip_bfloat16* Vb   = (__hip_bfloat16*)(ws + 58720256);    //  4,194,304 B  [4096][512]
  __hip_bfloat16* Vt   = (__hip_bfloat16*)(ws + 62914560);    //  4,194,304 B  [512][4096]
  __hip_bfloat16* AO   = Xb;  // Xb dead after gemm_qkv4p; reuse for attention output

  prep_all<<<10752, 256, 0, stream>>>(hidden, Wq, Wk, Wv, Wo, Xb, Wt, Wot);

  gemm_qkv4p<<<dim3(16, 12), 512, 0, stream>>>(Xb, Wt, Qb, Kb, Vb);

  postproc<<<768, 256, 0, stream>>>(cosb, sinb, Kb, Vb, Vt);

  attn_kernel<<<256, 512, 0, stream>>>(Qb, Kb, Vt, cosb, sinb, amask, AO);

  gemm_bt<<<dim3(32, 16), 256, 0, stream>>>(AO, Wot, (float*)d_out, 4096, 2048, 2048);
}

// Round 14
// 165.215 us; speedup vs baseline: 1.1043x; 1.0001x over previous
//
#include <hip/hip_runtime.h>
#include <hip/hip_bf16.h>

// HumanVAttention: QKV proj -> K-rope + V transpose -> GQA block-sparse attn (Q-rope fused) -> out proj
// B=1 S=4096 HID=2048 NH=16 NKV=4 HD=128 BLK=64 LOCAL=4 GNB=2 STRIDE=4 ROT=64

typedef short short8 __attribute__((ext_vector_type(8)));
typedef float f32x4  __attribute__((ext_vector_type(4)));

#define NEGV   (-1.0e9f)
#define SCALE  (0.08838834764831845f)

__device__ __forceinline__ void gload16(const void* g, void* l) {
  __builtin_amdgcn_global_load_lds(
      (const __attribute__((address_space(1))) unsigned int*)g,
      (__attribute__((address_space(3))) unsigned int*)l, 16, 0, 0);
}

__device__ __forceinline__ float bf2f(short s) {
  union { unsigned u; float f; } c;
  c.u = ((unsigned)(unsigned short)s) << 16;
  return c.f;
}

__device__ __forceinline__ short f2bf_s(float f) {
  __hip_bfloat16 b = __float2bfloat16(f);
  short s;
  __builtin_memcpy(&s, &b, 2);
  return s;
}

// ---------------- fused prep: hidden f32->bf16 convert + 4 weight transposes ----------------
// Vectorized (G13): conv = 32B read / 16B write per thread; transpose = float4 reads,
// LDS 64x64 tile, short8 (16B) writes. Grid 6656 = 4096 conv + 1024 Wq + 256 Wk + 256 Wv + 1024 Wo.
__global__ void prep_all(const float* __restrict__ H, const float* __restrict__ Wq,
                         const float* __restrict__ Wk, const float* __restrict__ Wv,
                         const float* __restrict__ Wo, __hip_bfloat16* __restrict__ X,
                         __hip_bfloat16* __restrict__ Wt, __hip_bfloat16* __restrict__ Wot) {
  __shared__ short tile[64][73];
  const int b = blockIdx.x;
  const int tid = threadIdx.x;
  if (b < 4096) {                           // conv hidden: 8 floats -> 8 bf16 per thread
    size_t t = (size_t)b * 256 + tid;
    const float* hp = H + t * 8;
    float4 v0 = *(const float4*)hp;
    float4 v1 = *(const float4*)(hp + 4);
    short8 o;
    o[0] = f2bf_s(v0.x); o[1] = f2bf_s(v0.y); o[2] = f2bf_s(v0.z); o[3] = f2bf_s(v0.w);
    o[4] = f2bf_s(v1.x); o[5] = f2bf_s(v1.y); o[6] = f2bf_s(v1.z); o[7] = f2bf_s(v1.w);
    *(short8*)&X[t * 8] = o;
    return;
  }
  const float* src; __hip_bfloat16* dst; int C; int idx;
  int q = b - 4096;
  if (q < 1024)      { src = Wq; dst = Wt;                       C = 2048; idx = q; }
  else if (q < 1280) { src = Wk; dst = Wt + (size_t)2048 * 2048; C = 512;  idx = q - 1024; }
  else if (q < 1536) { src = Wv; dst = Wt + (size_t)2560 * 2048; C = 512;  idx = q - 1280; }
  else               { src = Wo; dst = Wot;                      C = 2048; idx = q - 1536; }
  const int r0 = (idx & 31) * 64, c0 = (idx >> 5) * 64;
  // read: float4 per iteration (16B/lane), 4 rows per thread
  const int c4 = (tid & 15) * 4, rb = tid >> 4;
#pragma unroll
  for (int j = 0; j < 4; ++j) {
    int r = rb + j * 16;
    float4 v = *(const float4*)(src + (size_t)(r0 + r) * C + c0 + c4);
    tile[r][c4 + 0] = f2bf_s(v.x);
    tile[r][c4 + 1] = f2bf_s(v.y);
    tile[r][c4 + 2] = f2bf_s(v.z);
    tile[r][c4 + 3] = f2bf_s(v.w);
  }
  __syncthreads();
  // write: short8 (16B/lane), gather transposed from LDS
  const int cs = (tid & 7) * 8;
#pragma unroll
  for (int it = 0; it < 2; ++it) {
    int cc = (tid >> 3) + it * 32;
    short8 o;
#pragma unroll
    for (int i = 0; i < 8; ++i) o[i] = tile[cs + i][cc];
    *(short8*)&dst[(size_t)(c0 + cc) * 2048 + r0 + cs] = o;
  }
}

// ---------------- postproc: in-place K-rope + V transpose (R13-verified) ----------------
// blocks [0,256): K rope; [256,768): transpose Vb[4096][512] -> Vt[512][4096]
__global__ void postproc(const float* __restrict__ cosb, const float* __restrict__ sinb,
                         __hip_bfloat16* __restrict__ Kb,
                         const __hip_bfloat16* __restrict__ Vb, __hip_bfloat16* __restrict__ Vt) {
  __shared__ __hip_bfloat16 tile[64][73];
  int blk = blockIdx.x;
  if (blk < 256) {
    int tk = blk * 256 + threadIdx.x;       // [0, 65536): 4096 s x 4 h x 4 g
    int s = tk >> 4;
    int rem = tk & 15;
    __hip_bfloat16* p = Kb + (size_t)s * 512 + (rem >> 2) * 128 + (rem & 3) * 8;
    const int g8 = (tk & 3) * 8;            // d offset in [0,32)
    const float* cp = cosb + (size_t)s * 64 + g8;
    const float* sp = sinb + (size_t)s * 64 + g8;
    short8 a = *(const short8*)p;           // x[d],    d in [0,32)
    short8 b = *(const short8*)(p + 32);    // x[d+32]
    float ca[8], sa[8], cb[8], sb[8];
    *(float4*)&ca[0] = *(const float4*)cp;        *(float4*)&ca[4] = *(const float4*)(cp + 4);
    *(float4*)&cb[0] = *(const float4*)(cp + 32); *(float4*)&cb[4] = *(const float4*)(cp + 36);
    *(float4*)&sa[0] = *(const float4*)sp;        *(float4*)&sa[4] = *(const float4*)(sp + 4);
    *(float4*)&sb[0] = *(const float4*)(sp + 32); *(float4*)&sb[4] = *(const float4*)(sp + 36);
    short8 oa, ob;
#pragma unroll
    for (int i = 0; i < 8; ++i) {
      float av = bf2f(a[i]), bv = bf2f(b[i]);
      oa[i] = f2bf_s(av * ca[i] - bv * sa[i]);   // rot_half: d<32 -> -x[d+32]
      ob[i] = f2bf_s(bv * cb[i] + av * sb[i]);   // d>=32   -> +x[d-32]
    }
    *(short8*)p = oa;
    *(short8*)(p + 32) = ob;
    return;
  }
  int idx = blk - 256;                      // 512 blocks: 64 x 8
  int s0 = (idx & 63) * 64, c0 = (idx >> 6) * 64;
  int c = threadIdx.x & 63, rq = threadIdx.x >> 6;
#pragma unroll
  for (int i = 0; i < 16; ++i) {
    int r = i * 4 + rq;
    tile[r][c] = Vb[(size_t)(s0 + r) * 512 + c0 + c];
  }
  __syncthreads();
#pragma unroll
  for (int i = 0; i < 16; ++i) {
    int cc = i * 4 + rq;
    Vt[(size_t)(c0 + cc) * 4096 + s0 + c] = tile[c][cc];
  }
}

// ---------------- GEMM1: 256x256 tile, pipelined 4-phase (R10-verified, 62.3 us) ----------------
__global__ __launch_bounds__(512, 2) void gemm_qkv4p(
    const __hip_bfloat16* __restrict__ A, const __hip_bfloat16* __restrict__ Bt,
    __hip_bfloat16* __restrict__ Qb, __hip_bfloat16* __restrict__ Kb,
    __hip_bfloat16* __restrict__ Vb) {
  const int K = 2048;
  const int tid = threadIdx.x;
  const int wave = tid >> 6, lane = tid & 63;
  const int l15 = lane & 15, lg = lane >> 4;
  const int bm = blockIdx.x, bn = blockIdx.y;
  const int wm = wave >> 2, wn = wave & 3;

  __shared__ __hip_bfloat16 lds[65536];

  f32x4 acc[8][4] = {};
  const int srow = lane >> 3;
  const int sslot = lane & 7;
  const int scol = (sslot ^ srow) * 8;
  const size_t abase = (size_t)bm * 256 * K;
  const size_t bbase = (size_t)bn * 256 * K;
  const int r3 = l15 & 7;

#define STAGE_HALF(SRC, SBASE, HALF, KO, LBASE)                                  \
  {                                                                              \
    _Pragma("unroll")                                                            \
    for (int l = 0; l < 2; ++l) {                                                \
      int chunk = l * 8 + wave;                                                  \
      int row = chunk * 8 + srow;                                                \
      gload16(SRC + (SBASE) + (size_t)((HALF) * 128 + row) * K + (KO) + scol,    \
              &lds[(LBASE) + chunk * 512]);                                      \
    }                                                                            \
  }

  short8 bfr[4][2];
  short8 af[2][2][2];

#define READ_AF(P, Q, BA)                                                        \
  {                                                                              \
    _Pragma("unroll")                                                            \
    for (int m2 = 0; m2 < 2; ++m2)                                               \
      _Pragma("unroll")                                                          \
      for (int ks = 0; ks < 2; ++ks) {                                           \
        int row = ((Q) * 2 + m2) * 16 + l15;                                     \
        int slot = (ks * 4 + lg) ^ r3;                                           \
        af[P][m2][ks] = *(const short8*)&lds[(BA) + row * 64 + slot * 8];        \
      }                                                                          \
  }

#define READ_BF(BB)                                                              \
  {                                                                              \
    _Pragma("unroll")                                                            \
    for (int ni = 0; ni < 4; ++ni)                                               \
      _Pragma("unroll")                                                          \
      for (int ks = 0; ks < 2; ++ks) {                                           \
        int row = (wn & 1) * 64 + ni * 16 + l15;                                 \
        int slot = (ks * 4 + lg) ^ r3;                                           \
        bfr[ni][ks] = *(const short8*)&lds[(BB) + row * 64 + slot * 8];          \
      }                                                                          \
  }

#define MFMA_Q(Q, P)                                                             \
  {                                                                              \
    __builtin_amdgcn_s_setprio(1);                                               \
    _Pragma("unroll")                                                            \
    for (int ks = 0; ks < 2; ++ks)                                               \
      _Pragma("unroll")                                                          \
      for (int m2 = 0; m2 < 2; ++m2)                                             \
        _Pragma("unroll")                                                        \
        for (int ni = 0; ni < 4; ++ni)                                           \
          acc[(Q) * 2 + m2][ni] = __builtin_amdgcn_mfma_f32_16x16x32_bf16(       \
              af[P][m2][ks], bfr[ni][ks], acc[(Q) * 2 + m2][ni], 0, 0, 0);       \
    __builtin_amdgcn_s_setprio(0);                                               \
  }

#define LGKM0()                                                                  \
  asm volatile("s_waitcnt lgkmcnt(0)" ::: "memory");                             \
  __builtin_amdgcn_sched_barrier(0);

  STAGE_HALF(Bt, bbase, 0, 0, 16384);
  STAGE_HALF(Bt, bbase, 1, 0, 24576);
  STAGE_HALF(A, abase, 0, 0, 0);
  STAGE_HALF(A, abase, 1, 0, 8192);
  STAGE_HALF(Bt, bbase, 0, 64, 49152);
  STAGE_HALF(Bt, bbase, 1, 64, 57344);
  asm volatile("s_waitcnt vmcnt(4)" ::: "memory");
  __builtin_amdgcn_sched_barrier(0);
  __builtin_amdgcn_s_barrier();
  {
    const int bA0 = wm * 8192;
    const int bB0 = 16384 + (wn >> 1) * 8192;
    READ_BF(bB0);
    READ_AF(0, 0, bA0);
  }
  LGKM0();

  for (int t = 0; t < 32; ++t) {
    const int buf = (t & 1) * 32768;
    const int nbuf = buf ^ 32768;
    const int bA = buf + wm * 8192;
    if (t + 1 < 32) STAGE_HALF(A, abase, 0, (t + 1) * 64, nbuf);
    __builtin_amdgcn_s_barrier();
    MFMA_Q(0, 0);
    READ_AF(1, 1, bA);
    LGKM0();
    if (t + 1 < 32) STAGE_HALF(A, abase, 1, (t + 1) * 64, nbuf + 8192);
    __builtin_amdgcn_s_barrier();
    MFMA_Q(1, 1);
    READ_AF(0, 2, bA);
    LGKM0();
    if (t + 2 < 32) STAGE_HALF(Bt, bbase, 0, (t + 2) * 64, buf + 16384);
    __builtin_amdgcn_s_barrier();
    MFMA_Q(2, 0);
    READ_AF(1, 3, bA);
    LGKM0();
    if (t + 2 < 32) STAGE_HALF(Bt, bbase, 1, (t + 2) * 64, buf + 24576);
    if (t < 30) asm volatile("s_waitcnt vmcnt(4)" ::: "memory");
    else        asm volatile("s_waitcnt vmcnt(0)" ::: "memory");
    __builtin_amdgcn_sched_barrier(0);
    __builtin_amdgcn_s_barrier();
    MFMA_Q(3, 1);
    if (t + 1 < 32) {
      const int nbA = nbuf + wm * 8192;
      const int nbB = nbuf + 16384 + (wn >> 1) * 8192;
      READ_BF(nbB);
      READ_AF(0, 0, nbA);
    }
    LGKM0();
  }
#undef STAGE_HALF
#undef READ_AF
#undef READ_BF
#undef MFMA_Q
#undef LGKM0

  __hip_bfloat16* dst; int ldc, coff;
  if (bn < 8)       { dst = Qb; ldc = 2048; coff = bn * 256; }
  else if (bn < 10) { dst = Kb; ldc = 512;  coff = bn * 256 - 2048; }
  else              { dst = Vb; ldc = 512;  coff = bn * 256 - 2560; }
#pragma unroll
  for (int m8 = 0; m8 < 8; ++m8)
#pragma unroll
    for (int ni = 0; ni < 4; ++ni) {
      int row = bm * 256 + wm * 128 + m8 * 16 + lg * 4;
      int col = coff + wn * 64 + ni * 16 + l15;
#pragma unroll
      for (int r = 0; r < 4; ++r)
        dst[(size_t)(row + r) * ldc + col] = __float2bfloat16(acc[m8][ni][r]);
    }
}

// ---------------- GEMM2: C[M][N] f32 = A[M][K] bf16 . Bt[N][K]^T bf16 (verified 128^2) ----------------
__global__ __launch_bounds__(256) void gemm_bt(
    const __hip_bfloat16* __restrict__ A, const __hip_bfloat16* __restrict__ Bt,
    float* __restrict__ C, int M, int N, int K) {
  const int tid = threadIdx.x;
  const int wave = tid >> 6, lane = tid & 63;
  const int l15 = lane & 15, lg = lane >> 4;
  const int bm = blockIdx.x, bn = blockIdx.y;
  const int wm = wave >> 1, wn = wave & 1;

  __shared__ __hip_bfloat16 As[128 * 64];
  __shared__ __hip_bfloat16 Bs[128 * 64];

  f32x4 acc[4][4] = {};
  const int lrow = lane >> 3;
  const int lslot = lane & 7;
  const int scol = (lslot ^ lrow) * 8;
  const size_t abase = (size_t)bm * 128 * K;
  const size_t bbase = (size_t)bn * 128 * K;
  const int r3 = l15 & 7;

  for (int k0 = 0; k0 < K; k0 += 64) {
#pragma unroll
    for (int i = 0; i < 4; ++i) {
      int seg = i * 4 + wave;
      int row = seg * 8 + lrow;
      gload16(A + abase + (size_t)row * K + k0 + scol, &As[seg * 512]);
      gload16(Bt + bbase + (size_t)row * K + k0 + scol, &Bs[seg * 512]);
    }
    __syncthreads();
#pragma unroll
    for (int ks = 0; ks < 2; ++ks) {
      const int slot = (ks * 4 + lg) ^ r3;
      short8 af[4], bf[4];
#pragma unroll
      for (int mi = 0; mi < 4; ++mi)
        af[mi] = *(const short8*)&As[(wm * 64 + mi * 16 + l15) * 64 + slot * 8];
#pragma unroll
      for (int ni = 0; ni < 4; ++ni)
        bf[ni] = *(const short8*)&Bs[(wn * 64 + ni * 16 + l15) * 64 + slot * 8];
#pragma unroll
      for (int mi = 0; mi < 4; ++mi)
#pragma unroll
        for (int ni = 0; ni < 4; ++ni)
          acc[mi][ni] = __builtin_amdgcn_mfma_f32_16x16x32_bf16(af[mi], bf[ni], acc[mi][ni], 0, 0, 0);
    }
    __syncthreads();
  }
#pragma unroll
  for (int mi = 0; mi < 4; ++mi)
#pragma unroll
    for (int ni = 0; ni < 4; ++ni) {
      int row = bm * 128 + wm * 64 + mi * 16 + lg * 4;
      int col = bn * 128 + wn * 64 + ni * 16 + l15;
#pragma unroll
      for (int r = 0; r < 4; ++r)
        C[(size_t)(row + r) * N + col] = acc[mi][ni][r];
    }
}

// ---------------- block-sparse attention: one block per (bi, kvh), 8 waves (R13-verified)
// with fused Q-rope in the qf prologue.
__global__ __launch_bounds__(512, 2) void attn_kernel(
    const __hip_bfloat16* __restrict__ Qb,  // [4096][2048]  (un-roped)
    const __hip_bfloat16* __restrict__ Kb,  // [4096][512]   (roped by postproc)
    const __hip_bfloat16* __restrict__ Vt,  // [512][4096]   (channel-major)
    const float* __restrict__ cosb, const float* __restrict__ sinb,
    const float* __restrict__ amask,        // [4096]
    __hip_bfloat16* __restrict__ AO)        // [4096][2048]
{
  const int bid = blockIdx.x;
  const int kvh = bid & 3;
  const int bi  = bid >> 2;
  const int tid = threadIdx.x;
  const int wave = tid >> 6, lane = tid & 63;
  const int l15 = lane & 15, lg = lane >> 4;
  const int h  = kvh * 4 + (wave >> 1);
  const int rh = wave & 1;
  const int q0 = bi * 64 + rh * 32;

  int sel[6]; int nsel = 0;
  {
    int gtop = bi >> 2;
    for (int j = 0; j <= bi; ++j) {
      bool pick = (j == 0) || (j >= bi - 3) || (((j & 3) == 0) && ((j >> 2) >= gtop - 1));
      if (pick && nsel < 6) sel[nsel++] = j;
    }
  }

  __shared__ __hip_bfloat16 kv[2][16384];  // per buf: K [64][128] at 0, V [128][64] at 8192
  __shared__ __hip_bfloat16 Pl[8][2304];   // per wave: P [32][72]

  short8 qf[2][4];
#pragma unroll
  for (int mi = 0; mi < 2; ++mi) {
    const int s_ = q0 + mi * 16 + l15;
    const __hip_bfloat16* qrow = Qb + (size_t)s_ * 2048 + h * 128;
#pragma unroll
    for (int ks = 0; ks < 4; ++ks)
      qf[mi][ks] = *(const short8*)(qrow + ks * 32 + lg * 8);
    // fused partial RoPE on head-d < 64: a = qf[0] (d = lg*8+i), b = qf[1] (d+32)
    const float* cp = cosb + (size_t)s_ * 64 + lg * 8;
    const float* sp = sinb + (size_t)s_ * 64 + lg * 8;
    float ca[8], sa[8], cb[8], sb[8];
    *(float4*)&ca[0] = *(const float4*)cp;        *(float4*)&ca[4] = *(const float4*)(cp + 4);
    *(float4*)&cb[0] = *(const float4*)(cp + 32); *(float4*)&cb[4] = *(const float4*)(cp + 36);
    *(float4*)&sa[0] = *(const float4*)sp;        *(float4*)&sa[4] = *(const float4*)(sp + 4);
    *(float4*)&sb[0] = *(const float4*)(sp + 32); *(float4*)&sb[4] = *(const float4*)(sp + 36);
    short8 a = qf[mi][0], b = qf[mi][1], oa, ob;
#pragma unroll
    for (int i = 0; i < 8; ++i) {
      float av = bf2f(a[i]), bv = bf2f(b[i]);
      oa[i] = f2bf_s(av * ca[i] - bv * sa[i]);   // d<32:  -x[d+32]*sin
      ob[i] = f2bf_s(bv * cb[i] + av * sb[i]);   // d>=32: +x[d-32]*sin
    }
    qf[mi][0] = oa;
    qf[mi][1] = ob;
  }

  float m[2][4], l[2][4];
  f32x4 oacc[2][8] = {};
#pragma unroll
  for (int mi = 0; mi < 2; ++mi)
#pragma unroll
    for (int r = 0; r < 4; ++r) { m[mi][r] = -3.0e38f; l[mi][r] = 0.f; }

#define STAGE_KV(KB, BUF)                                                          \
  {                                                                                \
    _Pragma("unroll")                                                              \
    for (int i = 0; i < 2; ++i) {                                                  \
      int chunk = (i * 8 + wave) * 64 + lane;                                      \
      int row = chunk >> 4, slot = chunk & 15;                                     \
      gload16(Kb + (size_t)((KB) * 64 + row) * 512 + kvh * 128 +                   \
                  ((slot ^ (row & 15)) * 8),                                       \
              &kv[BUF][(i * 8 + wave) * 512]);                                     \
    }                                                                              \
    _Pragma("unroll")                                                              \
    for (int i = 0; i < 2; ++i) {                                                  \
      int chunk = (i * 8 + wave) * 64 + lane;                                      \
      int row = chunk >> 3, slot = chunk & 7;                                      \
      gload16(Vt + (size_t)(kvh * 128 + row) * 4096 + (KB) * 64 +                  \
                  ((slot ^ (row & 7)) * 8),                                        \
              &kv[BUF][8192 + (i * 8 + wave) * 512]);                              \
    }                                                                              \
  }

  STAGE_KV(sel[0], 0);

#pragma unroll
  for (int j = 0; j < 6; ++j) {
    if (j < nsel) {
      const int kb = sel[j];
      if (j + 1 < nsel) {
        STAGE_KV(sel[j + 1], (j + 1) & 1);
        asm volatile("s_waitcnt vmcnt(4)" ::: "memory");
      } else {
        asm volatile("s_waitcnt vmcnt(0)" ::: "memory");
      }
      __builtin_amdgcn_sched_barrier(0);
      __builtin_amdgcn_s_barrier();
      const __hip_bfloat16* kbuf = kv[j & 1];

      f32x4 sc[2][4] = {};
#pragma unroll
      for (int nf = 0; nf < 4; ++nf)
#pragma unroll
        for (int ks = 0; ks < 4; ++ks) {
          short8 b = *(const short8*)&kbuf[(nf * 16 + l15) * 128 +
                                           (((ks * 4 + lg) ^ l15) * 8)];
          sc[0][nf] = __builtin_amdgcn_mfma_f32_16x16x32_bf16(qf[0][ks], b, sc[0][nf], 0, 0, 0);
          sc[1][nf] = __builtin_amdgcn_mfma_f32_16x16x32_bf16(qf[1][ks], b, sc[1][nf], 0, 0, 0);
        }

      float am[4];
#pragma unroll
      for (int nf = 0; nf < 4; ++nf)
        am[nf] = (1.0f - amask[kb * 64 + nf * 16 + l15]) * NEGV;
#pragma unroll
      for (int mi = 0; mi < 2; ++mi)
#pragma unroll
        for (int nf = 0; nf < 4; ++nf) {
          int keyl = nf * 16 + l15;
#pragma unroll
          for (int r = 0; r < 4; ++r) {
            float s = sc[mi][nf][r] * SCALE + am[nf];
            if (kb == bi) {
              int qrow = rh * 32 + mi * 16 + lg * 4 + r;
              if (keyl > qrow) s = NEGV;
            }
            sc[mi][nf][r] = s;
          }
        }

      float pm[2][4];
#pragma unroll
      for (int mi = 0; mi < 2; ++mi)
#pragma unroll
        for (int r = 0; r < 4; ++r) {
          float v = fmaxf(fmaxf(sc[mi][0][r], sc[mi][1][r]),
                          fmaxf(sc[mi][2][r], sc[mi][3][r]));
          v = fmaxf(v, __shfl_xor(v, 1)); v = fmaxf(v, __shfl_xor(v, 2));
          v = fmaxf(v, __shfl_xor(v, 4)); v = fmaxf(v, __shfl_xor(v, 8));
          pm[mi][r] = v;
        }

      bool need = false;
#pragma unroll
      for (int mi = 0; mi < 2; ++mi)
#pragma unroll
        for (int r = 0; r < 4; ++r) need |= (pm[mi][r] - m[mi][r] > 8.0f);
      if (__any(need)) {
#pragma unroll
        for (int mi = 0; mi < 2; ++mi)
#pragma unroll
          for (int r = 0; r < 4; ++r) {
            float mn = fmaxf(m[mi][r], pm[mi][r]);
            float scl = __expf(m[mi][r] - mn);
            l[mi][r] *= scl;
#pragma unroll
            for (int df = 0; df < 8; ++df) oacc[mi][df][r] *= scl;
            m[mi][r] = mn;
          }
      }

#pragma unroll
      for (int mi = 0; mi < 2; ++mi)
#pragma unroll
        for (int r = 0; r < 4; ++r) {
          float rs = 0.f;
#pragma unroll
          for (int nf = 0; nf < 4; ++nf) {
            float p = __expf(sc[mi][nf][r] - m[mi][r]);
            rs += p;
            Pl[wave][(mi * 16 + lg * 4 + r) * 72 + nf * 16 + l15] = __float2bfloat16(p);
          }
          rs += __shfl_xor(rs, 1); rs += __shfl_xor(rs, 2);
          rs += __shfl_xor(rs, 4); rs += __shfl_xor(rs, 8);
          l[mi][r] += rs;
        }

      short8 af2[2][2];
#pragma unroll
      for (int mi = 0; mi < 2; ++mi)
#pragma unroll
        for (int ks = 0; ks < 2; ++ks)
          af2[mi][ks] = *(const short8*)&Pl[wave][(mi * 16 + l15) * 72 + ks * 32 + lg * 8];
#pragma unroll
      for (int df = 0; df < 8; ++df)
#pragma unroll
        for (int ks = 0; ks < 2; ++ks) {
          short8 vb = *(const short8*)&kbuf[8192 + (df * 16 + l15) * 64 +
                                            (((ks * 4 + lg) ^ (l15 & 7)) * 8)];
          oacc[0][df] = __builtin_amdgcn_mfma_f32_16x16x32_bf16(af2[0][ks], vb, oacc[0][df], 0, 0, 0);
          oacc[1][df] = __builtin_amdgcn_mfma_f32_16x16x32_bf16(af2[1][ks], vb, oacc[1][df], 0, 0, 0);
        }
      __builtin_amdgcn_s_barrier();
    }
  }
#undef STAGE_KV

#pragma unroll
  for (int mi = 0; mi < 2; ++mi) {
    float inv[4];
#pragma unroll
    for (int r = 0; r < 4; ++r) inv[r] = 1.0f / l[mi][r];
#pragma unroll
    for (int df = 0; df < 8; ++df)
#pragma unroll
      for (int r = 0; r < 4; ++r) {
        int qrow = q0 + mi * 16 + lg * 4 + r;
        AO[(size_t)qrow * 2048 + h * 128 + df * 16 + l15] =
            __float2bfloat16(oacc[mi][df][r] * inv[r]);
      }
  }
}

// ---------------- launch ----------------
extern "C" void kernel_launch(void* const* d_in, const int* in_sizes, int n_in,
                              void* d_out, int out_size, void* d_ws, size_t ws_size,
                              hipStream_t stream) {
  const float* hidden = (const float*)d_in[0];
  const float* cosb   = (const float*)d_in[1];
  const float* sinb   = (const float*)d_in[2];
  const float* Wq     = (const float*)d_in[3];
  const float* Wk     = (const float*)d_in[4];
  const float* Wv     = (const float*)d_in[5];
  const float* Wo     = (const float*)d_in[6];
  const float* amask  = (const float*)d_in[7];

  char* ws = (char*)d_ws;
  __hip_bfloat16* Xb   = (__hip_bfloat16*)(ws);               // 16,777,216 B  [4096][2048]
  __hip_bfloat16* Wt   = (__hip_bfloat16*)(ws + 16777216);    // 12,582,912 B  [3072][2048]
  __hip_bfloat16* Wot  = (__hip_bfloat16*)(ws + 29360128);    //  8,388,608 B  [2048][2048]
  __hip_bfloat16* Qb   = (__hip_bfloat16*)(ws + 37748736);    // 16,777,216 B  [4096][2048]
  __hip_bfloat16* Kb   = (__hip_bfloat16*)(ws + 54525952);    //  4,194,304 B  [4096][512]
  __hip_bfloat16* Vb   = (__hip_bfloat16*)(ws + 58720256);    //  4,194,304 B  [4096][512]
  __hip_bfloat16* Vt   = (__hip_bfloat16*)(ws + 62914560);    //  4,194,304 B  [512][4096]
  __hip_bfloat16* AO   = Xb;  // Xb dead after gemm_qkv4p; reuse for attention output

  prep_all<<<6656, 256, 0, stream>>>(hidden, Wq, Wk, Wv, Wo, Xb, Wt, Wot);

  gemm_qkv4p<<<dim3(16, 12), 512, 0, stream>>>(Xb, Wt, Qb, Kb, Vb);

  postproc<<<768, 256, 0, stream>>>(cosb, sinb, Kb, Vb, Vt);

  attn_kernel<<<256, 512, 0, stream>>>(Qb, Kb, Vt, cosb, sinb, amask, AO);

  gemm_bt<<<dim3(32, 16), 256, 0, stream>>>(AO, Wot, (float*)d_out, 4096, 2048, 2048);
}

// Round 15
// 157.070 us; speedup vs baseline: 1.1616x; 1.0519x over previous
//
#include <hip/hip_runtime.h>
#include <hip/hip_bf16.h>

// HumanVAttention: QKV proj -> K-rope + V transpose -> GQA block-sparse attn (Q-rope fused) -> out proj
// B=1 S=4096 HID=2048 NH=16 NKV=4 HD=128 BLK=64 LOCAL=4 GNB=2 STRIDE=4 ROT=64

typedef short short8 __attribute__((ext_vector_type(8)));
typedef float f32x4  __attribute__((ext_vector_type(4)));

#define NEGV   (-1.0e9f)
#define SCALE  (0.08838834764831845f)

__device__ __forceinline__ void gload16(const void* g, void* l) {
  __builtin_amdgcn_global_load_lds(
      (const __attribute__((address_space(1))) unsigned int*)g,
      (__attribute__((address_space(3))) unsigned int*)l, 16, 0, 0);
}

__device__ __forceinline__ float bf2f(short s) {
  union { unsigned u; float f; } c;
  c.u = ((unsigned)(unsigned short)s) << 16;
  return c.f;
}

__device__ __forceinline__ short f2bf_s(float f) {
  __hip_bfloat16 b = __float2bfloat16(f);
  short s;
  __builtin_memcpy(&s, &b, 2);
  return s;
}

// ---------------- fused prep: hidden f32->bf16 convert + 4 weight transposes (R14-verified) ----------------
__global__ void prep_all(const float* __restrict__ H, const float* __restrict__ Wq,
                         const float* __restrict__ Wk, const float* __restrict__ Wv,
                         const float* __restrict__ Wo, __hip_bfloat16* __restrict__ X,
                         __hip_bfloat16* __restrict__ Wt, __hip_bfloat16* __restrict__ Wot) {
  __shared__ short tile[64][73];
  const int b = blockIdx.x;
  const int tid = threadIdx.x;
  if (b < 4096) {                           // conv hidden: 8 floats -> 8 bf16 per thread
    size_t t = (size_t)b * 256 + tid;
    const float* hp = H + t * 8;
    float4 v0 = *(const float4*)hp;
    float4 v1 = *(const float4*)(hp + 4);
    short8 o;
    o[0] = f2bf_s(v0.x); o[1] = f2bf_s(v0.y); o[2] = f2bf_s(v0.z); o[3] = f2bf_s(v0.w);
    o[4] = f2bf_s(v1.x); o[5] = f2bf_s(v1.y); o[6] = f2bf_s(v1.z); o[7] = f2bf_s(v1.w);
    *(short8*)&X[t * 8] = o;
    return;
  }
  const float* src; __hip_bfloat16* dst; int C; int idx;
  int q = b - 4096;
  if (q < 1024)      { src = Wq; dst = Wt;                       C = 2048; idx = q; }
  else if (q < 1280) { src = Wk; dst = Wt + (size_t)2048 * 2048; C = 512;  idx = q - 1024; }
  else if (q < 1536) { src = Wv; dst = Wt + (size_t)2560 * 2048; C = 512;  idx = q - 1280; }
  else               { src = Wo; dst = Wot;                      C = 2048; idx = q - 1536; }
  const int r0 = (idx & 31) * 64, c0 = (idx >> 5) * 64;
  const int c4 = (tid & 15) * 4, rb = tid >> 4;
#pragma unroll
  for (int j = 0; j < 4; ++j) {
    int r = rb + j * 16;
    float4 v = *(const float4*)(src + (size_t)(r0 + r) * C + c0 + c4);
    tile[r][c4 + 0] = f2bf_s(v.x);
    tile[r][c4 + 1] = f2bf_s(v.y);
    tile[r][c4 + 2] = f2bf_s(v.z);
    tile[r][c4 + 3] = f2bf_s(v.w);
  }
  __syncthreads();
  const int cs = (tid & 7) * 8;
#pragma unroll
  for (int it = 0; it < 2; ++it) {
    int cc = (tid >> 3) + it * 32;
    short8 o;
#pragma unroll
    for (int i = 0; i < 8; ++i) o[i] = tile[cs + i][cc];
    *(short8*)&dst[(size_t)(c0 + cc) * 2048 + r0 + cs] = o;
  }
}

// ---------------- postproc: in-place K-rope + V transpose (R13-verified) ----------------
__global__ void postproc(const float* __restrict__ cosb, const float* __restrict__ sinb,
                         __hip_bfloat16* __restrict__ Kb,
                         const __hip_bfloat16* __restrict__ Vb, __hip_bfloat16* __restrict__ Vt) {
  __shared__ __hip_bfloat16 tile[64][73];
  int blk = blockIdx.x;
  if (blk < 256) {
    int tk = blk * 256 + threadIdx.x;       // [0, 65536): 4096 s x 4 h x 4 g
    int s = tk >> 4;
    int rem = tk & 15;
    __hip_bfloat16* p = Kb + (size_t)s * 512 + (rem >> 2) * 128 + (rem & 3) * 8;
    const int g8 = (tk & 3) * 8;            // d offset in [0,32)
    const float* cp = cosb + (size_t)s * 64 + g8;
    const float* sp = sinb + (size_t)s * 64 + g8;
    short8 a = *(const short8*)p;           // x[d],    d in [0,32)
    short8 b = *(const short8*)(p + 32);    // x[d+32]
    float ca[8], sa[8], cb[8], sb[8];
    *(float4*)&ca[0] = *(const float4*)cp;        *(float4*)&ca[4] = *(const float4*)(cp + 4);
    *(float4*)&cb[0] = *(const float4*)(cp + 32); *(float4*)&cb[4] = *(const float4*)(cp + 36);
    *(float4*)&sa[0] = *(const float4*)sp;        *(float4*)&sa[4] = *(const float4*)(sp + 4);
    *(float4*)&sb[0] = *(const float4*)(sp + 32); *(float4*)&sb[4] = *(const float4*)(sp + 36);
    short8 oa, ob;
#pragma unroll
    for (int i = 0; i < 8; ++i) {
      float av = bf2f(a[i]), bv = bf2f(b[i]);
      oa[i] = f2bf_s(av * ca[i] - bv * sa[i]);   // rot_half: d<32 -> -x[d+32]
      ob[i] = f2bf_s(bv * cb[i] + av * sb[i]);   // d>=32   -> +x[d-32]
    }
    *(short8*)p = oa;
    *(short8*)(p + 32) = ob;
    return;
  }
  int idx = blk - 256;                      // 512 blocks: 64 x 8
  int s0 = (idx & 63) * 64, c0 = (idx >> 6) * 64;
  int c = threadIdx.x & 63, rq = threadIdx.x >> 6;
#pragma unroll
  for (int i = 0; i < 16; ++i) {
    int r = i * 4 + rq;
    tile[r][c] = Vb[(size_t)(s0 + r) * 512 + c0 + c];
  }
  __syncthreads();
#pragma unroll
  for (int i = 0; i < 16; ++i) {
    int cc = i * 4 + rq;
    Vt[(size_t)(c0 + cc) * 4096 + s0 + c] = tile[c][cc];
  }
}

// ---------------- GEMM1: BM=256 x BN=192 tile, pipelined 4-phase, grid 16x16 = 256 = 1/CU ----
// Same 4-phase structure as R10 (verified); only re-parameterized: wave n-width 48
// (acc[8][3], 12 MFMA/phase), B staged as one 24KB unit (3 loads/thread) at q2,
// counted vmcnt(3) once per tile (leaves B(t+2) in flight). LDS 112 KiB =
// 2 buf x {A0 16KB, A1 16KB, B 24KB}. Swizzle algebra unchanged (48%8==0, 16%8==0).
__global__ __launch_bounds__(512, 2) void gemm_qkv4p(
    const __hip_bfloat16* __restrict__ A, const __hip_bfloat16* __restrict__ Bt,
    __hip_bfloat16* __restrict__ Qb, __hip_bfloat16* __restrict__ Kb,
    __hip_bfloat16* __restrict__ Vb) {
  const int K = 2048;
  const int tid = threadIdx.x;
  const int wave = tid >> 6, lane = tid & 63;
  const int l15 = lane & 15, lg = lane >> 4;
  const int bm = blockIdx.x, bn = blockIdx.y;     // 16 x 16
  const int wm = wave >> 2, wn = wave & 3;        // 2M x 4N; per-wave C: 128 x 48

  __shared__ __hip_bfloat16 lds[57344];           // 112 KiB; buf stride 28672 elems

  f32x4 acc[8][3] = {};
  const int srow = lane >> 3;
  const int sslot = lane & 7;
  const int scol = (sslot ^ srow) * 8;
  const size_t abase = (size_t)bm * 256 * K;
  const size_t bbase = (size_t)bn * 192 * K;
  const int r3 = l15 & 7;

  // A half-tile (128x64 = 16KB): 2 gload16/thread
#define STAGE_A(HALF, KO, LBASE)                                                 \
  {                                                                              \
    _Pragma("unroll")                                                            \
    for (int l = 0; l < 2; ++l) {                                                \
      int chunk = l * 8 + wave;                                                  \
      int row = chunk * 8 + srow;                                                \
      gload16(A + abase + (size_t)((HALF) * 128 + row) * K + (KO) + scol,        \
              &lds[(LBASE) + chunk * 512]);                                      \
    }                                                                            \
  }
  // B tile (192x64 = 24KB): 3 gload16/thread
#define STAGE_B(KO, LBASE)                                                       \
  {                                                                              \
    _Pragma("unroll")                                                            \
    for (int l = 0; l < 3; ++l) {                                                \
      int chunk = l * 8 + wave;                                                  \
      int row = chunk * 8 + srow;                                                \
      gload16(Bt + bbase + (size_t)row * K + (KO) + scol,                        \
              &lds[(LBASE) + chunk * 512]);                                      \
    }                                                                            \
  }

  short8 bfr[3][2];
  short8 af[2][2][2];

#define READ_AF(P, Q, BA)                                                        \
  {                                                                              \
    _Pragma("unroll")                                                            \
    for (int m2 = 0; m2 < 2; ++m2)                                               \
      _Pragma("unroll")                                                          \
      for (int ks = 0; ks < 2; ++ks) {                                           \
        int row = ((Q) * 2 + m2) * 16 + l15;                                     \
        int slot = (ks * 4 + lg) ^ r3;                                           \
        af[P][m2][ks] = *(const short8*)&lds[(BA) + row * 64 + slot * 8];        \
      }                                                                          \
  }

#define READ_BF(BB)                                                              \
  {                                                                              \
    _Pragma("unroll")                                                            \
    for (int ni = 0; ni < 3; ++ni)                                               \
      _Pragma("unroll")                                                          \
      for (int ks = 0; ks < 2; ++ks) {                                           \
        int row = wn * 48 + ni * 16 + l15;                                       \
        int slot = (ks * 4 + lg) ^ r3;                                           \
        bfr[ni][ks] = *(const short8*)&lds[(BB) + row * 64 + slot * 8];          \
      }                                                                          \
  }

#define MFMA_Q(Q, P)                                                             \
  {                                                                              \
    __builtin_amdgcn_s_setprio(1);                                               \
    _Pragma("unroll")                                                            \
    for (int ks = 0; ks < 2; ++ks)                                               \
      _Pragma("unroll")                                                          \
      for (int m2 = 0; m2 < 2; ++m2)                                             \
        _Pragma("unroll")                                                        \
        for (int ni = 0; ni < 3; ++ni)                                           \
          acc[(Q) * 2 + m2][ni] = __builtin_amdgcn_mfma_f32_16x16x32_bf16(       \
              af[P][m2][ks], bfr[ni][ks], acc[(Q) * 2 + m2][ni], 0, 0, 0);       \
    __builtin_amdgcn_s_setprio(0);                                               \
  }

#define LGKM0()                                                                  \
  asm volatile("s_waitcnt lgkmcnt(0)" ::: "memory");                             \
  __builtin_amdgcn_sched_barrier(0);

  // ---- prologue: B(0), A0(0), A1(0), B(1); vmcnt(3) leaves B(1) in flight ----
  STAGE_B(0, 16384);
  STAGE_A(0, 0, 0);
  STAGE_A(1, 0, 8192);
  STAGE_B(64, 28672 + 16384);
  asm volatile("s_waitcnt vmcnt(3)" ::: "memory");
  __builtin_amdgcn_sched_barrier(0);
  __builtin_amdgcn_s_barrier();
  {
    READ_BF(16384);
    READ_AF(0, 0, wm * 8192);
  }
  LGKM0();

  for (int t = 0; t < 32; ++t) {
    const int buf = (t & 1) * 28672;
    const int nbuf = buf ^ 28672;
    const int bA = buf + wm * 8192;
    // q0
    if (t + 1 < 32) STAGE_A(0, (t + 1) * 64, nbuf);
    __builtin_amdgcn_s_barrier();
    MFMA_Q(0, 0);
    READ_AF(1, 1, bA);
    LGKM0();
    // q1
    if (t + 1 < 32) STAGE_A(1, (t + 1) * 64, nbuf + 8192);
    __builtin_amdgcn_s_barrier();
    MFMA_Q(1, 1);
    READ_AF(0, 2, bA);
    LGKM0();
    // q2
    if (t + 2 < 32) STAGE_B((t + 2) * 64, buf + 16384);
    __builtin_amdgcn_s_barrier();
    MFMA_Q(2, 0);
    READ_AF(1, 3, bA);
    LGKM0();
    // q3: counted vmcnt (leave B(t+2)'s 3 loads in flight); preload next tile's bfr + af0
    if (t < 30) asm volatile("s_waitcnt vmcnt(3)" ::: "memory");
    else        asm volatile("s_waitcnt vmcnt(0)" ::: "memory");
    __builtin_amdgcn_sched_barrier(0);
    __builtin_amdgcn_s_barrier();
    MFMA_Q(3, 1);
    if (t + 1 < 32) {
      READ_BF(nbuf + 16384);
      READ_AF(0, 0, nbuf + wm * 8192);
    }
    LGKM0();
  }
#undef STAGE_A
#undef STAGE_B
#undef READ_AF
#undef READ_BF
#undef MFMA_Q
#undef LGKM0

  // ---- epilogue: per-fragment routing (region boundaries 2048/2560 are 16-aligned) ----
#pragma unroll
  for (int m8 = 0; m8 < 8; ++m8)
#pragma unroll
    for (int ni = 0; ni < 3; ++ni) {
      int colg = bn * 192 + wn * 48 + ni * 16;     // wave-uniform fragment base
      __hip_bfloat16* dst; int ldc, col;
      if (colg < 2048)      { dst = Qb; ldc = 2048; col = colg + l15; }
      else if (colg < 2560) { dst = Kb; ldc = 512;  col = colg - 2048 + l15; }
      else                  { dst = Vb; ldc = 512;  col = colg - 2560 + l15; }
      int row = bm * 256 + wm * 128 + m8 * 16 + lg * 4;
#pragma unroll
      for (int r = 0; r < 4; ++r)
        dst[(size_t)(row + r) * ldc + col] = __float2bfloat16(acc[m8][ni][r]);
    }
}

// ---------------- GEMM2: C[M][N] f32 = A[M][K] bf16 . Bt[N][K]^T bf16 (verified 128^2) ----------------
__global__ __launch_bounds__(256) void gemm_bt(
    const __hip_bfloat16* __restrict__ A, const __hip_bfloat16* __restrict__ Bt,
    float* __restrict__ C, int M, int N, int K) {
  const int tid = threadIdx.x;
  const int wave = tid >> 6, lane = tid & 63;
  const int l15 = lane & 15, lg = lane >> 4;
  const int bm = blockIdx.x, bn = blockIdx.y;
  const int wm = wave >> 1, wn = wave & 1;

  __shared__ __hip_bfloat16 As[128 * 64];
  __shared__ __hip_bfloat16 Bs[128 * 64];

  f32x4 acc[4][4] = {};
  const int lrow = lane >> 3;
  const int lslot = lane & 7;
  const int scol = (lslot ^ lrow) * 8;
  const size_t abase = (size_t)bm * 128 * K;
  const size_t bbase = (size_t)bn * 128 * K;
  const int r3 = l15 & 7;

  for (int k0 = 0; k0 < K; k0 += 64) {
#pragma unroll
    for (int i = 0; i < 4; ++i) {
      int seg = i * 4 + wave;
      int row = seg * 8 + lrow;
      gload16(A + abase + (size_t)row * K + k0 + scol, &As[seg * 512]);
      gload16(Bt + bbase + (size_t)row * K + k0 + scol, &Bs[seg * 512]);
    }
    __syncthreads();
#pragma unroll
    for (int ks = 0; ks < 2; ++ks) {
      const int slot = (ks * 4 + lg) ^ r3;
      short8 af[4], bf[4];
#pragma unroll
      for (int mi = 0; mi < 4; ++mi)
        af[mi] = *(const short8*)&As[(wm * 64 + mi * 16 + l15) * 64 + slot * 8];
#pragma unroll
      for (int ni = 0; ni < 4; ++ni)
        bf[ni] = *(const short8*)&Bs[(wn * 64 + ni * 16 + l15) * 64 + slot * 8];
#pragma unroll
      for (int mi = 0; mi < 4; ++mi)
#pragma unroll
        for (int ni = 0; ni < 4; ++ni)
          acc[mi][ni] = __builtin_amdgcn_mfma_f32_16x16x32_bf16(af[mi], bf[ni], acc[mi][ni], 0, 0, 0);
    }
    __syncthreads();
  }
#pragma unroll
  for (int mi = 0; mi < 4; ++mi)
#pragma unroll
    for (int ni = 0; ni < 4; ++ni) {
      int row = bm * 128 + wm * 64 + mi * 16 + lg * 4;
      int col = bn * 128 + wn * 64 + ni * 16 + l15;
#pragma unroll
      for (int r = 0; r < 4; ++r)
        C[(size_t)(row + r) * N + col] = acc[mi][ni][r];
    }
}

// ---------------- block-sparse attention: one block per (bi, kvh), 8 waves (R13-verified)
// with fused Q-rope in the qf prologue.
__global__ __launch_bounds__(512, 2) void attn_kernel(
    const __hip_bfloat16* __restrict__ Qb,  // [4096][2048]  (un-roped)
    const __hip_bfloat16* __restrict__ Kb,  // [4096][512]   (roped by postproc)
    const __hip_bfloat16* __restrict__ Vt,  // [512][4096]   (channel-major)
    const float* __restrict__ cosb, const float* __restrict__ sinb,
    const float* __restrict__ amask,        // [4096]
    __hip_bfloat16* __restrict__ AO)        // [4096][2048]
{
  const int bid = blockIdx.x;
  const int kvh = bid & 3;
  const int bi  = bid >> 2;
  const int tid = threadIdx.x;
  const int wave = tid >> 6, lane = tid & 63;
  const int l15 = lane & 15, lg = lane >> 4;
  const int h  = kvh * 4 + (wave >> 1);
  const int rh = wave & 1;
  const int q0 = bi * 64 + rh * 32;

  int sel[6]; int nsel = 0;
  {
    int gtop = bi >> 2;
    for (int j = 0; j <= bi; ++j) {
      bool pick = (j == 0) || (j >= bi - 3) || (((j & 3) == 0) && ((j >> 2) >= gtop - 1));
      if (pick && nsel < 6) sel[nsel++] = j;
    }
  }

  __shared__ __hip_bfloat16 kv[2][16384];  // per buf: K [64][128] at 0, V [128][64] at 8192
  __shared__ __hip_bfloat16 Pl[8][2304];   // per wave: P [32][72]

  short8 qf[2][4];
#pragma unroll
  for (int mi = 0; mi < 2; ++mi) {
    const int s_ = q0 + mi * 16 + l15;
    const __hip_bfloat16* qrow = Qb + (size_t)s_ * 2048 + h * 128;
#pragma unroll
    for (int ks = 0; ks < 4; ++ks)
      qf[mi][ks] = *(const short8*)(qrow + ks * 32 + lg * 8);
    // fused partial RoPE on head-d < 64: a = qf[0] (d = lg*8+i), b = qf[1] (d+32)
    const float* cp = cosb + (size_t)s_ * 64 + lg * 8;
    const float* sp = sinb + (size_t)s_ * 64 + lg * 8;
    float ca[8], sa[8], cb[8], sb[8];
    *(float4*)&ca[0] = *(const float4*)cp;        *(float4*)&ca[4] = *(const float4*)(cp + 4);
    *(float4*)&cb[0] = *(const float4*)(cp + 32); *(float4*)&cb[4] = *(const float4*)(cp + 36);
    *(float4*)&sa[0] = *(const float4*)sp;        *(float4*)&sa[4] = *(const float4*)(sp + 4);
    *(float4*)&sb[0] = *(const float4*)(sp + 32); *(float4*)&sb[4] = *(const float4*)(sp + 36);
    short8 a = qf[mi][0], b = qf[mi][1], oa, ob;
#pragma unroll
    for (int i = 0; i < 8; ++i) {
      float av = bf2f(a[i]), bv = bf2f(b[i]);
      oa[i] = f2bf_s(av * ca[i] - bv * sa[i]);   // d<32:  -x[d+32]*sin
      ob[i] = f2bf_s(bv * cb[i] + av * sb[i]);   // d>=32: +x[d-32]*sin
    }
    qf[mi][0] = oa;
    qf[mi][1] = ob;
  }

  float m[2][4], l[2][4];
  f32x4 oacc[2][8] = {};
#pragma unroll
  for (int mi = 0; mi < 2; ++mi)
#pragma unroll
    for (int r = 0; r < 4; ++r) { m[mi][r] = -3.0e38f; l[mi][r] = 0.f; }

#define STAGE_KV(KB, BUF)                                                          \
  {                                                                                \
    _Pragma("unroll")                                                              \
    for (int i = 0; i < 2; ++i) {                                                  \
      int chunk = (i * 8 + wave) * 64 + lane;                                      \
      int row = chunk >> 4, slot = chunk & 15;                                     \
      gload16(Kb + (size_t)((KB) * 64 + row) * 512 + kvh * 128 +                   \
                  ((slot ^ (row & 15)) * 8),                                       \
              &kv[BUF][(i * 8 + wave) * 512]);                                     \
    }                                                                              \
    _Pragma("unroll")                                                              \
    for (int i = 0; i < 2; ++i) {                                                  \
      int chunk = (i * 8 + wave) * 64 + lane;                                      \
      int row = chunk >> 3, slot = chunk & 7;                                      \
      gload16(Vt + (size_t)(kvh * 128 + row) * 4096 + (KB) * 64 +                  \
                  ((slot ^ (row & 7)) * 8),                                        \
              &kv[BUF][8192 + (i * 8 + wave) * 512]);                              \
    }                                                                              \
  }

  STAGE_KV(sel[0], 0);

#pragma unroll
  for (int j = 0; j < 6; ++j) {
    if (j < nsel) {
      const int kb = sel[j];
      if (j + 1 < nsel) {
        STAGE_KV(sel[j + 1], (j + 1) & 1);
        asm volatile("s_waitcnt vmcnt(4)" ::: "memory");
      } else {
        asm volatile("s_waitcnt vmcnt(0)" ::: "memory");
      }
      __builtin_amdgcn_sched_barrier(0);
      __builtin_amdgcn_s_barrier();
      const __hip_bfloat16* kbuf = kv[j & 1];

      f32x4 sc[2][4] = {};
#pragma unroll
      for (int nf = 0; nf < 4; ++nf)
#pragma unroll
        for (int ks = 0; ks < 4; ++ks) {
          short8 b = *(const short8*)&kbuf[(nf * 16 + l15) * 128 +
                                           (((ks * 4 + lg) ^ l15) * 8)];
          sc[0][nf] = __builtin_amdgcn_mfma_f32_16x16x32_bf16(qf[0][ks], b, sc[0][nf], 0, 0, 0);
          sc[1][nf] = __builtin_amdgcn_mfma_f32_16x16x32_bf16(qf[1][ks], b, sc[1][nf], 0, 0, 0);
        }

      float am[4];
#pragma unroll
      for (int nf = 0; nf < 4; ++nf)
        am[nf] = (1.0f - amask[kb * 64 + nf * 16 + l15]) * NEGV;
#pragma unroll
      for (int mi = 0; mi < 2; ++mi)
#pragma unroll
        for (int nf = 0; nf < 4; ++nf) {
          int keyl = nf * 16 + l15;
#pragma unroll
          for (int r = 0; r < 4; ++r) {
            float s = sc[mi][nf][r] * SCALE + am[nf];
            if (kb == bi) {
              int qrow = rh * 32 + mi * 16 + lg * 4 + r;
              if (keyl > qrow) s = NEGV;
            }
            sc[mi][nf][r] = s;
          }
        }

      float pm[2][4];
#pragma unroll
      for (int mi = 0; mi < 2; ++mi)
#pragma unroll
        for (int r = 0; r < 4; ++r) {
          float v = fmaxf(fmaxf(sc[mi][0][r], sc[mi][1][r]),
                          fmaxf(sc[mi][2][r], sc[mi][3][r]));
          v = fmaxf(v, __shfl_xor(v, 1)); v = fmaxf(v, __shfl_xor(v, 2));
          v = fmaxf(v, __shfl_xor(v, 4)); v = fmaxf(v, __shfl_xor(v, 8));
          pm[mi][r] = v;
        }

      bool need = false;
#pragma unroll
      for (int mi = 0; mi < 2; ++mi)
#pragma unroll
        for (int r = 0; r < 4; ++r) need |= (pm[mi][r] - m[mi][r] > 8.0f);
      if (__any(need)) {
#pragma unroll
        for (int mi = 0; mi < 2; ++mi)
#pragma unroll
          for (int r = 0; r < 4; ++r) {
            float mn = fmaxf(m[mi][r], pm[mi][r]);
            float scl = __expf(m[mi][r] - mn);
            l[mi][r] *= scl;
#pragma unroll
            for (int df = 0; df < 8; ++df) oacc[mi][df][r] *= scl;
            m[mi][r] = mn;
          }
      }

#pragma unroll
      for (int mi = 0; mi < 2; ++mi)
#pragma unroll
        for (int r = 0; r < 4; ++r) {
          float rs = 0.f;
#pragma unroll
          for (int nf = 0; nf < 4; ++nf) {
            float p = __expf(sc[mi][nf][r] - m[mi][r]);
            rs += p;
            Pl[wave][(mi * 16 + lg * 4 + r) * 72 + nf * 16 + l15] = __float2bfloat16(p);
          }
          rs += __shfl_xor(rs, 1); rs += __shfl_xor(rs, 2);
          rs += __shfl_xor(rs, 4); rs += __shfl_xor(rs, 8);
          l[mi][r] += rs;
        }

      short8 af2[2][2];
#pragma unroll
      for (int mi = 0; mi < 2; ++mi)
#pragma unroll
        for (int ks = 0; ks < 2; ++ks)
          af2[mi][ks] = *(const short8*)&Pl[wave][(mi * 16 + l15) * 72 + ks * 32 + lg * 8];
#pragma unroll
      for (int df = 0; df < 8; ++df)
#pragma unroll
        for (int ks = 0; ks < 2; ++ks) {
          short8 vb = *(const short8*)&kbuf[8192 + (df * 16 + l15) * 64 +
                                            (((ks * 4 + lg) ^ (l15 & 7)) * 8)];
          oacc[0][df] = __builtin_amdgcn_mfma_f32_16x16x32_bf16(af2[0][ks], vb, oacc[0][df], 0, 0, 0);
          oacc[1][df] = __builtin_amdgcn_mfma_f32_16x16x32_bf16(af2[1][ks], vb, oacc[1][df], 0, 0, 0);
        }
      __builtin_amdgcn_s_barrier();
    }
  }
#undef STAGE_KV

#pragma unroll
  for (int mi = 0; mi < 2; ++mi) {
    float inv[4];
#pragma unroll
    for (int r = 0; r < 4; ++r) inv[r] = 1.0f / l[mi][r];
#pragma unroll
    for (int df = 0; df < 8; ++df)
#pragma unroll
      for (int r = 0; r < 4; ++r) {
        int qrow = q0 + mi * 16 + lg * 4 + r;
        AO[(size_t)qrow * 2048 + h * 128 + df * 16 + l15] =
            __float2bfloat16(oacc[mi][df][r] * inv[r]);
      }
  }
}

// ---------------- launch ----------------
extern "C" void kernel_launch(void* const* d_in, const int* in_sizes, int n_in,
                              void* d_out, int out_size, void* d_ws, size_t ws_size,
                              hipStream_t stream) {
  const float* hidden = (const float*)d_in[0];
  const float* cosb   = (const float*)d_in[1];
  const float* sinb   = (const float*)d_in[2];
  const float* Wq     = (const float*)d_in[3];
  const float* Wk     = (const float*)d_in[4];
  const float* Wv     = (const float*)d_in[5];
  const float* Wo     = (const float*)d_in[6];
  const float* amask  = (const float*)d_in[7];

  char* ws = (char*)d_ws;
  __hip_bfloat16* Xb   = (__hip_bfloat16*)(ws);               // 16,777,216 B  [4096][2048]
  __hip_bfloat16* Wt   = (__hip_bfloat16*)(ws + 16777216);    // 12,582,912 B  [3072][2048]
  __hip_bfloat16* Wot  = (__hip_bfloat16*)(ws + 29360128);    //  8,388,608 B  [2048][2048]
  __hip_bfloat16* Qb   = (__hip_bfloat16*)(ws + 37748736);    // 16,777,216 B  [4096][2048]
  __hip_bfloat16* Kb   = (__hip_bfloat16*)(ws + 54525952);    //  4,194,304 B  [4096][512]
  __hip_bfloat16* Vb   = (__hip_bfloat16*)(ws + 58720256);    //  4,194,304 B  [4096][512]
  __hip_bfloat16* Vt   = (__hip_bfloat16*)(ws + 62914560);    //  4,194,304 B  [512][4096]
  __hip_bfloat16* AO   = Xb;  // Xb dead after gemm_qkv4p; reuse for attention output

  prep_all<<<6656, 256, 0, stream>>>(hidden, Wq, Wk, Wv, Wo, Xb, Wt, Wot);

  gemm_qkv4p<<<dim3(16, 16), 512, 0, stream>>>(Xb, Wt, Qb, Kb, Vb);

  postproc<<<768, 256, 0, stream>>>(cosb, sinb, Kb, Vb, Vt);

  attn_kernel<<<256, 512, 0, stream>>>(Qb, Kb, Vt, cosb, sinb, amask, AO);

  gemm_bt<<<dim3(32, 16), 256, 0, stream>>>(AO, Wot, (float*)d_out, 4096, 2048, 2048);
}

// Round 16
// 155.270 us; speedup vs baseline: 1.1750x; 1.0116x over previous
//
#include <hip/hip_runtime.h>
#include <hip/hip_bf16.h>

// HumanVAttention: QKV proj -> K-rope + V transpose -> GQA block-sparse attn (Q-rope fused) -> out proj
// B=1 S=4096 HID=2048 NH=16 NKV=4 HD=128 BLK=64 LOCAL=4 GNB=2 STRIDE=4 ROT=64

typedef short short8 __attribute__((ext_vector_type(8)));
typedef float f32x4  __attribute__((ext_vector_type(4)));

#define NEGV   (-1.0e9f)
#define SCALE  (0.08838834764831845f)

__device__ __forceinline__ void gload16(const void* g, void* l) {
  __builtin_amdgcn_global_load_lds(
      (const __attribute__((address_space(1))) unsigned int*)g,
      (__attribute__((address_space(3))) unsigned int*)l, 16, 0, 0);
}

__device__ __forceinline__ float bf2f(short s) {
  union { unsigned u; float f; } c;
  c.u = ((unsigned)(unsigned short)s) << 16;
  return c.f;
}

__device__ __forceinline__ short f2bf_s(float f) {
  __hip_bfloat16 b = __float2bfloat16(f);
  short s;
  __builtin_memcpy(&s, &b, 2);
  return s;
}

// ---------------- fused prep: hidden f32->bf16 convert + 4 weight transposes (R14-verified) ----------------
__global__ void prep_all(const float* __restrict__ H, const float* __restrict__ Wq,
                         const float* __restrict__ Wk, const float* __restrict__ Wv,
                         const float* __restrict__ Wo, __hip_bfloat16* __restrict__ X,
                         __hip_bfloat16* __restrict__ Wt, __hip_bfloat16* __restrict__ Wot) {
  __shared__ short tile[64][73];
  const int b = blockIdx.x;
  const int tid = threadIdx.x;
  if (b < 4096) {                           // conv hidden: 8 floats -> 8 bf16 per thread
    size_t t = (size_t)b * 256 + tid;
    const float* hp = H + t * 8;
    float4 v0 = *(const float4*)hp;
    float4 v1 = *(const float4*)(hp + 4);
    short8 o;
    o[0] = f2bf_s(v0.x); o[1] = f2bf_s(v0.y); o[2] = f2bf_s(v0.z); o[3] = f2bf_s(v0.w);
    o[4] = f2bf_s(v1.x); o[5] = f2bf_s(v1.y); o[6] = f2bf_s(v1.z); o[7] = f2bf_s(v1.w);
    *(short8*)&X[t * 8] = o;
    return;
  }
  const float* src; __hip_bfloat16* dst; int C; int idx;
  int q = b - 4096;
  if (q < 1024)      { src = Wq; dst = Wt;                       C = 2048; idx = q; }
  else if (q < 1280) { src = Wk; dst = Wt + (size_t)2048 * 2048; C = 512;  idx = q - 1024; }
  else if (q < 1536) { src = Wv; dst = Wt + (size_t)2560 * 2048; C = 512;  idx = q - 1280; }
  else               { src = Wo; dst = Wot;                      C = 2048; idx = q - 1536; }
  const int r0 = (idx & 31) * 64, c0 = (idx >> 5) * 64;
  const int c4 = (tid & 15) * 4, rb = tid >> 4;
#pragma unroll
  for (int j = 0; j < 4; ++j) {
    int r = rb + j * 16;
    float4 v = *(const float4*)(src + (size_t)(r0 + r) * C + c0 + c4);
    tile[r][c4 + 0] = f2bf_s(v.x);
    tile[r][c4 + 1] = f2bf_s(v.y);
    tile[r][c4 + 2] = f2bf_s(v.z);
    tile[r][c4 + 3] = f2bf_s(v.w);
  }
  __syncthreads();
  const int cs = (tid & 7) * 8;
#pragma unroll
  for (int it = 0; it < 2; ++it) {
    int cc = (tid >> 3) + it * 32;
    short8 o;
#pragma unroll
    for (int i = 0; i < 8; ++i) o[i] = tile[cs + i][cc];
    *(short8*)&dst[(size_t)(c0 + cc) * 2048 + r0 + cs] = o;
  }
}

// ---------------- postproc: in-place K-rope + V transpose (R13-verified) ----------------
__global__ void postproc(const float* __restrict__ cosb, const float* __restrict__ sinb,
                         __hip_bfloat16* __restrict__ Kb,
                         const __hip_bfloat16* __restrict__ Vb, __hip_bfloat16* __restrict__ Vt) {
  __shared__ __hip_bfloat16 tile[64][73];
  int blk = blockIdx.x;
  if (blk < 256) {
    int tk = blk * 256 + threadIdx.x;       // [0, 65536): 4096 s x 4 h x 4 g
    int s = tk >> 4;
    int rem = tk & 15;
    __hip_bfloat16* p = Kb + (size_t)s * 512 + (rem >> 2) * 128 + (rem & 3) * 8;
    const int g8 = (tk & 3) * 8;            // d offset in [0,32)
    const float* cp = cosb + (size_t)s * 64 + g8;
    const float* sp = sinb + (size_t)s * 64 + g8;
    short8 a = *(const short8*)p;           // x[d],    d in [0,32)
    short8 b = *(const short8*)(p + 32);    // x[d+32]
    float ca[8], sa[8], cb[8], sb[8];
    *(float4*)&ca[0] = *(const float4*)cp;        *(float4*)&ca[4] = *(const float4*)(cp + 4);
    *(float4*)&cb[0] = *(const float4*)(cp + 32); *(float4*)&cb[4] = *(const float4*)(cp + 36);
    *(float4*)&sa[0] = *(const float4*)sp;        *(float4*)&sa[4] = *(const float4*)(sp + 4);
    *(float4*)&sb[0] = *(const float4*)(sp + 32); *(float4*)&sb[4] = *(const float4*)(sp + 36);
    short8 oa, ob;
#pragma unroll
    for (int i = 0; i < 8; ++i) {
      float av = bf2f(a[i]), bv = bf2f(b[i]);
      oa[i] = f2bf_s(av * ca[i] - bv * sa[i]);   // rot_half: d<32 -> -x[d+32]
      ob[i] = f2bf_s(bv * cb[i] + av * sb[i]);   // d>=32   -> +x[d-32]
    }
    *(short8*)p = oa;
    *(short8*)(p + 32) = ob;
    return;
  }
  int idx = blk - 256;                      // 512 blocks: 64 x 8
  int s0 = (idx & 63) * 64, c0 = (idx >> 6) * 64;
  int c = threadIdx.x & 63, rq = threadIdx.x >> 6;
#pragma unroll
  for (int i = 0; i < 16; ++i) {
    int r = i * 4 + rq;
    tile[r][c] = Vb[(size_t)(s0 + r) * 512 + c0 + c];
  }
  __syncthreads();
#pragma unroll
  for (int i = 0; i < 16; ++i) {
    int cc = i * 4 + rq;
    Vt[(size_t)(c0 + cc) * 4096 + s0 + c] = tile[c][cc];
  }
}

// ---------------- GEMM1: BM=256 x BN=192 tile, pipelined 2-phase, grid 16x16 = 256 = 1/CU ----
// R15 structure with q0+q1 / q2+q3 merged: 24 MFMA per phase, 2 barriers per K-tile.
// Stage A0(t+1),A1(t+1) at ph0; B(t+2) at ph1; counted vmcnt(3) at ph1 drains exactly
// {B(t+1), A0(t+1), A1(t+1)} (10 outstanding -> 3) which ph1's tail preloads consume.
// LDS 112 KiB = 2 buf x {A0 16KB, A1 16KB, B 24KB}; swizzle algebra unchanged.
__global__ __launch_bounds__(512, 2) void gemm_qkv2p(
    const __hip_bfloat16* __restrict__ A, const __hip_bfloat16* __restrict__ Bt,
    __hip_bfloat16* __restrict__ Qb, __hip_bfloat16* __restrict__ Kb,
    __hip_bfloat16* __restrict__ Vb) {
  const int K = 2048;
  const int tid = threadIdx.x;
  const int wave = tid >> 6, lane = tid & 63;
  const int l15 = lane & 15, lg = lane >> 4;
  const int bm = blockIdx.x, bn = blockIdx.y;     // 16 x 16
  const int wm = wave >> 2, wn = wave & 3;        // 2M x 4N; per-wave C: 128 x 48

  __shared__ __hip_bfloat16 lds[57344];           // 112 KiB; buf stride 28672 elems

  f32x4 acc[8][3] = {};
  const int srow = lane >> 3;
  const int sslot = lane & 7;
  const int scol = (sslot ^ srow) * 8;
  const size_t abase = (size_t)bm * 256 * K;
  const size_t bbase = (size_t)bn * 192 * K;
  const int r3 = l15 & 7;

#define STAGE_A(HALF, KO, LBASE)                                                 \
  {                                                                              \
    _Pragma("unroll")                                                            \
    for (int l = 0; l < 2; ++l) {                                                \
      int chunk = l * 8 + wave;                                                  \
      int row = chunk * 8 + srow;                                                \
      gload16(A + abase + (size_t)((HALF) * 128 + row) * K + (KO) + scol,        \
              &lds[(LBASE) + chunk * 512]);                                      \
    }                                                                            \
  }
#define STAGE_B(KO, LBASE)                                                       \
  {                                                                              \
    _Pragma("unroll")                                                            \
    for (int l = 0; l < 3; ++l) {                                                \
      int chunk = l * 8 + wave;                                                  \
      int row = chunk * 8 + srow;                                                \
      gload16(Bt + bbase + (size_t)row * K + (KO) + scol,                        \
              &lds[(LBASE) + chunk * 512]);                                      \
    }                                                                            \
  }

  short8 bfr[3][2];
  short8 af[2][2][2];   // [slotAB][m2][ks] -- af[0]/af[1] hold two consecutive quadrants

#define READ_AF(P, Q, BA)                                                        \
  {                                                                              \
    _Pragma("unroll")                                                            \
    for (int m2 = 0; m2 < 2; ++m2)                                               \
      _Pragma("unroll")                                                          \
      for (int ks = 0; ks < 2; ++ks) {                                           \
        int row = ((Q) * 2 + m2) * 16 + l15;                                     \
        int slot = (ks * 4 + lg) ^ r3;                                           \
        af[P][m2][ks] = *(const short8*)&lds[(BA) + row * 64 + slot * 8];        \
      }                                                                          \
  }

#define READ_BF(BB)                                                              \
  {                                                                              \
    _Pragma("unroll")                                                            \
    for (int ni = 0; ni < 3; ++ni)                                               \
      _Pragma("unroll")                                                          \
      for (int ks = 0; ks < 2; ++ks) {                                           \
        int row = wn * 48 + ni * 16 + l15;                                       \
        int slot = (ks * 4 + lg) ^ r3;                                           \
        bfr[ni][ks] = *(const short8*)&lds[(BB) + row * 64 + slot * 8];          \
      }                                                                          \
  }

// 24 MFMA: quadrants QA (af[0]) and QB (af[1])
#define MFMA_2Q(QA, QB)                                                          \
  {                                                                              \
    __builtin_amdgcn_s_setprio(1);                                               \
    _Pragma("unroll")                                                            \
    for (int ks = 0; ks < 2; ++ks)                                               \
      _Pragma("unroll")                                                          \
      for (int m2 = 0; m2 < 2; ++m2)                                             \
        _Pragma("unroll")                                                        \
        for (int ni = 0; ni < 3; ++ni) {                                         \
          acc[(QA) * 2 + m2][ni] = __builtin_amdgcn_mfma_f32_16x16x32_bf16(      \
              af[0][m2][ks], bfr[ni][ks], acc[(QA) * 2 + m2][ni], 0, 0, 0);      \
          acc[(QB) * 2 + m2][ni] = __builtin_amdgcn_mfma_f32_16x16x32_bf16(      \
              af[1][m2][ks], bfr[ni][ks], acc[(QB) * 2 + m2][ni], 0, 0, 0);      \
        }                                                                        \
    __builtin_amdgcn_s_setprio(0);                                               \
  }

#define LGKM0()                                                                  \
  asm volatile("s_waitcnt lgkmcnt(0)" ::: "memory");                             \
  __builtin_amdgcn_sched_barrier(0);

  // ---- prologue: B(0), A0(0), A1(0), B(1); vmcnt(3) leaves B(1) in flight ----
  STAGE_B(0, 16384);
  STAGE_A(0, 0, 0);
  STAGE_A(1, 0, 8192);
  STAGE_B(64, 28672 + 16384);
  asm volatile("s_waitcnt vmcnt(3)" ::: "memory");
  __builtin_amdgcn_sched_barrier(0);
  __builtin_amdgcn_s_barrier();
  {
    READ_BF(16384);
    READ_AF(0, 0, wm * 8192);   // q0
    READ_AF(1, 1, wm * 8192);   // q1
  }
  LGKM0();

  for (int t = 0; t < 32; ++t) {
    const int buf = (t & 1) * 28672;
    const int nbuf = buf ^ 28672;
    const int bA = buf + wm * 8192;
    // ---- ph0: MFMA q0+q1; stage A(t+1); preload q2,q3 ----
    if (t + 1 < 32) { STAGE_A(0, (t + 1) * 64, nbuf); STAGE_A(1, (t + 1) * 64, nbuf + 8192); }
    __builtin_amdgcn_s_barrier();
    MFMA_2Q(0, 1);
    READ_AF(0, 2, bA);
    READ_AF(1, 3, bA);
    LGKM0();
    // ---- ph1: stage B(t+2); counted vmcnt; MFMA q2+q3; preload next tile's bfr + q0,q1 ----
    if (t + 2 < 32) STAGE_B((t + 2) * 64, buf + 16384);
    if (t < 30) asm volatile("s_waitcnt vmcnt(3)" ::: "memory");
    else        asm volatile("s_waitcnt vmcnt(0)" ::: "memory");
    __builtin_amdgcn_sched_barrier(0);
    __builtin_amdgcn_s_barrier();
    MFMA_2Q(2, 3);
    if (t + 1 < 32) {
      READ_BF(nbuf + 16384);
      READ_AF(0, 0, nbuf + wm * 8192);
      READ_AF(1, 1, nbuf + wm * 8192);
    }
    LGKM0();
  }
#undef STAGE_A
#undef STAGE_B
#undef READ_AF
#undef READ_BF
#undef MFMA_2Q
#undef LGKM0

  // ---- epilogue: per-fragment routing (region boundaries 2048/2560 are 16-aligned) ----
#pragma unroll
  for (int m8 = 0; m8 < 8; ++m8)
#pragma unroll
    for (int ni = 0; ni < 3; ++ni) {
      int colg = bn * 192 + wn * 48 + ni * 16;     // wave-uniform fragment base
      __hip_bfloat16* dst; int ldc, col;
      if (colg < 2048)      { dst = Qb; ldc = 2048; col = colg + l15; }
      else if (colg < 2560) { dst = Kb; ldc = 512;  col = colg - 2048 + l15; }
      else                  { dst = Vb; ldc = 512;  col = colg - 2560 + l15; }
      int row = bm * 256 + wm * 128 + m8 * 16 + lg * 4;
#pragma unroll
      for (int r = 0; r < 4; ++r)
        dst[(size_t)(row + r) * ldc + col] = __float2bfloat16(acc[m8][ni][r]);
    }
}

// ---------------- GEMM2: C[M][N] f32 = A[M][K] bf16 . Bt[N][K]^T bf16 (verified 128^2) ----------------
__global__ __launch_bounds__(256) void gemm_bt(
    const __hip_bfloat16* __restrict__ A, const __hip_bfloat16* __restrict__ Bt,
    float* __restrict__ C, int M, int N, int K) {
  const int tid = threadIdx.x;
  const int wave = tid >> 6, lane = tid & 63;
  const int l15 = lane & 15, lg = lane >> 4;
  const int bm = blockIdx.x, bn = blockIdx.y;
  const int wm = wave >> 1, wn = wave & 1;

  __shared__ __hip_bfloat16 As[128 * 64];
  __shared__ __hip_bfloat16 Bs[128 * 64];

  f32x4 acc[4][4] = {};
  const int lrow = lane >> 3;
  const int lslot = lane & 7;
  const int scol = (lslot ^ lrow) * 8;
  const size_t abase = (size_t)bm * 128 * K;
  const size_t bbase = (size_t)bn * 128 * K;
  const int r3 = l15 & 7;

  for (int k0 = 0; k0 < K; k0 += 64) {
#pragma unroll
    for (int i = 0; i < 4; ++i) {
      int seg = i * 4 + wave;
      int row = seg * 8 + lrow;
      gload16(A + abase + (size_t)row * K + k0 + scol, &As[seg * 512]);
      gload16(Bt + bbase + (size_t)row * K + k0 + scol, &Bs[seg * 512]);
    }
    __syncthreads();
#pragma unroll
    for (int ks = 0; ks < 2; ++ks) {
      const int slot = (ks * 4 + lg) ^ r3;
      short8 af[4], bf[4];
#pragma unroll
      for (int mi = 0; mi < 4; ++mi)
        af[mi] = *(const short8*)&As[(wm * 64 + mi * 16 + l15) * 64 + slot * 8];
#pragma unroll
      for (int ni = 0; ni < 4; ++ni)
        bf[ni] = *(const short8*)&Bs[(wn * 64 + ni * 16 + l15) * 64 + slot * 8];
#pragma unroll
      for (int mi = 0; mi < 4; ++mi)
#pragma unroll
        for (int ni = 0; ni < 4; ++ni)
          acc[mi][ni] = __builtin_amdgcn_mfma_f32_16x16x32_bf16(af[mi], bf[ni], acc[mi][ni], 0, 0, 0);
    }
    __syncthreads();
  }
#pragma unroll
  for (int mi = 0; mi < 4; ++mi)
#pragma unroll
    for (int ni = 0; ni < 4; ++ni) {
      int row = bm * 128 + wm * 64 + mi * 16 + lg * 4;
      int col = bn * 128 + wn * 64 + ni * 16 + l15;
#pragma unroll
      for (int r = 0; r < 4; ++r)
        C[(size_t)(row + r) * N + col] = acc[mi][ni][r];
    }
}

// ---------------- block-sparse attention: one block per (bi, kvh), 8 waves (R13-verified)
// with fused Q-rope in the qf prologue.
__global__ __launch_bounds__(512, 2) void attn_kernel(
    const __hip_bfloat16* __restrict__ Qb,  // [4096][2048]  (un-roped)
    const __hip_bfloat16* __restrict__ Kb,  // [4096][512]   (roped by postproc)
    const __hip_bfloat16* __restrict__ Vt,  // [512][4096]   (channel-major)
    const float* __restrict__ cosb, const float* __restrict__ sinb,
    const float* __restrict__ amask,        // [4096]
    __hip_bfloat16* __restrict__ AO)        // [4096][2048]
{
  const int bid = blockIdx.x;
  const int kvh = bid & 3;
  const int bi  = bid >> 2;
  const int tid = threadIdx.x;
  const int wave = tid >> 6, lane = tid & 63;
  const int l15 = lane & 15, lg = lane >> 4;
  const int h  = kvh * 4 + (wave >> 1);
  const int rh = wave & 1;
  const int q0 = bi * 64 + rh * 32;

  int sel[6]; int nsel = 0;
  {
    int gtop = bi >> 2;
    for (int j = 0; j <= bi; ++j) {
      bool pick = (j == 0) || (j >= bi - 3) || (((j & 3) == 0) && ((j >> 2) >= gtop - 1));
      if (pick && nsel < 6) sel[nsel++] = j;
    }
  }

  __shared__ __hip_bfloat16 kv[2][16384];  // per buf: K [64][128] at 0, V [128][64] at 8192
  __shared__ __hip_bfloat16 Pl[8][2304];   // per wave: P [32][72]

  short8 qf[2][4];
#pragma unroll
  for (int mi = 0; mi < 2; ++mi) {
    const int s_ = q0 + mi * 16 + l15;
    const __hip_bfloat16* qrow = Qb + (size_t)s_ * 2048 + h * 128;
#pragma unroll
    for (int ks = 0; ks < 4; ++ks)
      qf[mi][ks] = *(const short8*)(qrow + ks * 32 + lg * 8);
    // fused partial RoPE on head-d < 64: a = qf[0] (d = lg*8+i), b = qf[1] (d+32)
    const float* cp = cosb + (size_t)s_ * 64 + lg * 8;
    const float* sp = sinb + (size_t)s_ * 64 + lg * 8;
    float ca[8], sa[8], cb[8], sb[8];
    *(float4*)&ca[0] = *(const float4*)cp;        *(float4*)&ca[4] = *(const float4*)(cp + 4);
    *(float4*)&cb[0] = *(const float4*)(cp + 32); *(float4*)&cb[4] = *(const float4*)(cp + 36);
    *(float4*)&sa[0] = *(const float4*)sp;        *(float4*)&sa[4] = *(const float4*)(sp + 4);
    *(float4*)&sb[0] = *(const float4*)(sp + 32); *(float4*)&sb[4] = *(const float4*)(sp + 36);
    short8 a = qf[mi][0], b = qf[mi][1], oa, ob;
#pragma unroll
    for (int i = 0; i < 8; ++i) {
      float av = bf2f(a[i]), bv = bf2f(b[i]);
      oa[i] = f2bf_s(av * ca[i] - bv * sa[i]);   // d<32:  -x[d+32]*sin
      ob[i] = f2bf_s(bv * cb[i] + av * sb[i]);   // d>=32: +x[d-32]*sin
    }
    qf[mi][0] = oa;
    qf[mi][1] = ob;
  }

  float m[2][4], l[2][4];
  f32x4 oacc[2][8] = {};
#pragma unroll
  for (int mi = 0; mi < 2; ++mi)
#pragma unroll
    for (int r = 0; r < 4; ++r) { m[mi][r] = -3.0e38f; l[mi][r] = 0.f; }

#define STAGE_KV(KB, BUF)                                                          \
  {                                                                                \
    _Pragma("unroll")                                                              \
    for (int i = 0; i < 2; ++i) {                                                  \
      int chunk = (i * 8 + wave) * 64 + lane;                                      \
      int row = chunk >> 4, slot = chunk & 15;                                     \
      gload16(Kb + (size_t)((KB) * 64 + row) * 512 + kvh * 128 +                   \
                  ((slot ^ (row & 15)) * 8),                                       \
              &kv[BUF][(i * 8 + wave) * 512]);                                     \
    }                                                                              \
    _Pragma("unroll")                                                              \
    for (int i = 0; i < 2; ++i) {                                                  \
      int chunk = (i * 8 + wave) * 64 + lane;                                      \
      int row = chunk >> 3, slot = chunk & 7;                                      \
      gload16(Vt + (size_t)(kvh * 128 + row) * 4096 + (KB) * 64 +                  \
                  ((slot ^ (row & 7)) * 8),                                        \
              &kv[BUF][8192 + (i * 8 + wave) * 512]);                              \
    }                                                                              \
  }

  STAGE_KV(sel[0], 0);

#pragma unroll
  for (int j = 0; j < 6; ++j) {
    if (j < nsel) {
      const int kb = sel[j];
      if (j + 1 < nsel) {
        STAGE_KV(sel[j + 1], (j + 1) & 1);
        asm volatile("s_waitcnt vmcnt(4)" ::: "memory");
      } else {
        asm volatile("s_waitcnt vmcnt(0)" ::: "memory");
      }
      __builtin_amdgcn_sched_barrier(0);
      __builtin_amdgcn_s_barrier();
      const __hip_bfloat16* kbuf = kv[j & 1];

      f32x4 sc[2][4] = {};
#pragma unroll
      for (int nf = 0; nf < 4; ++nf)
#pragma unroll
        for (int ks = 0; ks < 4; ++ks) {
          short8 b = *(const short8*)&kbuf[(nf * 16 + l15) * 128 +
                                           (((ks * 4 + lg) ^ l15) * 8)];
          sc[0][nf] = __builtin_amdgcn_mfma_f32_16x16x32_bf16(qf[0][ks], b, sc[0][nf], 0, 0, 0);
          sc[1][nf] = __builtin_amdgcn_mfma_f32_16x16x32_bf16(qf[1][ks], b, sc[1][nf], 0, 0, 0);
        }

      float am[4];
#pragma unroll
      for (int nf = 0; nf < 4; ++nf)
        am[nf] = (1.0f - amask[kb * 64 + nf * 16 + l15]) * NEGV;
#pragma unroll
      for (int mi = 0; mi < 2; ++mi)
#pragma unroll
        for (int nf = 0; nf < 4; ++nf) {
          int keyl = nf * 16 + l15;
#pragma unroll
          for (int r = 0; r < 4; ++r) {
            float s = sc[mi][nf][r] * SCALE + am[nf];
            if (kb == bi) {
              int qrow = rh * 32 + mi * 16 + lg * 4 + r;
              if (keyl > qrow) s = NEGV;
            }
            sc[mi][nf][r] = s;
          }
        }

      float pm[2][4];
#pragma unroll
      for (int mi = 0; mi < 2; ++mi)
#pragma unroll
        for (int r = 0; r < 4; ++r) {
          float v = fmaxf(fmaxf(sc[mi][0][r], sc[mi][1][r]),
                          fmaxf(sc[mi][2][r], sc[mi][3][r]));
          v = fmaxf(v, __shfl_xor(v, 1)); v = fmaxf(v, __shfl_xor(v, 2));
          v = fmaxf(v, __shfl_xor(v, 4)); v = fmaxf(v, __shfl_xor(v, 8));
          pm[mi][r] = v;
        }

      bool need = false;
#pragma unroll
      for (int mi = 0; mi < 2; ++mi)
#pragma unroll
        for (int r = 0; r < 4; ++r) need |= (pm[mi][r] - m[mi][r] > 8.0f);
      if (__any(need)) {
#pragma unroll
        for (int mi = 0; mi < 2; ++mi)
#pragma unroll
          for (int r = 0; r < 4; ++r) {
            float mn = fmaxf(m[mi][r], pm[mi][r]);
            float scl = __expf(m[mi][r] - mn);
            l[mi][r] *= scl;
#pragma unroll
            for (int df = 0; df < 8; ++df) oacc[mi][df][r] *= scl;
            m[mi][r] = mn;
          }
      }

#pragma unroll
      for (int mi = 0; mi < 2; ++mi)
#pragma unroll
        for (int r = 0; r < 4; ++r) {
          float rs = 0.f;
#pragma unroll
          for (int nf = 0; nf < 4; ++nf) {
            float p = __expf(sc[mi][nf][r] - m[mi][r]);
            rs += p;
            Pl[wave][(mi * 16 + lg * 4 + r) * 72 + nf * 16 + l15] = __float2bfloat16(p);
          }
          rs += __shfl_xor(rs, 1); rs += __shfl_xor(rs, 2);
          rs += __shfl_xor(rs, 4); rs += __shfl_xor(rs, 8);
          l[mi][r] += rs;
        }

      short8 af2[2][2];
#pragma unroll
      for (int mi = 0; mi < 2; ++mi)
#pragma unroll
        for (int ks = 0; ks < 2; ++ks)
          af2[mi][ks] = *(const short8*)&Pl[wave][(mi * 16 + l15) * 72 + ks * 32 + lg * 8];
#pragma unroll
      for (int df = 0; df < 8; ++df)
#pragma unroll
        for (int ks = 0; ks < 2; ++ks) {
          short8 vb = *(const short8*)&kbuf[8192 + (df * 16 + l15) * 64 +
                                            (((ks * 4 + lg) ^ (l15 & 7)) * 8)];
          oacc[0][df] = __builtin_amdgcn_mfma_f32_16x16x32_bf16(af2[0][ks], vb, oacc[0][df], 0, 0, 0);
          oacc[1][df] = __builtin_amdgcn_mfma_f32_16x16x32_bf16(af2[1][ks], vb, oacc[1][df], 0, 0, 0);
        }
      __builtin_amdgcn_s_barrier();
    }
  }
#undef STAGE_KV

#pragma unroll
  for (int mi = 0; mi < 2; ++mi) {
    float inv[4];
#pragma unroll
    for (int r = 0; r < 4; ++r) inv[r] = 1.0f / l[mi][r];
#pragma unroll
    for (int df = 0; df < 8; ++df)
#pragma unroll
      for (int r = 0; r < 4; ++r) {
        int qrow = q0 + mi * 16 + lg * 4 + r;
        AO[(size_t)qrow * 2048 + h * 128 + df * 16 + l15] =
            __float2bfloat16(oacc[mi][df][r] * inv[r]);
      }
  }
}

// ---------------- launch ----------------
extern "C" void kernel_launch(void* const* d_in, const int* in_sizes, int n_in,
                              void* d_out, int out_size, void* d_ws, size_t ws_size,
                              hipStream_t stream) {
  const float* hidden = (const float*)d_in[0];
  const float* cosb   = (const float*)d_in[1];
  const float* sinb   = (const float*)d_in[2];
  const float* Wq     = (const float*)d_in[3];
  const float* Wk     = (const float*)d_in[4];
  const float* Wv     = (const float*)d_in[5];
  const float* Wo     = (const float*)d_in[6];
  const float* amask  = (const float*)d_in[7];

  char* ws = (char*)d_ws;
  __hip_bfloat16* Xb   = (__hip_bfloat16*)(ws);               // 16,777,216 B  [4096][2048]
  __hip_bfloat16* Wt   = (__hip_bfloat16*)(ws + 16777216);    // 12,582,912 B  [3072][2048]
  __hip_bfloat16* Wot  = (__hip_bfloat16*)(ws + 29360128);    //  8,388,608 B  [2048][2048]
  __hip_bfloat16* Qb   = (__hip_bfloat16*)(ws + 37748736);    // 16,777,216 B  [4096][2048]
  __hip_bfloat16* Kb   = (__hip_bfloat16*)(ws + 54525952);    //  4,194,304 B  [4096][512]
  __hip_bfloat16* Vb   = (__hip_bfloat16*)(ws + 58720256);    //  4,194,304 B  [4096][512]
  __hip_bfloat16* Vt   = (__hip_bfloat16*)(ws + 62914560);    //  4,194,304 B  [512][4096]
  __hip_bfloat16* AO   = Xb;  // Xb dead after gemm_qkv2p; reuse for attention output

  prep_all<<<6656, 256, 0, stream>>>(hidden, Wq, Wk, Wv, Wo, Xb, Wt, Wot);

  gemm_qkv2p<<<dim3(16, 16), 512, 0, stream>>>(Xb, Wt, Qb, Kb, Vb);

  postproc<<<768, 256, 0, stream>>>(cosb, sinb, Kb, Vb, Vt);

  attn_kernel<<<256, 512, 0, stream>>>(Qb, Kb, Vt, cosb, sinb, amask, AO);

  gemm_bt<<<dim3(32, 16), 256, 0, stream>>>(AO, Wot, (float*)d_out, 4096, 2048, 2048);
}

// Round 17
// 150.143 us; speedup vs baseline: 1.2152x; 1.0341x over previous
//
#include <hip/hip_runtime.h>
#include <hip/hip_bf16.h>

// HumanVAttention: QKV proj -> K-rope + V transpose -> GQA block-sparse attn (Q-rope fused) -> out proj
// B=1 S=4096 HID=2048 NH=16 NKV=4 HD=128 BLK=64 LOCAL=4 GNB=2 STRIDE=4 ROT=64

typedef short short8 __attribute__((ext_vector_type(8)));
typedef float f32x4  __attribute__((ext_vector_type(4)));

#define NEGV   (-1.0e9f)
#define SCALE  (0.08838834764831845f)

__device__ __forceinline__ void gload16(const void* g, void* l) {
  __builtin_amdgcn_global_load_lds(
      (const __attribute__((address_space(1))) unsigned int*)g,
      (__attribute__((address_space(3))) unsigned int*)l, 16, 0, 0);
}

__device__ __forceinline__ float bf2f(short s) {
  union { unsigned u; float f; } c;
  c.u = ((unsigned)(unsigned short)s) << 16;
  return c.f;
}

__device__ __forceinline__ short f2bf_s(float f) {
  __hip_bfloat16 b = __float2bfloat16(f);
  short s;
  __builtin_memcpy(&s, &b, 2);
  return s;
}

// ---------------- fused prep: hidden f32->bf16 convert + 4 weight transposes (R14-verified) ----------------
__global__ void prep_all(const float* __restrict__ H, const float* __restrict__ Wq,
                         const float* __restrict__ Wk, const float* __restrict__ Wv,
                         const float* __restrict__ Wo, __hip_bfloat16* __restrict__ X,
                         __hip_bfloat16* __restrict__ Wt, __hip_bfloat16* __restrict__ Wot) {
  __shared__ short tile[64][73];
  const int b = blockIdx.x;
  const int tid = threadIdx.x;
  if (b < 4096) {                           // conv hidden: 8 floats -> 8 bf16 per thread
    size_t t = (size_t)b * 256 + tid;
    const float* hp = H + t * 8;
    float4 v0 = *(const float4*)hp;
    float4 v1 = *(const float4*)(hp + 4);
    short8 o;
    o[0] = f2bf_s(v0.x); o[1] = f2bf_s(v0.y); o[2] = f2bf_s(v0.z); o[3] = f2bf_s(v0.w);
    o[4] = f2bf_s(v1.x); o[5] = f2bf_s(v1.y); o[6] = f2bf_s(v1.z); o[7] = f2bf_s(v1.w);
    *(short8*)&X[t * 8] = o;
    return;
  }
  const float* src; __hip_bfloat16* dst; int C; int idx;
  int q = b - 4096;
  if (q < 1024)      { src = Wq; dst = Wt;                       C = 2048; idx = q; }
  else if (q < 1280) { src = Wk; dst = Wt + (size_t)2048 * 2048; C = 512;  idx = q - 1024; }
  else if (q < 1536) { src = Wv; dst = Wt + (size_t)2560 * 2048; C = 512;  idx = q - 1280; }
  else               { src = Wo; dst = Wot;                      C = 2048; idx = q - 1536; }
  const int r0 = (idx & 31) * 64, c0 = (idx >> 5) * 64;
  const int c4 = (tid & 15) * 4, rb = tid >> 4;
#pragma unroll
  for (int j = 0; j < 4; ++j) {
    int r = rb + j * 16;
    float4 v = *(const float4*)(src + (size_t)(r0 + r) * C + c0 + c4);
    tile[r][c4 + 0] = f2bf_s(v.x);
    tile[r][c4 + 1] = f2bf_s(v.y);
    tile[r][c4 + 2] = f2bf_s(v.z);
    tile[r][c4 + 3] = f2bf_s(v.w);
  }
  __syncthreads();
  const int cs = (tid & 7) * 8;
#pragma unroll
  for (int it = 0; it < 2; ++it) {
    int cc = (tid >> 3) + it * 32;
    short8 o;
#pragma unroll
    for (int i = 0; i < 8; ++i) o[i] = tile[cs + i][cc];
    *(short8*)&dst[(size_t)(c0 + cc) * 2048 + r0 + cs] = o;
  }
}

// ---------------- postproc: in-place K-rope + V transpose (R13-verified) ----------------
__global__ void postproc(const float* __restrict__ cosb, const float* __restrict__ sinb,
                         __hip_bfloat16* __restrict__ Kb,
                         const __hip_bfloat16* __restrict__ Vb, __hip_bfloat16* __restrict__ Vt) {
  __shared__ __hip_bfloat16 tile[64][73];
  int blk = blockIdx.x;
  if (blk < 256) {
    int tk = blk * 256 + threadIdx.x;       // [0, 65536): 4096 s x 4 h x 4 g
    int s = tk >> 4;
    int rem = tk & 15;
    __hip_bfloat16* p = Kb + (size_t)s * 512 + (rem >> 2) * 128 + (rem & 3) * 8;
    const int g8 = (tk & 3) * 8;            // d offset in [0,32)
    const float* cp = cosb + (size_t)s * 64 + g8;
    const float* sp = sinb + (size_t)s * 64 + g8;
    short8 a = *(const short8*)p;           // x[d],    d in [0,32)
    short8 b = *(const short8*)(p + 32);    // x[d+32]
    float ca[8], sa[8], cb[8], sb[8];
    *(float4*)&ca[0] = *(const float4*)cp;        *(float4*)&ca[4] = *(const float4*)(cp + 4);
    *(float4*)&cb[0] = *(const float4*)(cp + 32); *(float4*)&cb[4] = *(const float4*)(cp + 36);
    *(float4*)&sa[0] = *(const float4*)sp;        *(float4*)&sa[4] = *(const float4*)(sp + 4);
    *(float4*)&sb[0] = *(const float4*)(sp + 32); *(float4*)&sb[4] = *(const float4*)(sp + 36);
    short8 oa, ob;
#pragma unroll
    for (int i = 0; i < 8; ++i) {
      float av = bf2f(a[i]), bv = bf2f(b[i]);
      oa[i] = f2bf_s(av * ca[i] - bv * sa[i]);   // rot_half: d<32 -> -x[d+32]
      ob[i] = f2bf_s(bv * cb[i] + av * sb[i]);   // d>=32   -> +x[d-32]
    }
    *(short8*)p = oa;
    *(short8*)(p + 32) = ob;
    return;
  }
  int idx = blk - 256;                      // 512 blocks: 64 x 8
  int s0 = (idx & 63) * 64, c0 = (idx >> 6) * 64;
  int c = threadIdx.x & 63, rq = threadIdx.x >> 6;
#pragma unroll
  for (int i = 0; i < 16; ++i) {
    int r = i * 4 + rq;
    tile[r][c] = Vb[(size_t)(s0 + r) * 512 + c0 + c];
  }
  __syncthreads();
#pragma unroll
  for (int i = 0; i < 16; ++i) {
    int cc = i * 4 + rq;
    Vt[(size_t)(c0 + cc) * 4096 + s0 + c] = tile[c][cc];
  }
}

// ---------------- GEMM1: BM=256 x BN=192 tile, pipelined 2-phase, grid 16x16 (R16-verified) ----
__global__ __launch_bounds__(512, 2) void gemm_qkv2p(
    const __hip_bfloat16* __restrict__ A, const __hip_bfloat16* __restrict__ Bt,
    __hip_bfloat16* __restrict__ Qb, __hip_bfloat16* __restrict__ Kb,
    __hip_bfloat16* __restrict__ Vb) {
  const int K = 2048;
  const int tid = threadIdx.x;
  const int wave = tid >> 6, lane = tid & 63;
  const int l15 = lane & 15, lg = lane >> 4;
  const int bm = blockIdx.x, bn = blockIdx.y;     // 16 x 16
  const int wm = wave >> 2, wn = wave & 3;        // 2M x 4N; per-wave C: 128 x 48

  __shared__ __hip_bfloat16 lds[57344];           // 112 KiB; buf stride 28672 elems

  f32x4 acc[8][3] = {};
  const int srow = lane >> 3;
  const int sslot = lane & 7;
  const int scol = (sslot ^ srow) * 8;
  const size_t abase = (size_t)bm * 256 * K;
  const size_t bbase = (size_t)bn * 192 * K;
  const int r3 = l15 & 7;

#define STAGE_A(HALF, KO, LBASE)                                                 \
  {                                                                              \
    _Pragma("unroll")                                                            \
    for (int l = 0; l < 2; ++l) {                                                \
      int chunk = l * 8 + wave;                                                  \
      int row = chunk * 8 + srow;                                                \
      gload16(A + abase + (size_t)((HALF) * 128 + row) * K + (KO) + scol,        \
              &lds[(LBASE) + chunk * 512]);                                      \
    }                                                                            \
  }
#define STAGE_B(KO, LBASE)                                                       \
  {                                                                              \
    _Pragma("unroll")                                                            \
    for (int l = 0; l < 3; ++l) {                                                \
      int chunk = l * 8 + wave;                                                  \
      int row = chunk * 8 + srow;                                                \
      gload16(Bt + bbase + (size_t)row * K + (KO) + scol,                        \
              &lds[(LBASE) + chunk * 512]);                                      \
    }                                                                            \
  }

  short8 bfr[3][2];
  short8 af[2][2][2];

#define READ_AF(P, Q, BA)                                                        \
  {                                                                              \
    _Pragma("unroll")                                                            \
    for (int m2 = 0; m2 < 2; ++m2)                                               \
      _Pragma("unroll")                                                          \
      for (int ks = 0; ks < 2; ++ks) {                                           \
        int row = ((Q) * 2 + m2) * 16 + l15;                                     \
        int slot = (ks * 4 + lg) ^ r3;                                           \
        af[P][m2][ks] = *(const short8*)&lds[(BA) + row * 64 + slot * 8];        \
      }                                                                          \
  }

#define READ_BF(BB)                                                              \
  {                                                                              \
    _Pragma("unroll")                                                            \
    for (int ni = 0; ni < 3; ++ni)                                               \
      _Pragma("unroll")                                                          \
      for (int ks = 0; ks < 2; ++ks) {                                           \
        int row = wn * 48 + ni * 16 + l15;                                       \
        int slot = (ks * 4 + lg) ^ r3;                                           \
        bfr[ni][ks] = *(const short8*)&lds[(BB) + row * 64 + slot * 8];          \
      }                                                                          \
  }

#define MFMA_2Q(QA, QB)                                                          \
  {                                                                              \
    __builtin_amdgcn_s_setprio(1);                                               \
    _Pragma("unroll")                                                            \
    for (int ks = 0; ks < 2; ++ks)                                               \
      _Pragma("unroll")                                                          \
      for (int m2 = 0; m2 < 2; ++m2)                                             \
        _Pragma("unroll")                                                        \
        for (int ni = 0; ni < 3; ++ni) {                                         \
          acc[(QA) * 2 + m2][ni] = __builtin_amdgcn_mfma_f32_16x16x32_bf16(      \
              af[0][m2][ks], bfr[ni][ks], acc[(QA) * 2 + m2][ni], 0, 0, 0);      \
          acc[(QB) * 2 + m2][ni] = __builtin_amdgcn_mfma_f32_16x16x32_bf16(      \
              af[1][m2][ks], bfr[ni][ks], acc[(QB) * 2 + m2][ni], 0, 0, 0);      \
        }                                                                        \
    __builtin_amdgcn_s_setprio(0);                                               \
  }

#define LGKM0()                                                                  \
  asm volatile("s_waitcnt lgkmcnt(0)" ::: "memory");                             \
  __builtin_amdgcn_sched_barrier(0);

  STAGE_B(0, 16384);
  STAGE_A(0, 0, 0);
  STAGE_A(1, 0, 8192);
  STAGE_B(64, 28672 + 16384);
  asm volatile("s_waitcnt vmcnt(3)" ::: "memory");
  __builtin_amdgcn_sched_barrier(0);
  __builtin_amdgcn_s_barrier();
  {
    READ_BF(16384);
    READ_AF(0, 0, wm * 8192);   // q0
    READ_AF(1, 1, wm * 8192);   // q1
  }
  LGKM0();

  for (int t = 0; t < 32; ++t) {
    const int buf = (t & 1) * 28672;
    const int nbuf = buf ^ 28672;
    const int bA = buf + wm * 8192;
    if (t + 1 < 32) { STAGE_A(0, (t + 1) * 64, nbuf); STAGE_A(1, (t + 1) * 64, nbuf + 8192); }
    __builtin_amdgcn_s_barrier();
    MFMA_2Q(0, 1);
    READ_AF(0, 2, bA);
    READ_AF(1, 3, bA);
    LGKM0();
    if (t + 2 < 32) STAGE_B((t + 2) * 64, buf + 16384);
    if (t < 30) asm volatile("s_waitcnt vmcnt(3)" ::: "memory");
    else        asm volatile("s_waitcnt vmcnt(0)" ::: "memory");
    __builtin_amdgcn_sched_barrier(0);
    __builtin_amdgcn_s_barrier();
    MFMA_2Q(2, 3);
    if (t + 1 < 32) {
      READ_BF(nbuf + 16384);
      READ_AF(0, 0, nbuf + wm * 8192);
      READ_AF(1, 1, nbuf + wm * 8192);
    }
    LGKM0();
  }
#undef STAGE_A
#undef STAGE_B

#pragma unroll
  for (int m8 = 0; m8 < 8; ++m8)
#pragma unroll
    for (int ni = 0; ni < 3; ++ni) {
      int colg = bn * 192 + wn * 48 + ni * 16;
      __hip_bfloat16* dst; int ldc, col;
      if (colg < 2048)      { dst = Qb; ldc = 2048; col = colg + l15; }
      else if (colg < 2560) { dst = Kb; ldc = 512;  col = colg - 2048 + l15; }
      else                  { dst = Vb; ldc = 512;  col = colg - 2560 + l15; }
      int row = bm * 256 + wm * 128 + m8 * 16 + lg * 4;
#pragma unroll
      for (int r = 0; r < 4; ++r)
        dst[(size_t)(row + r) * ldc + col] = __float2bfloat16(acc[m8][ni][r]);
    }
#undef READ_AF
#undef READ_BF
#undef MFMA_2Q
#undef LGKM0
}

// ---------------- GEMM2: BM=256 x BN=128, pipelined 2-phase, grid 16x16 = 1/CU ----------------
// Re-parameterization of gemm_qkv2p: per-wave C 128x32 (acc[8][2], 16 MFMA/phase),
// B tile 128x64 = 16KB (2 loads/thread), counted vmcnt(2) (leaves B(t+2) in flight).
// LDS 96 KiB = 2 buf x {A0 16K, A1 16K, B 16K}. f32 output.
__global__ __launch_bounds__(512, 2) void gemm_out2p(
    const __hip_bfloat16* __restrict__ A, const __hip_bfloat16* __restrict__ Bt,
    float* __restrict__ C) {
  const int K = 2048, N = 2048;
  const int tid = threadIdx.x;
  const int wave = tid >> 6, lane = tid & 63;
  const int l15 = lane & 15, lg = lane >> 4;
  const int bm = blockIdx.x, bn = blockIdx.y;     // 16 x 16
  const int wm = wave >> 2, wn = wave & 3;        // 2M x 4N; per-wave C: 128 x 32

  __shared__ __hip_bfloat16 lds[49152];           // 96 KiB; buf stride 24576 elems

  f32x4 acc[8][2] = {};
  const int srow = lane >> 3;
  const int sslot = lane & 7;
  const int scol = (sslot ^ srow) * 8;
  const size_t abase = (size_t)bm * 256 * K;
  const size_t bbase = (size_t)bn * 128 * K;
  const int r3 = l15 & 7;

#define STAGE_A(HALF, KO, LBASE)                                                 \
  {                                                                              \
    _Pragma("unroll")                                                            \
    for (int l = 0; l < 2; ++l) {                                                \
      int chunk = l * 8 + wave;                                                  \
      int row = chunk * 8 + srow;                                                \
      gload16(A + abase + (size_t)((HALF) * 128 + row) * K + (KO) + scol,        \
              &lds[(LBASE) + chunk * 512]);                                      \
    }                                                                            \
  }
#define STAGE_B(KO, LBASE)                                                       \
  {                                                                              \
    _Pragma("unroll")                                                            \
    for (int l = 0; l < 2; ++l) {                                                \
      int chunk = l * 8 + wave;                                                  \
      int row = chunk * 8 + srow;                                                \
      gload16(Bt + bbase + (size_t)row * K + (KO) + scol,                        \
              &lds[(LBASE) + chunk * 512]);                                      \
    }                                                                            \
  }

  short8 bfr[2][2];
  short8 af[2][2][2];

#define READ_AF(P, Q, BA)                                                        \
  {                                                                              \
    _Pragma("unroll")                                                            \
    for (int m2 = 0; m2 < 2; ++m2)                                               \
      _Pragma("unroll")                                                          \
      for (int ks = 0; ks < 2; ++ks) {                                           \
        int row = ((Q) * 2 + m2) * 16 + l15;                                     \
        int slot = (ks * 4 + lg) ^ r3;                                           \
        af[P][m2][ks] = *(const short8*)&lds[(BA) + row * 64 + slot * 8];        \
      }                                                                          \
  }

#define READ_BF(BB)                                                              \
  {                                                                              \
    _Pragma("unroll")                                                            \
    for (int ni = 0; ni < 2; ++ni)                                               \
      _Pragma("unroll")                                                          \
      for (int ks = 0; ks < 2; ++ks) {                                           \
        int row = wn * 32 + ni * 16 + l15;                                       \
        int slot = (ks * 4 + lg) ^ r3;                                           \
        bfr[ni][ks] = *(const short8*)&lds[(BB) + row * 64 + slot * 8];          \
      }                                                                          \
  }

#define MFMA_2Q(QA, QB)                                                          \
  {                                                                              \
    __builtin_amdgcn_s_setprio(1);                                               \
    _Pragma("unroll")                                                            \
    for (int ks = 0; ks < 2; ++ks)                                               \
      _Pragma("unroll")                                                          \
      for (int m2 = 0; m2 < 2; ++m2)                                             \
        _Pragma("unroll")                                                        \
        for (int ni = 0; ni < 2; ++ni) {                                         \
          acc[(QA) * 2 + m2][ni] = __builtin_amdgcn_mfma_f32_16x16x32_bf16(      \
              af[0][m2][ks], bfr[ni][ks], acc[(QA) * 2 + m2][ni], 0, 0, 0);      \
          acc[(QB) * 2 + m2][ni] = __builtin_amdgcn_mfma_f32_16x16x32_bf16(      \
              af[1][m2][ks], bfr[ni][ks], acc[(QB) * 2 + m2][ni], 0, 0, 0);      \
        }                                                                        \
    __builtin_amdgcn_s_setprio(0);                                               \
  }

#define LGKM0()                                                                  \
  asm volatile("s_waitcnt lgkmcnt(0)" ::: "memory");                             \
  __builtin_amdgcn_sched_barrier(0);

  // ---- prologue: B(0), A0(0), A1(0), B(1); vmcnt(2) leaves B(1) in flight ----
  STAGE_B(0, 16384);
  STAGE_A(0, 0, 0);
  STAGE_A(1, 0, 8192);
  STAGE_B(64, 24576 + 16384);
  asm volatile("s_waitcnt vmcnt(2)" ::: "memory");
  __builtin_amdgcn_sched_barrier(0);
  __builtin_amdgcn_s_barrier();
  {
    READ_BF(16384);
    READ_AF(0, 0, wm * 8192);
    READ_AF(1, 1, wm * 8192);
  }
  LGKM0();

  for (int t = 0; t < 32; ++t) {
    const int buf = (t & 1) * 24576;
    const int nbuf = buf ^ 24576;
    const int bA = buf + wm * 8192;
    // ph0: MFMA q0+q1; stage A(t+1); preload q2,q3
    if (t + 1 < 32) { STAGE_A(0, (t + 1) * 64, nbuf); STAGE_A(1, (t + 1) * 64, nbuf + 8192); }
    __builtin_amdgcn_s_barrier();
    MFMA_2Q(0, 1);
    READ_AF(0, 2, bA);
    READ_AF(1, 3, bA);
    LGKM0();
    // ph1: stage B(t+2); counted vmcnt; MFMA q2+q3; preload next tile's bfr + q0,q1
    if (t + 2 < 32) STAGE_B((t + 2) * 64, buf + 16384);
    if (t < 30) asm volatile("s_waitcnt vmcnt(2)" ::: "memory");
    else        asm volatile("s_waitcnt vmcnt(0)" ::: "memory");
    __builtin_amdgcn_sched_barrier(0);
    __builtin_amdgcn_s_barrier();
    MFMA_2Q(2, 3);
    if (t + 1 < 32) {
      READ_BF(nbuf + 16384);
      READ_AF(0, 0, nbuf + wm * 8192);
      READ_AF(1, 1, nbuf + wm * 8192);
    }
    LGKM0();
  }
#undef STAGE_A
#undef STAGE_B
#undef READ_AF
#undef READ_BF
#undef MFMA_2Q
#undef LGKM0

  // ---- epilogue: f32 C write ----
#pragma unroll
  for (int m8 = 0; m8 < 8; ++m8)
#pragma unroll
    for (int ni = 0; ni < 2; ++ni) {
      int row = bm * 256 + wm * 128 + m8 * 16 + lg * 4;
      int col = bn * 128 + wn * 32 + ni * 16 + l15;
#pragma unroll
      for (int r = 0; r < 4; ++r)
        C[(size_t)(row + r) * N + col] = acc[m8][ni][r];
    }
}

// ---------------- block-sparse attention: one block per (bi, kvh), 8 waves (R13-verified)
// with fused Q-rope in the qf prologue.
__global__ __launch_bounds__(512, 2) void attn_kernel(
    const __hip_bfloat16* __restrict__ Qb,  // [4096][2048]  (un-roped)
    const __hip_bfloat16* __restrict__ Kb,  // [4096][512]   (roped by postproc)
    const __hip_bfloat16* __restrict__ Vt,  // [512][4096]   (channel-major)
    const float* __restrict__ cosb, const float* __restrict__ sinb,
    const float* __restrict__ amask,        // [4096]
    __hip_bfloat16* __restrict__ AO)        // [4096][2048]
{
  const int bid = blockIdx.x;
  const int kvh = bid & 3;
  const int bi  = bid >> 2;
  const int tid = threadIdx.x;
  const int wave = tid >> 6, lane = tid & 63;
  const int l15 = lane & 15, lg = lane >> 4;
  const int h  = kvh * 4 + (wave >> 1);
  const int rh = wave & 1;
  const int q0 = bi * 64 + rh * 32;

  int sel[6]; int nsel = 0;
  {
    int gtop = bi >> 2;
    for (int j = 0; j <= bi; ++j) {
      bool pick = (j == 0) || (j >= bi - 3) || (((j & 3) == 0) && ((j >> 2) >= gtop - 1));
      if (pick && nsel < 6) sel[nsel++] = j;
    }
  }

  __shared__ __hip_bfloat16 kv[2][16384];  // per buf: K [64][128] at 0, V [128][64] at 8192
  __shared__ __hip_bfloat16 Pl[8][2304];   // per wave: P [32][72]

  short8 qf[2][4];
#pragma unroll
  for (int mi = 0; mi < 2; ++mi) {
    const int s_ = q0 + mi * 16 + l15;
    const __hip_bfloat16* qrow = Qb + (size_t)s_ * 2048 + h * 128;
#pragma unroll
    for (int ks = 0; ks < 4; ++ks)
      qf[mi][ks] = *(const short8*)(qrow + ks * 32 + lg * 8);
    const float* cp = cosb + (size_t)s_ * 64 + lg * 8;
    const float* sp = sinb + (size_t)s_ * 64 + lg * 8;
    float ca[8], sa[8], cb[8], sb[8];
    *(float4*)&ca[0] = *(const float4*)cp;        *(float4*)&ca[4] = *(const float4*)(cp + 4);
    *(float4*)&cb[0] = *(const float4*)(cp + 32); *(float4*)&cb[4] = *(const float4*)(cp + 36);
    *(float4*)&sa[0] = *(const float4*)sp;        *(float4*)&sa[4] = *(const float4*)(sp + 4);
    *(float4*)&sb[0] = *(const float4*)(sp + 32); *(float4*)&sb[4] = *(const float4*)(sp + 36);
    short8 a = qf[mi][0], b = qf[mi][1], oa, ob;
#pragma unroll
    for (int i = 0; i < 8; ++i) {
      float av = bf2f(a[i]), bv = bf2f(b[i]);
      oa[i] = f2bf_s(av * ca[i] - bv * sa[i]);   // d<32:  -x[d+32]*sin
      ob[i] = f2bf_s(bv * cb[i] + av * sb[i]);   // d>=32: +x[d-32]*sin
    }
    qf[mi][0] = oa;
    qf[mi][1] = ob;
  }

  float m[2][4], l[2][4];
  f32x4 oacc[2][8] = {};
#pragma unroll
  for (int mi = 0; mi < 2; ++mi)
#pragma unroll
    for (int r = 0; r < 4; ++r) { m[mi][r] = -3.0e38f; l[mi][r] = 0.f; }

#define STAGE_KV(KB, BUF)                                                          \
  {                                                                                \
    _Pragma("unroll")                                                              \
    for (int i = 0; i < 2; ++i) {                                                  \
      int chunk = (i * 8 + wave) * 64 + lane;                                      \
      int row = chunk >> 4, slot = chunk & 15;                                     \
      gload16(Kb + (size_t)((KB) * 64 + row) * 512 + kvh * 128 +                   \
                  ((slot ^ (row & 15)) * 8),                                       \
              &kv[BUF][(i * 8 + wave) * 512]);                                     \
    }                                                                              \
    _Pragma("unroll")                                                              \
    for (int i = 0; i < 2; ++i) {                                                  \
      int chunk = (i * 8 + wave) * 64 + lane;                                      \
      int row = chunk >> 3, slot = chunk & 7;                                      \
      gload16(Vt + (size_t)(kvh * 128 + row) * 4096 + (KB) * 64 +                  \
                  ((slot ^ (row & 7)) * 8),                                        \
              &kv[BUF][8192 + (i * 8 + wave) * 512]);                              \
    }                                                                              \
  }

  STAGE_KV(sel[0], 0);

#pragma unroll
  for (int j = 0; j < 6; ++j) {
    if (j < nsel) {
      const int kb = sel[j];
      if (j + 1 < nsel) {
        STAGE_KV(sel[j + 1], (j + 1) & 1);
        asm volatile("s_waitcnt vmcnt(4)" ::: "memory");
      } else {
        asm volatile("s_waitcnt vmcnt(0)" ::: "memory");
      }
      __builtin_amdgcn_sched_barrier(0);
      __builtin_amdgcn_s_barrier();
      const __hip_bfloat16* kbuf = kv[j & 1];

      f32x4 sc[2][4] = {};
#pragma unroll
      for (int nf = 0; nf < 4; ++nf)
#pragma unroll
        for (int ks = 0; ks < 4; ++ks) {
          short8 b = *(const short8*)&kbuf[(nf * 16 + l15) * 128 +
                                           (((ks * 4 + lg) ^ l15) * 8)];
          sc[0][nf] = __builtin_amdgcn_mfma_f32_16x16x32_bf16(qf[0][ks], b, sc[0][nf], 0, 0, 0);
          sc[1][nf] = __builtin_amdgcn_mfma_f32_16x16x32_bf16(qf[1][ks], b, sc[1][nf], 0, 0, 0);
        }

      float am[4];
#pragma unroll
      for (int nf = 0; nf < 4; ++nf)
        am[nf] = (1.0f - amask[kb * 64 + nf * 16 + l15]) * NEGV;
#pragma unroll
      for (int mi = 0; mi < 2; ++mi)
#pragma unroll
        for (int nf = 0; nf < 4; ++nf) {
          int keyl = nf * 16 + l15;
#pragma unroll
          for (int r = 0; r < 4; ++r) {
            float s = sc[mi][nf][r] * SCALE + am[nf];
            if (kb == bi) {
              int qrow = rh * 32 + mi * 16 + lg * 4 + r;
              if (keyl > qrow) s = NEGV;
            }
            sc[mi][nf][r] = s;
          }
        }

      float pm[2][4];
#pragma unroll
      for (int mi = 0; mi < 2; ++mi)
#pragma unroll
        for (int r = 0; r < 4; ++r) {
          float v = fmaxf(fmaxf(sc[mi][0][r], sc[mi][1][r]),
                          fmaxf(sc[mi][2][r], sc[mi][3][r]));
          v = fmaxf(v, __shfl_xor(v, 1)); v = fmaxf(v, __shfl_xor(v, 2));
          v = fmaxf(v, __shfl_xor(v, 4)); v = fmaxf(v, __shfl_xor(v, 8));
          pm[mi][r] = v;
        }

      bool need = false;
#pragma unroll
      for (int mi = 0; mi < 2; ++mi)
#pragma unroll
        for (int r = 0; r < 4; ++r) need |= (pm[mi][r] - m[mi][r] > 8.0f);
      if (__any(need)) {
#pragma unroll
        for (int mi = 0; mi < 2; ++mi)
#pragma unroll
          for (int r = 0; r < 4; ++r) {
            float mn = fmaxf(m[mi][r], pm[mi][r]);
            float scl = __expf(m[mi][r] - mn);
            l[mi][r] *= scl;
#pragma unroll
            for (int df = 0; df < 8; ++df) oacc[mi][df][r] *= scl;
            m[mi][r] = mn;
          }
      }

#pragma unroll
      for (int mi = 0; mi < 2; ++mi)
#pragma unroll
        for (int r = 0; r < 4; ++r) {
          float rs = 0.f;
#pragma unroll
          for (int nf = 0; nf < 4; ++nf) {
            float p = __expf(sc[mi][nf][r] - m[mi][r]);
            rs += p;
            Pl[wave][(mi * 16 + lg * 4 + r) * 72 + nf * 16 + l15] = __float2bfloat16(p);
          }
          rs += __shfl_xor(rs, 1); rs += __shfl_xor(rs, 2);
          rs += __shfl_xor(rs, 4); rs += __shfl_xor(rs, 8);
          l[mi][r] += rs;
        }

      short8 af2[2][2];
#pragma unroll
      for (int mi = 0; mi < 2; ++mi)
#pragma unroll
        for (int ks = 0; ks < 2; ++ks)
          af2[mi][ks] = *(const short8*)&Pl[wave][(mi * 16 + l15) * 72 + ks * 32 + lg * 8];
#pragma unroll
      for (int df = 0; df < 8; ++df)
#pragma unroll
        for (int ks = 0; ks < 2; ++ks) {
          short8 vb = *(const short8*)&kbuf[8192 + (df * 16 + l15) * 64 +
                                            (((ks * 4 + lg) ^ (l15 & 7)) * 8)];
          oacc[0][df] = __builtin_amdgcn_mfma_f32_16x16x32_bf16(af2[0][ks], vb, oacc[0][df], 0, 0, 0);
          oacc[1][df] = __builtin_amdgcn_mfma_f32_16x16x32_bf16(af2[1][ks], vb, oacc[1][df], 0, 0, 0);
        }
      __builtin_amdgcn_s_barrier();
    }
  }
#undef STAGE_KV

#pragma unroll
  for (int mi = 0; mi < 2; ++mi) {
    float inv[4];
#pragma unroll
    for (int r = 0; r < 4; ++r) inv[r] = 1.0f / l[mi][r];
#pragma unroll
    for (int df = 0; df < 8; ++df)
#pragma unroll
      for (int r = 0; r < 4; ++r) {
        int qrow = q0 + mi * 16 + lg * 4 + r;
        AO[(size_t)qrow * 2048 + h * 128 + df * 16 + l15] =
            __float2bfloat16(oacc[mi][df][r] * inv[r]);
      }
  }
}

// ---------------- launch ----------------
extern "C" void kernel_launch(void* const* d_in, const int* in_sizes, int n_in,
                              void* d_out, int out_size, void* d_ws, size_t ws_size,
                              hipStream_t stream) {
  const float* hidden = (const float*)d_in[0];
  const float* cosb   = (const float*)d_in[1];
  const float* sinb   = (const float*)d_in[2];
  const float* Wq     = (const float*)d_in[3];
  const float* Wk     = (const float*)d_in[4];
  const float* Wv     = (const float*)d_in[5];
  const float* Wo     = (const float*)d_in[6];
  const float* amask  = (const float*)d_in[7];

  char* ws = (char*)d_ws;
  __hip_bfloat16* Xb   = (__hip_bfloat16*)(ws);               // 16,777,216 B  [4096][2048]
  __hip_bfloat16* Wt   = (__hip_bfloat16*)(ws + 16777216);    // 12,582,912 B  [3072][2048]
  __hip_bfloat16* Wot  = (__hip_bfloat16*)(ws + 29360128);    //  8,388,608 B  [2048][2048]
  __hip_bfloat16* Qb   = (__hip_bfloat16*)(ws + 37748736);    // 16,777,216 B  [4096][2048]
  __hip_bfloat16* Kb   = (__hip_bfloat16*)(ws + 54525952);    //  4,194,304 B  [4096][512]
  __hip_bfloat16* Vb   = (__hip_bfloat16*)(ws + 58720256);    //  4,194,304 B  [4096][512]
  __hip_bfloat16* Vt   = (__hip_bfloat16*)(ws + 62914560);    //  4,194,304 B  [512][4096]
  __hip_bfloat16* AO   = Xb;  // Xb dead after gemm_qkv2p; reuse for attention output

  prep_all<<<6656, 256, 0, stream>>>(hidden, Wq, Wk, Wv, Wo, Xb, Wt, Wot);

  gemm_qkv2p<<<dim3(16, 16), 512, 0, stream>>>(Xb, Wt, Qb, Kb, Vb);

  postproc<<<768, 256, 0, stream>>>(cosb, sinb, Kb, Vb, Vt);

  attn_kernel<<<256, 512, 0, stream>>>(Qb, Kb, Vt, cosb, sinb, amask, AO);

  gemm_out2p<<<dim3(16, 16), 512, 0, stream>>>(AO, Wot, (float*)d_out);
}

// Round 18
// 150.093 us; speedup vs baseline: 1.2156x; 1.0003x over previous
//
#include <hip/hip_runtime.h>
#include <hip/hip_bf16.h>

// HumanVAttention: QKV proj -> K-rope + V transpose -> GQA block-sparse attn (Q-rope fused) -> out proj
// B=1 S=4096 HID=2048 NH=16 NKV=4 HD=128 BLK=64 LOCAL=4 GNB=2 STRIDE=4 ROT=64

typedef short short8 __attribute__((ext_vector_type(8)));
typedef float f32x4  __attribute__((ext_vector_type(4)));

#define NEGV   (-1.0e9f)
#define SCALE  (0.08838834764831845f)

__device__ __forceinline__ void gload16(const void* g, void* l) {
  __builtin_amdgcn_global_load_lds(
      (const __attribute__((address_space(1))) unsigned int*)g,
      (__attribute__((address_space(3))) unsigned int*)l, 16, 0, 0);
}

__device__ __forceinline__ float bf2f(short s) {
  union { unsigned u; float f; } c;
  c.u = ((unsigned)(unsigned short)s) << 16;
  return c.f;
}

__device__ __forceinline__ short f2bf_s(float f) {
  __hip_bfloat16 b = __float2bfloat16(f);
  short s;
  __builtin_memcpy(&s, &b, 2);
  return s;
}

// ---------------- fused prep: hidden f32->bf16 convert + 4 weight transposes (R14-verified) ----------------
__global__ void prep_all(const float* __restrict__ H, const float* __restrict__ Wq,
                         const float* __restrict__ Wk, const float* __restrict__ Wv,
                         const float* __restrict__ Wo, __hip_bfloat16* __restrict__ X,
                         __hip_bfloat16* __restrict__ Wt, __hip_bfloat16* __restrict__ Wot) {
  __shared__ short tile[64][73];
  const int b = blockIdx.x;
  const int tid = threadIdx.x;
  if (b < 4096) {                           // conv hidden: 8 floats -> 8 bf16 per thread
    size_t t = (size_t)b * 256 + tid;
    const float* hp = H + t * 8;
    float4 v0 = *(const float4*)hp;
    float4 v1 = *(const float4*)(hp + 4);
    short8 o;
    o[0] = f2bf_s(v0.x); o[1] = f2bf_s(v0.y); o[2] = f2bf_s(v0.z); o[3] = f2bf_s(v0.w);
    o[4] = f2bf_s(v1.x); o[5] = f2bf_s(v1.y); o[6] = f2bf_s(v1.z); o[7] = f2bf_s(v1.w);
    *(short8*)&X[t * 8] = o;
    return;
  }
  const float* src; __hip_bfloat16* dst; int C; int idx;
  int q = b - 4096;
  if (q < 1024)      { src = Wq; dst = Wt;                       C = 2048; idx = q; }
  else if (q < 1280) { src = Wk; dst = Wt + (size_t)2048 * 2048; C = 512;  idx = q - 1024; }
  else if (q < 1536) { src = Wv; dst = Wt + (size_t)2560 * 2048; C = 512;  idx = q - 1280; }
  else               { src = Wo; dst = Wot;                      C = 2048; idx = q - 1536; }
  const int r0 = (idx & 31) * 64, c0 = (idx >> 5) * 64;
  const int c4 = (tid & 15) * 4, rb = tid >> 4;
#pragma unroll
  for (int j = 0; j < 4; ++j) {
    int r = rb + j * 16;
    float4 v = *(const float4*)(src + (size_t)(r0 + r) * C + c0 + c4);
    tile[r][c4 + 0] = f2bf_s(v.x);
    tile[r][c4 + 1] = f2bf_s(v.y);
    tile[r][c4 + 2] = f2bf_s(v.z);
    tile[r][c4 + 3] = f2bf_s(v.w);
  }
  __syncthreads();
  const int cs = (tid & 7) * 8;
#pragma unroll
  for (int it = 0; it < 2; ++it) {
    int cc = (tid >> 3) + it * 32;
    short8 o;
#pragma unroll
    for (int i = 0; i < 8; ++i) o[i] = tile[cs + i][cc];
    *(short8*)&dst[(size_t)(c0 + cc) * 2048 + r0 + cs] = o;
  }
}

// ---------------- postproc: in-place K-rope + V transpose (R13-verified) ----------------
__global__ void postproc(const float* __restrict__ cosb, const float* __restrict__ sinb,
                         __hip_bfloat16* __restrict__ Kb,
                         const __hip_bfloat16* __restrict__ Vb, __hip_bfloat16* __restrict__ Vt) {
  __shared__ __hip_bfloat16 tile[64][73];
  int blk = blockIdx.x;
  if (blk < 256) {
    int tk = blk * 256 + threadIdx.x;       // [0, 65536): 4096 s x 4 h x 4 g
    int s = tk >> 4;
    int rem = tk & 15;
    __hip_bfloat16* p = Kb + (size_t)s * 512 + (rem >> 2) * 128 + (rem & 3) * 8;
    const int g8 = (tk & 3) * 8;            // d offset in [0,32)
    const float* cp = cosb + (size_t)s * 64 + g8;
    const float* sp = sinb + (size_t)s * 64 + g8;
    short8 a = *(const short8*)p;           // x[d],    d in [0,32)
    short8 b = *(const short8*)(p + 32);    // x[d+32]
    float ca[8], sa[8], cb[8], sb[8];
    *(float4*)&ca[0] = *(const float4*)cp;        *(float4*)&ca[4] = *(const float4*)(cp + 4);
    *(float4*)&cb[0] = *(const float4*)(cp + 32); *(float4*)&cb[4] = *(const float4*)(cp + 36);
    *(float4*)&sa[0] = *(const float4*)sp;        *(float4*)&sa[4] = *(const float4*)(sp + 4);
    *(float4*)&sb[0] = *(const float4*)(sp + 32); *(float4*)&sb[4] = *(const float4*)(sp + 36);
    short8 oa, ob;
#pragma unroll
    for (int i = 0; i < 8; ++i) {
      float av = bf2f(a[i]), bv = bf2f(b[i]);
      oa[i] = f2bf_s(av * ca[i] - bv * sa[i]);   // rot_half: d<32 -> -x[d+32]
      ob[i] = f2bf_s(bv * cb[i] + av * sb[i]);   // d>=32   -> +x[d-32]
    }
    *(short8*)p = oa;
    *(short8*)(p + 32) = ob;
    return;
  }
  int idx = blk - 256;                      // 512 blocks: 64 x 8
  int s0 = (idx & 63) * 64, c0 = (idx >> 6) * 64;
  int c = threadIdx.x & 63, rq = threadIdx.x >> 6;
#pragma unroll
  for (int i = 0; i < 16; ++i) {
    int r = i * 4 + rq;
    tile[r][c] = Vb[(size_t)(s0 + r) * 512 + c0 + c];
  }
  __syncthreads();
#pragma unroll
  for (int i = 0; i < 16; ++i) {
    int cc = i * 4 + rq;
    Vt[(size_t)(c0 + cc) * 4096 + s0 + c] = tile[c][cc];
  }
}

// ---------------- GEMM1: BM=256 x BN=192, 2-phase + split-MFMA read interleave ----------------
// R16-verified schedule (barriers/vmcnt identical); within each phase the 24-MFMA cluster
// is split into two 12-MFMA halves with the next quadrant's ds_reads issued between them
// (WAR cleared after the first half consumes af[P]; bfr reads stay after its last consumer).
__global__ __launch_bounds__(512, 2) void gemm_qkv2p(
    const __hip_bfloat16* __restrict__ A, const __hip_bfloat16* __restrict__ Bt,
    __hip_bfloat16* __restrict__ Qb, __hip_bfloat16* __restrict__ Kb,
    __hip_bfloat16* __restrict__ Vb) {
  const int K = 2048;
  const int tid = threadIdx.x;
  const int wave = tid >> 6, lane = tid & 63;
  const int l15 = lane & 15, lg = lane >> 4;
  const int bm = blockIdx.x, bn = blockIdx.y;     // 16 x 16
  const int wm = wave >> 2, wn = wave & 3;        // 2M x 4N; per-wave C: 128 x 48

  __shared__ __hip_bfloat16 lds[57344];           // 112 KiB; buf stride 28672 elems

  f32x4 acc[8][3] = {};
  const int srow = lane >> 3;
  const int sslot = lane & 7;
  const int scol = (sslot ^ srow) * 8;
  const size_t abase = (size_t)bm * 256 * K;
  const size_t bbase = (size_t)bn * 192 * K;
  const int r3 = l15 & 7;

#define STAGE_A(HALF, KO, LBASE)                                                 \
  {                                                                              \
    _Pragma("unroll")                                                            \
    for (int l = 0; l < 2; ++l) {                                                \
      int chunk = l * 8 + wave;                                                  \
      int row = chunk * 8 + srow;                                                \
      gload16(A + abase + (size_t)((HALF) * 128 + row) * K + (KO) + scol,        \
              &lds[(LBASE) + chunk * 512]);                                      \
    }                                                                            \
  }
#define STAGE_B(KO, LBASE)                                                       \
  {                                                                              \
    _Pragma("unroll")                                                            \
    for (int l = 0; l < 3; ++l) {                                                \
      int chunk = l * 8 + wave;                                                  \
      int row = chunk * 8 + srow;                                                \
      gload16(Bt + bbase + (size_t)row * K + (KO) + scol,                        \
              &lds[(LBASE) + chunk * 512]);                                      \
    }                                                                            \
  }

  short8 bfr[3][2];
  short8 af[2][2][2];

#define READ_AF(P, Q, BA)                                                        \
  {                                                                              \
    _Pragma("unroll")                                                            \
    for (int m2 = 0; m2 < 2; ++m2)                                               \
      _Pragma("unroll")                                                          \
      for (int ks = 0; ks < 2; ++ks) {                                           \
        int row = ((Q) * 2 + m2) * 16 + l15;                                     \
        int slot = (ks * 4 + lg) ^ r3;                                           \
        af[P][m2][ks] = *(const short8*)&lds[(BA) + row * 64 + slot * 8];        \
      }                                                                          \
  }

#define READ_BF(BB)                                                              \
  {                                                                              \
    _Pragma("unroll")                                                            \
    for (int ni = 0; ni < 3; ++ni)                                               \
      _Pragma("unroll")                                                          \
      for (int ks = 0; ks < 2; ++ks) {                                           \
        int row = wn * 48 + ni * 16 + l15;                                       \
        int slot = (ks * 4 + lg) ^ r3;                                           \
        bfr[ni][ks] = *(const short8*)&lds[(BB) + row * 64 + slot * 8];          \
      }                                                                          \
  }

// 12 MFMA: one quadrant Q using af[P]
#define MFMA_1Q(Q, P)                                                            \
  {                                                                              \
    __builtin_amdgcn_s_setprio(1);                                               \
    _Pragma("unroll")                                                            \
    for (int ks = 0; ks < 2; ++ks)                                               \
      _Pragma("unroll")                                                          \
      for (int m2 = 0; m2 < 2; ++m2)                                             \
        _Pragma("unroll")                                                        \
        for (int ni = 0; ni < 3; ++ni)                                           \
          acc[(Q) * 2 + m2][ni] = __builtin_amdgcn_mfma_f32_16x16x32_bf16(       \
              af[P][m2][ks], bfr[ni][ks], acc[(Q) * 2 + m2][ni], 0, 0, 0);       \
    __builtin_amdgcn_s_setprio(0);                                               \
  }

#define LGKM0()                                                                  \
  asm volatile("s_waitcnt lgkmcnt(0)" ::: "memory");                             \
  __builtin_amdgcn_sched_barrier(0);

  STAGE_B(0, 16384);
  STAGE_A(0, 0, 0);
  STAGE_A(1, 0, 8192);
  STAGE_B(64, 28672 + 16384);
  asm volatile("s_waitcnt vmcnt(3)" ::: "memory");
  __builtin_amdgcn_sched_barrier(0);
  __builtin_amdgcn_s_barrier();
  {
    READ_BF(16384);
    READ_AF(0, 0, wm * 8192);   // q0
    READ_AF(1, 1, wm * 8192);   // q1
  }
  LGKM0();

  for (int t = 0; t < 32; ++t) {
    const int buf = (t & 1) * 28672;
    const int nbuf = buf ^ 28672;
    const int bA = buf + wm * 8192;
    // ---- ph0: MFMA q0 | read q2 | MFMA q1 | read q3 ----
    if (t + 1 < 32) { STAGE_A(0, (t + 1) * 64, nbuf); STAGE_A(1, (t + 1) * 64, nbuf + 8192); }
    __builtin_amdgcn_s_barrier();
    MFMA_1Q(0, 0);
    READ_AF(0, 2, bA);          // af[0] free after q0's MFMAs; reads fly under q1
    MFMA_1Q(1, 1);
    READ_AF(1, 3, bA);
    LGKM0();
    // ---- ph1: stage B(t+2); counted vmcnt; MFMA q2 | read next-q0 | MFMA q3 | read bfr+next-q1 ----
    if (t + 2 < 32) STAGE_B((t + 2) * 64, buf + 16384);
    if (t < 30) asm volatile("s_waitcnt vmcnt(3)" ::: "memory");
    else        asm volatile("s_waitcnt vmcnt(0)" ::: "memory");
    __builtin_amdgcn_sched_barrier(0);
    __builtin_amdgcn_s_barrier();
    MFMA_1Q(2, 0);
    if (t + 1 < 32) READ_AF(0, 0, nbuf + wm * 8192);   // af[0] free after q2; fly under q3
    MFMA_1Q(3, 1);
    if (t + 1 < 32) {
      READ_BF(nbuf + 16384);    // bfr free after q3 (its last consumer)
      READ_AF(1, 1, nbuf + wm * 8192);
    }
    LGKM0();
  }
#undef STAGE_A
#undef STAGE_B

#pragma unroll
  for (int m8 = 0; m8 < 8; ++m8)
#pragma unroll
    for (int ni = 0; ni < 3; ++ni) {
      int colg = bn * 192 + wn * 48 + ni * 16;
      __hip_bfloat16* dst; int ldc, col;
      if (colg < 2048)      { dst = Qb; ldc = 2048; col = colg + l15; }
      else if (colg < 2560) { dst = Kb; ldc = 512;  col = colg - 2048 + l15; }
      else                  { dst = Vb; ldc = 512;  col = colg - 2560 + l15; }
      int row = bm * 256 + wm * 128 + m8 * 16 + lg * 4;
#pragma unroll
      for (int r = 0; r < 4; ++r)
        dst[(size_t)(row + r) * ldc + col] = __float2bfloat16(acc[m8][ni][r]);
    }
#undef READ_AF
#undef READ_BF
#undef MFMA_1Q
#undef LGKM0
}

// ---------------- GEMM2: BM=256 x BN=128, 2-phase + split-MFMA read interleave ----------------
__global__ __launch_bounds__(512, 2) void gemm_out2p(
    const __hip_bfloat16* __restrict__ A, const __hip_bfloat16* __restrict__ Bt,
    float* __restrict__ C) {
  const int K = 2048, N = 2048;
  const int tid = threadIdx.x;
  const int wave = tid >> 6, lane = tid & 63;
  const int l15 = lane & 15, lg = lane >> 4;
  const int bm = blockIdx.x, bn = blockIdx.y;     // 16 x 16
  const int wm = wave >> 2, wn = wave & 3;        // 2M x 4N; per-wave C: 128 x 32

  __shared__ __hip_bfloat16 lds[49152];           // 96 KiB; buf stride 24576 elems

  f32x4 acc[8][2] = {};
  const int srow = lane >> 3;
  const int sslot = lane & 7;
  const int scol = (sslot ^ srow) * 8;
  const size_t abase = (size_t)bm * 256 * K;
  const size_t bbase = (size_t)bn * 128 * K;
  const int r3 = l15 & 7;

#define STAGE_A(HALF, KO, LBASE)                                                 \
  {                                                                              \
    _Pragma("unroll")                                                            \
    for (int l = 0; l < 2; ++l) {                                                \
      int chunk = l * 8 + wave;                                                  \
      int row = chunk * 8 + srow;                                                \
      gload16(A + abase + (size_t)((HALF) * 128 + row) * K + (KO) + scol,        \
              &lds[(LBASE) + chunk * 512]);                                      \
    }                                                                            \
  }
#define STAGE_B(KO, LBASE)                                                       \
  {                                                                              \
    _Pragma("unroll")                                                            \
    for (int l = 0; l < 2; ++l) {                                                \
      int chunk = l * 8 + wave;                                                  \
      int row = chunk * 8 + srow;                                                \
      gload16(Bt + bbase + (size_t)row * K + (KO) + scol,                        \
              &lds[(LBASE) + chunk * 512]);                                      \
    }                                                                            \
  }

  short8 bfr[2][2];
  short8 af[2][2][2];

#define READ_AF(P, Q, BA)                                                        \
  {                                                                              \
    _Pragma("unroll")                                                            \
    for (int m2 = 0; m2 < 2; ++m2)                                               \
      _Pragma("unroll")                                                          \
      for (int ks = 0; ks < 2; ++ks) {                                           \
        int row = ((Q) * 2 + m2) * 16 + l15;                                     \
        int slot = (ks * 4 + lg) ^ r3;                                           \
        af[P][m2][ks] = *(const short8*)&lds[(BA) + row * 64 + slot * 8];        \
      }                                                                          \
  }

#define READ_BF(BB)                                                              \
  {                                                                              \
    _Pragma("unroll")                                                            \
    for (int ni = 0; ni < 2; ++ni)                                               \
      _Pragma("unroll")                                                          \
      for (int ks = 0; ks < 2; ++ks) {                                           \
        int row = wn * 32 + ni * 16 + l15;                                       \
        int slot = (ks * 4 + lg) ^ r3;                                           \
        bfr[ni][ks] = *(const short8*)&lds[(BB) + row * 64 + slot * 8];          \
      }                                                                          \
  }

#define MFMA_1Q(Q, P)                                                            \
  {                                                                              \
    __builtin_amdgcn_s_setprio(1);                                               \
    _Pragma("unroll")                                                            \
    for (int ks = 0; ks < 2; ++ks)                                               \
      _Pragma("unroll")                                                          \
      for (int m2 = 0; m2 < 2; ++m2)                                             \
        _Pragma("unroll")                                                        \
        for (int ni = 0; ni < 2; ++ni)                                           \
          acc[(Q) * 2 + m2][ni] = __builtin_amdgcn_mfma_f32_16x16x32_bf16(       \
              af[P][m2][ks], bfr[ni][ks], acc[(Q) * 2 + m2][ni], 0, 0, 0);       \
    __builtin_amdgcn_s_setprio(0);                                               \
  }

#define LGKM0()                                                                  \
  asm volatile("s_waitcnt lgkmcnt(0)" ::: "memory");                             \
  __builtin_amdgcn_sched_barrier(0);

  STAGE_B(0, 16384);
  STAGE_A(0, 0, 0);
  STAGE_A(1, 0, 8192);
  STAGE_B(64, 24576 + 16384);
  asm volatile("s_waitcnt vmcnt(2)" ::: "memory");
  __builtin_amdgcn_sched_barrier(0);
  __builtin_amdgcn_s_barrier();
  {
    READ_BF(16384);
    READ_AF(0, 0, wm * 8192);
    READ_AF(1, 1, wm * 8192);
  }
  LGKM0();

  for (int t = 0; t < 32; ++t) {
    const int buf = (t & 1) * 24576;
    const int nbuf = buf ^ 24576;
    const int bA = buf + wm * 8192;
    // ph0: MFMA q0 | read q2 | MFMA q1 | read q3
    if (t + 1 < 32) { STAGE_A(0, (t + 1) * 64, nbuf); STAGE_A(1, (t + 1) * 64, nbuf + 8192); }
    __builtin_amdgcn_s_barrier();
    MFMA_1Q(0, 0);
    READ_AF(0, 2, bA);
    MFMA_1Q(1, 1);
    READ_AF(1, 3, bA);
    LGKM0();
    // ph1: stage B(t+2); counted vmcnt; MFMA q2 | read next-q0 | MFMA q3 | read bfr+next-q1
    if (t + 2 < 32) STAGE_B((t + 2) * 64, buf + 16384);
    if (t < 30) asm volatile("s_waitcnt vmcnt(2)" ::: "memory");
    else        asm volatile("s_waitcnt vmcnt(0)" ::: "memory");
    __builtin_amdgcn_sched_barrier(0);
    __builtin_amdgcn_s_barrier();
    MFMA_1Q(2, 0);
    if (t + 1 < 32) READ_AF(0, 0, nbuf + wm * 8192);
    MFMA_1Q(3, 1);
    if (t + 1 < 32) {
      READ_BF(nbuf + 16384);
      READ_AF(1, 1, nbuf + wm * 8192);
    }
    LGKM0();
  }
#undef STAGE_A
#undef STAGE_B
#undef READ_AF
#undef READ_BF
#undef MFMA_1Q
#undef LGKM0

  // ---- epilogue: f32 C write ----
#pragma unroll
  for (int m8 = 0; m8 < 8; ++m8)
#pragma unroll
    for (int ni = 0; ni < 2; ++ni) {
      int row = bm * 256 + wm * 128 + m8 * 16 + lg * 4;
      int col = bn * 128 + wn * 32 + ni * 16 + l15;
#pragma unroll
      for (int r = 0; r < 4; ++r)
        C[(size_t)(row + r) * N + col] = acc[m8][ni][r];
    }
}

// ---------------- block-sparse attention: one block per (bi, kvh), 8 waves (R13-verified)
// with fused Q-rope in the qf prologue.
__global__ __launch_bounds__(512, 2) void attn_kernel(
    const __hip_bfloat16* __restrict__ Qb,  // [4096][2048]  (un-roped)
    const __hip_bfloat16* __restrict__ Kb,  // [4096][512]   (roped by postproc)
    const __hip_bfloat16* __restrict__ Vt,  // [512][4096]   (channel-major)
    const float* __restrict__ cosb, const float* __restrict__ sinb,
    const float* __restrict__ amask,        // [4096]
    __hip_bfloat16* __restrict__ AO)        // [4096][2048]
{
  const int bid = blockIdx.x;
  const int kvh = bid & 3;
  const int bi  = bid >> 2;
  const int tid = threadIdx.x;
  const int wave = tid >> 6, lane = tid & 63;
  const int l15 = lane & 15, lg = lane >> 4;
  const int h  = kvh * 4 + (wave >> 1);
  const int rh = wave & 1;
  const int q0 = bi * 64 + rh * 32;

  int sel[6]; int nsel = 0;
  {
    int gtop = bi >> 2;
    for (int j = 0; j <= bi; ++j) {
      bool pick = (j == 0) || (j >= bi - 3) || (((j & 3) == 0) && ((j >> 2) >= gtop - 1));
      if (pick && nsel < 6) sel[nsel++] = j;
    }
  }

  __shared__ __hip_bfloat16 kv[2][16384];  // per buf: K [64][128] at 0, V [128][64] at 8192
  __shared__ __hip_bfloat16 Pl[8][2304];   // per wave: P [32][72]

  short8 qf[2][4];
#pragma unroll
  for (int mi = 0; mi < 2; ++mi) {
    const int s_ = q0 + mi * 16 + l15;
    const __hip_bfloat16* qrow = Qb + (size_t)s_ * 2048 + h * 128;
#pragma unroll
    for (int ks = 0; ks < 4; ++ks)
      qf[mi][ks] = *(const short8*)(qrow + ks * 32 + lg * 8);
    const float* cp = cosb + (size_t)s_ * 64 + lg * 8;
    const float* sp = sinb + (size_t)s_ * 64 + lg * 8;
    float ca[8], sa[8], cb[8], sb[8];
    *(float4*)&ca[0] = *(const float4*)cp;        *(float4*)&ca[4] = *(const float4*)(cp + 4);
    *(float4*)&cb[0] = *(const float4*)(cp + 32); *(float4*)&cb[4] = *(const float4*)(cp + 36);
    *(float4*)&sa[0] = *(const float4*)sp;        *(float4*)&sa[4] = *(const float4*)(sp + 4);
    *(float4*)&sb[0] = *(const float4*)(sp + 32); *(float4*)&sb[4] = *(const float4*)(sp + 36);
    short8 a = qf[mi][0], b = qf[mi][1], oa, ob;
#pragma unroll
    for (int i = 0; i < 8; ++i) {
      float av = bf2f(a[i]), bv = bf2f(b[i]);
      oa[i] = f2bf_s(av * ca[i] - bv * sa[i]);   // d<32:  -x[d+32]*sin
      ob[i] = f2bf_s(bv * cb[i] + av * sb[i]);   // d>=32: +x[d-32]*sin
    }
    qf[mi][0] = oa;
    qf[mi][1] = ob;
  }

  float m[2][4], l[2][4];
  f32x4 oacc[2][8] = {};
#pragma unroll
  for (int mi = 0; mi < 2; ++mi)
#pragma unroll
    for (int r = 0; r < 4; ++r) { m[mi][r] = -3.0e38f; l[mi][r] = 0.f; }

#define STAGE_KV(KB, BUF)                                                          \
  {                                                                                \
    _Pragma("unroll")                                                              \
    for (int i = 0; i < 2; ++i) {                                                  \
      int chunk = (i * 8 + wave) * 64 + lane;                                      \
      int row = chunk >> 4, slot = chunk & 15;                                     \
      gload16(Kb + (size_t)((KB) * 64 + row) * 512 + kvh * 128 +                   \
                  ((slot ^ (row & 15)) * 8),                                       \
              &kv[BUF][(i * 8 + wave) * 512]);                                     \
    }                                                                              \
    _Pragma("unroll")                                                              \
    for (int i = 0; i < 2; ++i) {                                                  \
      int chunk = (i * 8 + wave) * 64 + lane;                                      \
      int row = chunk >> 3, slot = chunk & 7;                                      \
      gload16(Vt + (size_t)(kvh * 128 + row) * 4096 + (KB) * 64 +                  \
                  ((slot ^ (row & 7)) * 8),                                        \
              &kv[BUF][8192 + (i * 8 + wave) * 512]);                              \
    }                                                                              \
  }

  STAGE_KV(sel[0], 0);

#pragma unroll
  for (int j = 0; j < 6; ++j) {
    if (j < nsel) {
      const int kb = sel[j];
      if (j + 1 < nsel) {
        STAGE_KV(sel[j + 1], (j + 1) & 1);
        asm volatile("s_waitcnt vmcnt(4)" ::: "memory");
      } else {
        asm volatile("s_waitcnt vmcnt(0)" ::: "memory");
      }
      __builtin_amdgcn_sched_barrier(0);
      __builtin_amdgcn_s_barrier();
      const __hip_bfloat16* kbuf = kv[j & 1];

      f32x4 sc[2][4] = {};
#pragma unroll
      for (int nf = 0; nf < 4; ++nf)
#pragma unroll
        for (int ks = 0; ks < 4; ++ks) {
          short8 b = *(const short8*)&kbuf[(nf * 16 + l15) * 128 +
                                           (((ks * 4 + lg) ^ l15) * 8)];
          sc[0][nf] = __builtin_amdgcn_mfma_f32_16x16x32_bf16(qf[0][ks], b, sc[0][nf], 0, 0, 0);
          sc[1][nf] = __builtin_amdgcn_mfma_f32_16x16x32_bf16(qf[1][ks], b, sc[1][nf], 0, 0, 0);
        }

      float am[4];
#pragma unroll
      for (int nf = 0; nf < 4; ++nf)
        am[nf] = (1.0f - amask[kb * 64 + nf * 16 + l15]) * NEGV;
#pragma unroll
      for (int mi = 0; mi < 2; ++mi)
#pragma unroll
        for (int nf = 0; nf < 4; ++nf) {
          int keyl = nf * 16 + l15;
#pragma unroll
          for (int r = 0; r < 4; ++r) {
            float s = sc[mi][nf][r] * SCALE + am[nf];
            if (kb == bi) {
              int qrow = rh * 32 + mi * 16 + lg * 4 + r;
              if (keyl > qrow) s = NEGV;
            }
            sc[mi][nf][r] = s;
          }
        }

      float pm[2][4];
#pragma unroll
      for (int mi = 0; mi < 2; ++mi)
#pragma unroll
        for (int r = 0; r < 4; ++r) {
          float v = fmaxf(fmaxf(sc[mi][0][r], sc[mi][1][r]),
                          fmaxf(sc[mi][2][r], sc[mi][3][r]));
          v = fmaxf(v, __shfl_xor(v, 1)); v = fmaxf(v, __shfl_xor(v, 2));
          v = fmaxf(v, __shfl_xor(v, 4)); v = fmaxf(v, __shfl_xor(v, 8));
          pm[mi][r] = v;
        }

      bool need = false;
#pragma unroll
      for (int mi = 0; mi < 2; ++mi)
#pragma unroll
        for (int r = 0; r < 4; ++r) need |= (pm[mi][r] - m[mi][r] > 8.0f);
      if (__any(need)) {
#pragma unroll
        for (int mi = 0; mi < 2; ++mi)
#pragma unroll
          for (int r = 0; r < 4; ++r) {
            float mn = fmaxf(m[mi][r], pm[mi][r]);
            float scl = __expf(m[mi][r] - mn);
            l[mi][r] *= scl;
#pragma unroll
            for (int df = 0; df < 8; ++df) oacc[mi][df][r] *= scl;
            m[mi][r] = mn;
          }
      }

#pragma unroll
      for (int mi = 0; mi < 2; ++mi)
#pragma unroll
        for (int r = 0; r < 4; ++r) {
          float rs = 0.f;
#pragma unroll
          for (int nf = 0; nf < 4; ++nf) {
            float p = __expf(sc[mi][nf][r] - m[mi][r]);
            rs += p;
            Pl[wave][(mi * 16 + lg * 4 + r) * 72 + nf * 16 + l15] = __float2bfloat16(p);
          }
          rs += __shfl_xor(rs, 1); rs += __shfl_xor(rs, 2);
          rs += __shfl_xor(rs, 4); rs += __shfl_xor(rs, 8);
          l[mi][r] += rs;
        }

      short8 af2[2][2];
#pragma unroll
      for (int mi = 0; mi < 2; ++mi)
#pragma unroll
        for (int ks = 0; ks < 2; ++ks)
          af2[mi][ks] = *(const short8*)&Pl[wave][(mi * 16 + l15) * 72 + ks * 32 + lg * 8];
#pragma unroll
      for (int df = 0; df < 8; ++df)
#pragma unroll
        for (int ks = 0; ks < 2; ++ks) {
          short8 vb = *(const short8*)&kbuf[8192 + (df * 16 + l15) * 64 +
                                            (((ks * 4 + lg) ^ (l15 & 7)) * 8)];
          oacc[0][df] = __builtin_amdgcn_mfma_f32_16x16x32_bf16(af2[0][ks], vb, oacc[0][df], 0, 0, 0);
          oacc[1][df] = __builtin_amdgcn_mfma_f32_16x16x32_bf16(af2[1][ks], vb, oacc[1][df], 0, 0, 0);
        }
      __builtin_amdgcn_s_barrier();
    }
  }
#undef STAGE_KV

#pragma unroll
  for (int mi = 0; mi < 2; ++mi) {
    float inv[4];
#pragma unroll
    for (int r = 0; r < 4; ++r) inv[r] = 1.0f / l[mi][r];
#pragma unroll
    for (int df = 0; df < 8; ++df)
#pragma unroll
      for (int r = 0; r < 4; ++r) {
        int qrow = q0 + mi * 16 + lg * 4 + r;
        AO[(size_t)qrow * 2048 + h * 128 + df * 16 + l15] =
            __float2bfloat16(oacc[mi][df][r] * inv[r]);
      }
  }
}

// ---------------- launch ----------------
extern "C" void kernel_launch(void* const* d_in, const int* in_sizes, int n_in,
                              void* d_out, int out_size, void* d_ws, size_t ws_size,
                              hipStream_t stream) {
  const float* hidden = (const float*)d_in[0];
  const float* cosb   = (const float*)d_in[1];
  const float* sinb   = (const float*)d_in[2];
  const float* Wq     = (const float*)d_in[3];
  const float* Wk     = (const float*)d_in[4];
  const float* Wv     = (const float*)d_in[5];
  const float* Wo     = (const float*)d_in[6];
  const float* amask  = (const float*)d_in[7];

  char* ws = (char*)d_ws;
  __hip_bfloat16* Xb   = (__hip_bfloat16*)(ws);               // 16,777,216 B  [4096][2048]
  __hip_bfloat16* Wt   = (__hip_bfloat16*)(ws + 16777216);    // 12,582,912 B  [3072][2048]
  __hip_bfloat16* Wot  = (__hip_bfloat16*)(ws + 29360128);    //  8,388,608 B  [2048][2048]
  __hip_bfloat16* Qb   = (__hip_bfloat16*)(ws + 37748736);    // 16,777,216 B  [4096][2048]
  __hip_bfloat16* Kb   = (__hip_bfloat16*)(ws + 54525952);    //  4,194,304 B  [4096][512]
  __hip_bfloat16* Vb   = (__hip_bfloat16*)(ws + 58720256);    //  4,194,304 B  [4096][512]
  __hip_bfloat16* Vt   = (__hip_bfloat16*)(ws + 62914560);    //  4,194,304 B  [512][4096]
  __hip_bfloat16* AO   = Xb;  // Xb dead after gemm_qkv2p; reuse for attention output

  prep_all<<<6656, 256, 0, stream>>>(hidden, Wq, Wk, Wv, Wo, Xb, Wt, Wot);

  gemm_qkv2p<<<dim3(16, 16), 512, 0, stream>>>(Xb, Wt, Qb, Kb, Vb);

  postproc<<<768, 256, 0, stream>>>(cosb, sinb, Kb, Vb, Vt);

  attn_kernel<<<256, 512, 0, stream>>>(Qb, Kb, Vt, cosb, sinb, amask, AO);

  gemm_out2p<<<dim3(16, 16), 512, 0, stream>>>(AO, Wot, (float*)d_out);
}